// Round 1
// baseline (6390.033 us; speedup 1.0000x reference)
//
#include <hip/hip_runtime.h>
#include <math.h>

// Problem constants (fixed by reference)
#define NNODES 100000
#define NEDGE  3200000
#define NF     512
#define NH     256
#define NC     40
#define NLAY   8
#define EPSV   1e-5f

// ---------------------------------------------------------------- utilities

__device__ __forceinline__ float block_sum_256(float v) {
    __shared__ float sb[8];
    #pragma unroll
    for (int off = 32; off; off >>= 1) v += __shfl_down(v, off, 64);
    if ((threadIdx.x & 63) == 0) sb[threadIdx.x >> 6] = v;
    __syncthreads();
    return sb[0] + sb[1] + sb[2] + sb[3];
}

// ---------------------------------------------------------------- CSR build

__global__ void k_hist(const int* __restrict__ dst, int* __restrict__ counts, int n) {
    int i = blockIdx.x * 256 + threadIdx.x;
    if (i < n) atomicAdd(&counts[dst[i]], 1);
}

__global__ void k_scan1(const int* __restrict__ in, int* __restrict__ out,
                        int* __restrict__ bsum, int n) {
    __shared__ int s[1024];
    int t = threadIdx.x, g = blockIdx.x * 1024 + t;
    int v = (g < n) ? in[g] : 0;
    s[t] = v; __syncthreads();
    for (int off = 1; off < 1024; off <<= 1) {
        int u = (t >= off) ? s[t - off] : 0;
        __syncthreads();
        s[t] += u;
        __syncthreads();
    }
    if (g < n) out[g] = s[t] - v;           // exclusive
    if (t == 1023) bsum[blockIdx.x] = s[1023];
}

__global__ void k_scan2(int* __restrict__ bsum, int nb) {
    __shared__ int s[128];
    int t = threadIdx.x;
    int v = (t < nb) ? bsum[t] : 0;
    s[t] = v; __syncthreads();
    for (int off = 1; off < 128; off <<= 1) {
        int u = (t >= off) ? s[t - off] : 0;
        __syncthreads();
        s[t] += u;
        __syncthreads();
    }
    if (t < nb) bsum[t] = s[t] - v;         // exclusive
}

__global__ void k_scan3(int* __restrict__ out, const int* __restrict__ bsum, int n) {
    int g = blockIdx.x * 1024 + threadIdx.x;
    if (g < n) out[g] += bsum[blockIdx.x];
}

__global__ void k_scatter(const int* __restrict__ src, const int* __restrict__ dst,
                          const float* __restrict__ w, const int* __restrict__ rstart,
                          int* __restrict__ cursor, int* __restrict__ ssrc,
                          float* __restrict__ sw, int n) {
    int i = blockIdx.x * 256 + threadIdx.x;
    if (i < n) {
        int d = dst[i];
        int pos = rstart[d] + atomicAdd(&cursor[d], 1);
        ssrc[pos] = src[i];
        sw[pos]   = w[i];
    }
}

// ---------------------------------------------------------------- ortho prep

// Zc0 = W0 - rowmean(W0), [256 x 512]. One block per row.
__global__ void k_zc0(const float* __restrict__ W0, float* __restrict__ Zc0) {
    int r = blockIdx.x, t = threadIdx.x;
    float a = W0[r * NF + t];
    float b = W0[r * NF + 256 + t];
    float mean = block_sum_256(a + b) * (1.0f / 512.0f);
    Zc0[r * NF + t]       = a - mean;
    Zc0[r * NF + 256 + t] = b - mean;
}

// we = 0.5*convW + 0.5*I; ZcC[g] = we - rowmean(we). One block per (g,row).
__global__ void k_zcC(const float* __restrict__ convW, float* __restrict__ ZcC) {
    int g = blockIdx.x >> 8, r = blockIdx.x & 255, t = threadIdx.x;
    float v = 0.5f * convW[((size_t)g * NH + r) * NH + t] + ((r == t) ? 0.5f : 0.0f);
    float mean = block_sum_256(v) * (1.0f / 256.0f);
    ZcC[((size_t)g * NH + r) * NH + t] = v - mean;
}

// S[b] = Zc[b] @ Zc[b]^T + EPS*I   (b=0: Zc0 K=512; b>0: ZcC[b-1] K=256)
__global__ __launch_bounds__(256) void k_gram(const float* __restrict__ Zc0,
                                              const float* __restrict__ ZcC,
                                              float* __restrict__ S) {
    const int b = blockIdx.z;
    const float* A = (b == 0) ? Zc0 : (ZcC + (size_t)(b - 1) * 65536);
    const int K = (b == 0) ? 512 : 256;
    const int r0 = blockIdx.y * 64, c0 = blockIdx.x * 64;
    __shared__ float As[32][76], Bs[32][76];
    const int t = threadIdx.x, tx = t & 15, ty = t >> 4;
    const int lr = t >> 2, lk = (t & 3) * 4;
    float acc[4][4] = {};
    for (int k0 = 0; k0 < K; k0 += 32) {
        float4 a0 = *(const float4*)(A + (size_t)(r0 + lr) * K + k0 + lk);
        float4 a1 = *(const float4*)(A + (size_t)(r0 + lr) * K + k0 + lk + 16);
        As[lk + 0][lr] = a0.x; As[lk + 1][lr] = a0.y; As[lk + 2][lr] = a0.z; As[lk + 3][lr] = a0.w;
        As[lk + 16][lr] = a1.x; As[lk + 17][lr] = a1.y; As[lk + 18][lr] = a1.z; As[lk + 19][lr] = a1.w;
        float4 b0 = *(const float4*)(A + (size_t)(c0 + lr) * K + k0 + lk);
        float4 b1 = *(const float4*)(A + (size_t)(c0 + lr) * K + k0 + lk + 16);
        Bs[lk + 0][lr] = b0.x; Bs[lk + 1][lr] = b0.y; Bs[lk + 2][lr] = b0.z; Bs[lk + 3][lr] = b0.w;
        Bs[lk + 16][lr] = b1.x; Bs[lk + 17][lr] = b1.y; Bs[lk + 18][lr] = b1.z; Bs[lk + 19][lr] = b1.w;
        __syncthreads();
        #pragma unroll
        for (int kk = 0; kk < 32; kk++) {
            float a[4], bb[4];
            *(float4*)&a[0]  = *(const float4*)&As[kk][ty * 4];
            *(float4*)&bb[0] = *(const float4*)&Bs[kk][tx * 4];
            #pragma unroll
            for (int i = 0; i < 4; i++)
                #pragma unroll
                for (int j = 0; j < 4; j++) acc[i][j] = fmaf(a[i], bb[j], acc[i][j]);
        }
        __syncthreads();
    }
    #pragma unroll
    for (int i = 0; i < 4; i++)
        #pragma unroll
        for (int j = 0; j < 4; j++) {
            int r = r0 + ty * 4 + i, c = c0 + tx * 4 + j;
            float v = acc[i][j];
            if (r == c) v += EPSV;
            S[(size_t)b * 65536 + r * NH + c] = v;
        }
}

// scales[b] = 1/||S_b||_F ; scales[16+b] = 1/sqrt(||S_b||_F)
__global__ void k_fro(const float* __restrict__ S, float* __restrict__ scales) {
    __shared__ float sb[8];
    const int b = blockIdx.x, t = threadIdx.x;
    const float* p = S + (size_t)b * 65536;
    float s = 0.f;
    for (int i = t; i < 65536; i += 256) { float v = p[i]; s = fmaf(v, v, s); }
    #pragma unroll
    for (int off = 32; off; off >>= 1) s += __shfl_down(s, off, 64);
    if ((t & 63) == 0) sb[t >> 6] = s;
    __syncthreads();
    if (t == 0) {
        float nrm = sqrtf(sb[0] + sb[1] + sb[2] + sb[3]);
        scales[b]      = 1.0f / nrm;
        scales[16 + b] = rsqrtf(nrm);
    }
}

__global__ void k_initB(float* __restrict__ B) {
    int i = blockIdx.x * 256 + threadIdx.x;
    int m = i & 65535;
    B[i] = ((m >> 8) == (m & 255)) ? 1.0f : 0.0f;
}

// Batched small NN matmul, M=256, tile 64x64, Ktile 32.
// mode 0: C = A@B ; mode 1: C = 1.5*C - 0.5*scale[b]*(A@B) ; mode 2: C = scale[b]*(A@B)
__global__ __launch_bounds__(256) void k_small_nn(const float* __restrict__ A0,
                                                  const float* __restrict__ B0,
                                                  float* __restrict__ C0,
                                                  int sA, int sB, int sC,
                                                  int K, int Ncols, int mode,
                                                  const float* __restrict__ scale) {
    const int b = blockIdx.z;
    const float* A = A0 + (size_t)b * sA;
    const float* Bm = B0 + (size_t)b * sB;
    float* C = C0 + (size_t)b * sC;
    const int r0 = blockIdx.y * 64, c0 = blockIdx.x * 64;
    __shared__ float As[32][76], Bs[32][76];
    const int t = threadIdx.x, tx = t & 15, ty = t >> 4;
    const int lr = t >> 2, lk = (t & 3) * 4;
    const int bk = t >> 3, bc = (t & 7) * 8;
    float acc[4][4] = {};
    for (int k0 = 0; k0 < K; k0 += 32) {
        float4 a0 = *(const float4*)(A + (size_t)(r0 + lr) * K + k0 + lk);
        float4 a1 = *(const float4*)(A + (size_t)(r0 + lr) * K + k0 + lk + 16);
        As[lk + 0][lr] = a0.x; As[lk + 1][lr] = a0.y; As[lk + 2][lr] = a0.z; As[lk + 3][lr] = a0.w;
        As[lk + 16][lr] = a1.x; As[lk + 17][lr] = a1.y; As[lk + 18][lr] = a1.z; As[lk + 19][lr] = a1.w;
        float4 b0 = *(const float4*)(Bm + (size_t)(k0 + bk) * Ncols + c0 + bc);
        float4 b1 = *(const float4*)(Bm + (size_t)(k0 + bk) * Ncols + c0 + bc + 4);
        *(float4*)&Bs[bk][bc]     = b0;
        *(float4*)&Bs[bk][bc + 4] = b1;
        __syncthreads();
        #pragma unroll
        for (int kk = 0; kk < 32; kk++) {
            float a[4], bb[4];
            *(float4*)&a[0]  = *(const float4*)&As[kk][ty * 4];
            *(float4*)&bb[0] = *(const float4*)&Bs[kk][tx * 4];
            #pragma unroll
            for (int i = 0; i < 4; i++)
                #pragma unroll
                for (int j = 0; j < 4; j++) acc[i][j] = fmaf(a[i], bb[j], acc[i][j]);
        }
        __syncthreads();
    }
    #pragma unroll
    for (int i = 0; i < 4; i++)
        #pragma unroll
        for (int j = 0; j < 4; j++) {
            size_t idx = (size_t)(r0 + ty * 4 + i) * Ncols + c0 + tx * 4 + j;
            if (mode == 0) C[idx] = acc[i][j];
            else if (mode == 1) C[idx] = 1.5f * C[idx] - 0.5f * scale[b] * acc[i][j];
            else C[idx] = scale[b] * acc[i][j];
        }
}

// ---------------------------------------------------------------- big matmuls

// h = h0 = relu(X @ W^T + bias), X [100000 x 512], W [256 x 512]
__global__ __launch_bounds__(256) void k_fc0(const float* __restrict__ X,
                                             const float* __restrict__ W,
                                             const float* __restrict__ bias,
                                             float* __restrict__ h, float* __restrict__ h0) {
    __shared__ float As[16][132], Bs[16][132];
    const int t = threadIdx.x, tx = t & 15, ty = t >> 4;
    const int r0 = blockIdx.y * 128, c0 = blockIdx.x * 128;
    const int lr = t >> 1, lk = (t & 1) * 8;
    float acc[8][8] = {};
    for (int k0 = 0; k0 < NF; k0 += 16) {
        int gr = r0 + lr; if (gr > NNODES - 1) gr = NNODES - 1;
        float4 a0 = *(const float4*)(X + (size_t)gr * NF + k0 + lk);
        float4 a1 = *(const float4*)(X + (size_t)gr * NF + k0 + lk + 4);
        As[lk + 0][lr] = a0.x; As[lk + 1][lr] = a0.y; As[lk + 2][lr] = a0.z; As[lk + 3][lr] = a0.w;
        As[lk + 4][lr] = a1.x; As[lk + 5][lr] = a1.y; As[lk + 6][lr] = a1.z; As[lk + 7][lr] = a1.w;
        float4 b0 = *(const float4*)(W + (size_t)(c0 + lr) * NF + k0 + lk);
        float4 b1 = *(const float4*)(W + (size_t)(c0 + lr) * NF + k0 + lk + 4);
        Bs[lk + 0][lr] = b0.x; Bs[lk + 1][lr] = b0.y; Bs[lk + 2][lr] = b0.z; Bs[lk + 3][lr] = b0.w;
        Bs[lk + 4][lr] = b1.x; Bs[lk + 5][lr] = b1.y; Bs[lk + 6][lr] = b1.z; Bs[lk + 7][lr] = b1.w;
        __syncthreads();
        #pragma unroll
        for (int kk = 0; kk < 16; kk++) {
            float a[8], bb[8];
            *(float4*)&a[0]  = *(const float4*)&As[kk][ty * 8];
            *(float4*)&a[4]  = *(const float4*)&As[kk][ty * 8 + 4];
            *(float4*)&bb[0] = *(const float4*)&Bs[kk][tx * 8];
            *(float4*)&bb[4] = *(const float4*)&Bs[kk][tx * 8 + 4];
            #pragma unroll
            for (int i = 0; i < 8; i++)
                #pragma unroll
                for (int j = 0; j < 8; j++) acc[i][j] = fmaf(a[i], bb[j], acc[i][j]);
        }
        __syncthreads();
    }
    float bv[8];
    #pragma unroll
    for (int j = 0; j < 8; j++) bv[j] = bias[c0 + tx * 8 + j];
    #pragma unroll
    for (int i = 0; i < 8; i++) {
        int gr = r0 + ty * 8 + i;
        if (gr >= NNODES) continue;
        size_t base = (size_t)gr * NH + c0 + tx * 8;
        float4 o0, o1;
        o0.x = fmaxf(acc[i][0] + bv[0], 0.f); o0.y = fmaxf(acc[i][1] + bv[1], 0.f);
        o0.z = fmaxf(acc[i][2] + bv[2], 0.f); o0.w = fmaxf(acc[i][3] + bv[3], 0.f);
        o1.x = fmaxf(acc[i][4] + bv[4], 0.f); o1.y = fmaxf(acc[i][5] + bv[5], 0.f);
        o1.z = fmaxf(acc[i][6] + bv[6], 0.f); o1.w = fmaxf(acc[i][7] + bv[7], 0.f);
        *(float4*)(h + base) = o0;  *(float4*)(h + base + 4) = o1;
        *(float4*)(h0 + base) = o0; *(float4*)(h0 + base + 4) = o1;
    }
}

// Hout = relu(theta*(Sup@T) + (1-theta)*Sup), Sup [100000 x 256], T [256 x 256]
__global__ __launch_bounds__(256) void k_layer(const float* __restrict__ Sup,
                                               const float* __restrict__ T,
                                               float* __restrict__ Hout, float theta) {
    __shared__ float As[16][132], Bs[16][132];
    const int t = threadIdx.x, tx = t & 15, ty = t >> 4;
    const int r0 = blockIdx.y * 128, c0 = blockIdx.x * 128;
    const int lr = t >> 1, lk = (t & 1) * 8;
    const int bk = t >> 4, bc = (t & 15) * 8;
    float acc[8][8] = {};
    for (int k0 = 0; k0 < NH; k0 += 16) {
        int gr = r0 + lr; if (gr > NNODES - 1) gr = NNODES - 1;
        float4 a0 = *(const float4*)(Sup + (size_t)gr * NH + k0 + lk);
        float4 a1 = *(const float4*)(Sup + (size_t)gr * NH + k0 + lk + 4);
        As[lk + 0][lr] = a0.x; As[lk + 1][lr] = a0.y; As[lk + 2][lr] = a0.z; As[lk + 3][lr] = a0.w;
        As[lk + 4][lr] = a1.x; As[lk + 5][lr] = a1.y; As[lk + 6][lr] = a1.z; As[lk + 7][lr] = a1.w;
        float4 b0 = *(const float4*)(T + (size_t)(k0 + bk) * NH + c0 + bc);
        float4 b1 = *(const float4*)(T + (size_t)(k0 + bk) * NH + c0 + bc + 4);
        *(float4*)&Bs[bk][bc]     = b0;
        *(float4*)&Bs[bk][bc + 4] = b1;
        __syncthreads();
        #pragma unroll
        for (int kk = 0; kk < 16; kk++) {
            float a[8], bb[8];
            *(float4*)&a[0]  = *(const float4*)&As[kk][ty * 8];
            *(float4*)&a[4]  = *(const float4*)&As[kk][ty * 8 + 4];
            *(float4*)&bb[0] = *(const float4*)&Bs[kk][tx * 8];
            *(float4*)&bb[4] = *(const float4*)&Bs[kk][tx * 8 + 4];
            #pragma unroll
            for (int i = 0; i < 8; i++)
                #pragma unroll
                for (int j = 0; j < 8; j++) acc[i][j] = fmaf(a[i], bb[j], acc[i][j]);
        }
        __syncthreads();
    }
    const float mtheta = 1.0f - theta;
    #pragma unroll
    for (int i = 0; i < 8; i++) {
        int gr = r0 + ty * 8 + i;
        if (gr >= NNODES) continue;
        size_t base = (size_t)gr * NH + c0 + tx * 8;
        float4 s0 = *(const float4*)(Sup + base);
        float4 s1 = *(const float4*)(Sup + base + 4);
        float4 o0, o1;
        o0.x = fmaxf(fmaf(theta, acc[i][0], mtheta * s0.x), 0.f);
        o0.y = fmaxf(fmaf(theta, acc[i][1], mtheta * s0.y), 0.f);
        o0.z = fmaxf(fmaf(theta, acc[i][2], mtheta * s0.z), 0.f);
        o0.w = fmaxf(fmaf(theta, acc[i][3], mtheta * s0.w), 0.f);
        o1.x = fmaxf(fmaf(theta, acc[i][4], mtheta * s1.x), 0.f);
        o1.y = fmaxf(fmaf(theta, acc[i][5], mtheta * s1.y), 0.f);
        o1.z = fmaxf(fmaf(theta, acc[i][6], mtheta * s1.z), 0.f);
        o1.w = fmaxf(fmaf(theta, acc[i][7], mtheta * s1.w), 0.f);
        *(float4*)(Hout + base) = o0; *(float4*)(Hout + base + 4) = o1;
    }
}

// ---------------------------------------------------------------- SpMM

// support[d,:] = 0.9 * sum_{e: dst=d} w_e * h[src_e,:] + 0.1 * h0[d,:]
__global__ __launch_bounds__(256) void k_spmm(const int* __restrict__ rstart,
                                              const int* __restrict__ counts,
                                              const int* __restrict__ ssrc,
                                              const float* __restrict__ sw,
                                              const float* __restrict__ h,
                                              const float* __restrict__ h0,
                                              float* __restrict__ support) {
    const int node = blockIdx.x, f = threadIdx.x;
    const int start = rstart[node], deg = counts[node];
    __shared__ int s_src[256];
    __shared__ float s_w[256];
    float acc = 0.f;
    for (int base = 0; base < deg; base += 256) {
        int j = base + f;
        if (j < deg) { s_src[f] = ssrc[start + j]; s_w[f] = sw[start + j]; }
        __syncthreads();
        int m = deg - base; if (m > 256) m = 256;
        int e = 0;
        for (; e + 4 <= m; e += 4) {
            int   i0 = s_src[e], i1 = s_src[e + 1], i2 = s_src[e + 2], i3 = s_src[e + 3];
            float w0 = s_w[e], w1 = s_w[e + 1], w2 = s_w[e + 2], w3 = s_w[e + 3];
            float v0 = h[(size_t)i0 * NH + f];
            float v1 = h[(size_t)i1 * NH + f];
            float v2 = h[(size_t)i2 * NH + f];
            float v3 = h[(size_t)i3 * NH + f];
            acc = fmaf(w0, v0, acc); acc = fmaf(w1, v1, acc);
            acc = fmaf(w2, v2, acc); acc = fmaf(w3, v3, acc);
        }
        for (; e < m; e++) acc = fmaf(s_w[e], h[(size_t)s_src[e] * NH + f], acc);
        __syncthreads();
    }
    size_t idx = (size_t)node * NH + f;
    support[idx] = fmaf(0.9f, acc, 0.1f * h0[idx]);
}

// ---------------------------------------------------------------- logits + log_softmax

__global__ __launch_bounds__(128) void k_logits(const float* __restrict__ h,
                                                const float* __restrict__ W1,
                                                const float* __restrict__ b1,
                                                float* __restrict__ out, int nrows) {
    __shared__ float hs[16][260];
    __shared__ float Ws[40][260];
    __shared__ float ls[16][44];
    __shared__ float lse[16];
    const int t = threadIdx.x;
    const int row0 = blockIdx.x * 16;
    for (int i = t; i < 40 * 64; i += 128) {
        int c = i >> 6, k4 = i & 63;
        *(float4*)&Ws[c][k4 * 4] = *(const float4*)(W1 + (size_t)c * NH + k4 * 4);
    }
    for (int i = t; i < 16 * 64; i += 128) {
        int r = i >> 6, k4 = i & 63;
        int gr = row0 + r;
        float4 v = make_float4(0.f, 0.f, 0.f, 0.f);
        if (gr < nrows) v = *(const float4*)(h + (size_t)gr * NH + k4 * 4);
        *(float4*)&hs[r][k4 * 4] = v;
    }
    __syncthreads();
    const int r = t & 15, cg = t >> 4;   // cg in 0..7, 5 classes each
    float acc[5];
    #pragma unroll
    for (int j = 0; j < 5; j++) acc[j] = b1[cg * 5 + j];
    for (int k = 0; k < NH; k++) {
        float hv = hs[r][k];
        #pragma unroll
        for (int j = 0; j < 5; j++) acc[j] = fmaf(hv, Ws[cg * 5 + j][k], acc[j]);
    }
    #pragma unroll
    for (int j = 0; j < 5; j++) ls[r][cg * 5 + j] = acc[j];
    __syncthreads();
    if (t < 16) {
        float m = -3.4e38f;
        for (int c = 0; c < NC; c++) m = fmaxf(m, ls[t][c]);
        float s = 0.f;
        for (int c = 0; c < NC; c++) s += expf(ls[t][c] - m);
        lse[t] = m + logf(s);
    }
    __syncthreads();
    for (int i = t; i < 16 * NC; i += 128) {
        int r2 = i / NC, c = i % NC;
        int gr = row0 + r2;
        if (gr < nrows) out[(size_t)gr * NC + c] = ls[r2][c] - lse[r2];
    }
}

// ---------------------------------------------------------------- launch

extern "C" void kernel_launch(void* const* d_in, const int* in_sizes, int n_in,
                              void* d_out, int out_size, void* d_ws, size_t ws_size,
                              hipStream_t stream) {
    const float* x      = (const float*)d_in[0];
    const int*   e_src  = (const int*)d_in[1];
    const int*   e_dst  = (const int*)d_in[2];
    const float* e_w    = (const float*)d_in[3];
    const float* W0     = (const float*)d_in[4];
    const float* b0     = (const float*)d_in[5];
    const float* convW  = (const float*)d_in[6];
    const float* W1     = (const float*)d_in[7];
    const float* b1     = (const float*)d_in[8];
    float* out = (float*)d_out;

    char* ws = (char*)d_ws;
    // workspace layout (bytes), total ~349 MB
    const size_t OFF_H0     = 0;                                // 102,400,000
    const size_t OFF_H      = OFF_H0 + (size_t)NNODES * NH * 4;
    const size_t OFF_SUP    = OFF_H + (size_t)NNODES * NH * 4;
    const size_t OFF_SSRC   = OFF_SUP + (size_t)NNODES * NH * 4;
    const size_t OFF_SW     = OFF_SSRC + (size_t)NEDGE * 4;
    const size_t OFF_RSTART = OFF_SW + (size_t)NEDGE * 4;
    const size_t OFF_COUNTS = OFF_RSTART + (size_t)NNODES * 4;
    const size_t OFF_CURSOR = OFF_COUNTS + (size_t)NNODES * 4;
    const size_t OFF_BSUM   = OFF_CURSOR + (size_t)NNODES * 4;
    const size_t OFF_ZC0    = OFF_BSUM + 1024;
    const size_t OFF_ZCC    = OFF_ZC0 + 256 * 512 * 4;
    const size_t OFF_S      = OFF_ZCC + 8 * 65536 * 4;
    const size_t OFF_B      = OFF_S + 9 * 65536 * 4;
    const size_t OFF_T1     = OFF_B + 9 * 65536 * 4;
    const size_t OFF_T2     = OFF_T1 + 9 * 65536 * 4;
    const size_t OFF_T      = OFF_T2 + 9 * 65536 * 4;
    const size_t OFF_W0O    = OFF_T + 8 * 65536 * 4;
    const size_t OFF_SCALES = OFF_W0O + 256 * 512 * 4;

    float* h0     = (float*)(ws + OFF_H0);
    float* h      = (float*)(ws + OFF_H);
    float* sup    = (float*)(ws + OFF_SUP);
    int*   ssrc   = (int*)(ws + OFF_SSRC);
    float* sw     = (float*)(ws + OFF_SW);
    int*   rstart = (int*)(ws + OFF_RSTART);
    int*   counts = (int*)(ws + OFF_COUNTS);
    int*   cursor = (int*)(ws + OFF_CURSOR);
    int*   bsum   = (int*)(ws + OFF_BSUM);
    float* Zc0    = (float*)(ws + OFF_ZC0);
    float* ZcC    = (float*)(ws + OFF_ZCC);
    float* Smat   = (float*)(ws + OFF_S);
    float* Bb     = (float*)(ws + OFF_B);
    float* T1b    = (float*)(ws + OFF_T1);
    float* T2b    = (float*)(ws + OFF_T2);
    float* tbuf   = (float*)(ws + OFF_T);
    float* W0o    = (float*)(ws + OFF_W0O);
    float* scales = (float*)(ws + OFF_SCALES);

    (void)in_sizes; (void)n_in; (void)out_size; (void)ws_size;

    // ---- CSR build (per call; ws is re-poisoned by harness)
    hipMemsetAsync(counts, 0, (size_t)NNODES * 4, stream);
    hipMemsetAsync(cursor, 0, (size_t)NNODES * 4, stream);
    k_hist<<<(NEDGE + 255) / 256, 256, 0, stream>>>(e_dst, counts, NEDGE);
    const int NB = (NNODES + 1023) / 1024;   // 98
    k_scan1<<<NB, 1024, 0, stream>>>(counts, rstart, bsum, NNODES);
    k_scan2<<<1, 128, 0, stream>>>(bsum, NB);
    k_scan3<<<NB, 1024, 0, stream>>>(rstart, bsum, NNODES);
    k_scatter<<<(NEDGE + 255) / 256, 256, 0, stream>>>(e_src, e_dst, e_w, rstart, cursor,
                                                       ssrc, sw, NEDGE);

    // ---- ortho: batched Newton-Schulz for W0 (b=0) + 8 conv weights (b=1..8)
    k_zc0<<<256, 256, 0, stream>>>(W0, Zc0);
    k_zcC<<<8 * 256, 256, 0, stream>>>(convW, ZcC);
    k_gram<<<dim3(4, 4, 9), 256, 0, stream>>>(Zc0, ZcC, Smat);
    k_fro<<<9, 256, 0, stream>>>(Smat, scales);
    k_initB<<<9 * 256, 256, 0, stream>>>(Bb);
    for (int it = 0; it < 5; it++) {
        k_small_nn<<<dim3(4, 4, 9), 256, 0, stream>>>(Bb, Bb, T1b, 65536, 65536, 65536,
                                                      256, 256, 0, nullptr);
        k_small_nn<<<dim3(4, 4, 9), 256, 0, stream>>>(T1b, Bb, T2b, 65536, 65536, 65536,
                                                      256, 256, 0, nullptr);
        k_small_nn<<<dim3(4, 4, 9), 256, 0, stream>>>(T2b, Smat, Bb, 65536, 65536, 65536,
                                                      256, 256, 1, scales);
    }
    // W0o = (B0 @ Zc0) * rsqn[0]   [256 x 512]
    k_small_nn<<<dim3(8, 4, 1), 256, 0, stream>>>(Bb, Zc0, W0o, 0, 0, 0,
                                                  256, 512, 2, scales + 16);
    // t[g] = (B[g+1] @ ZcC[g]) * rsqn[g+1]   [8 x 256 x 256]
    k_small_nn<<<dim3(4, 4, 8), 256, 0, stream>>>(Bb + 65536, ZcC, tbuf, 65536, 65536, 65536,
                                                  256, 256, 2, scales + 17);

    // ---- fc0: h = h0 = relu(x @ W0o^T + b0)
    k_fc0<<<dim3(2, 782), 256, 0, stream>>>(x, W0o, b0, h, h0);

    // ---- 8 GCNII layers
    for (int l = 1; l <= NLAY; l++) {
        k_spmm<<<NNODES, 256, 0, stream>>>(rstart, counts, ssrc, sw, h, h0, sup);
        float theta = logf(0.5f / (float)l + 1.0f);
        k_layer<<<dim3(2, 782), 256, 0, stream>>>(sup, tbuf + (size_t)(l - 1) * 65536, h, theta);
    }

    // ---- logits + log_softmax
    k_logits<<<NNODES / 16, 128, 0, stream>>>(h, W1, b1, out, NNODES);
}

// Round 2
// 4680.613 us; speedup vs baseline: 1.3652x; 1.3652x over previous
//
#include <hip/hip_runtime.h>
#include <math.h>

// Problem constants (fixed by reference)
#define NNODES 100000
#define NEDGE  3200000
#define NF     512
#define NH     256
#define NC     40
#define NLAY   8
#define EPSV   1e-5f

// ---------------------------------------------------------------- utilities

__device__ __forceinline__ float block_sum_256(float v) {
    __shared__ float sb[8];
    #pragma unroll
    for (int off = 32; off; off >>= 1) v += __shfl_down(v, off, 64);
    if ((threadIdx.x & 63) == 0) sb[threadIdx.x >> 6] = v;
    __syncthreads();
    return sb[0] + sb[1] + sb[2] + sb[3];
}

// round-to-nearest-even f32 -> bf16 (as ushort)
__device__ __forceinline__ unsigned int pack_bf2(float a, float b) {
    unsigned int ua = __float_as_uint(a), ub = __float_as_uint(b);
    ua = (ua + 0x7fffu + ((ua >> 16) & 1u)) >> 16;
    ub = (ub + 0x7fffu + ((ub >> 16) & 1u)) & 0xffff0000u;
    return ua | ub;
}

// ---------------------------------------------------------------- CSR build

__global__ void k_hist(const int* __restrict__ dst, int* __restrict__ counts, int n) {
    int i = blockIdx.x * 256 + threadIdx.x;
    if (i < n) atomicAdd(&counts[dst[i]], 1);
}

__global__ void k_scan1(const int* __restrict__ in, int* __restrict__ out,
                        int* __restrict__ bsum, int n) {
    __shared__ int s[1024];
    int t = threadIdx.x, g = blockIdx.x * 1024 + t;
    int v = (g < n) ? in[g] : 0;
    s[t] = v; __syncthreads();
    for (int off = 1; off < 1024; off <<= 1) {
        int u = (t >= off) ? s[t - off] : 0;
        __syncthreads();
        s[t] += u;
        __syncthreads();
    }
    if (g < n) out[g] = s[t] - v;           // exclusive
    if (t == 1023) bsum[blockIdx.x] = s[1023];
}

__global__ void k_scan2(int* __restrict__ bsum, int nb) {
    __shared__ int s[128];
    int t = threadIdx.x;
    int v = (t < nb) ? bsum[t] : 0;
    s[t] = v; __syncthreads();
    for (int off = 1; off < 128; off <<= 1) {
        int u = (t >= off) ? s[t - off] : 0;
        __syncthreads();
        s[t] += u;
        __syncthreads();
    }
    if (t < nb) bsum[t] = s[t] - v;         // exclusive
}

__global__ void k_scan3(int* __restrict__ out, const int* __restrict__ bsum, int n) {
    int g = blockIdx.x * 1024 + threadIdx.x;
    if (g < n) out[g] += bsum[blockIdx.x];
}

// pack (src, weight-bits) interleaved for single ds_read_b64 broadcast later
__global__ void k_scatter(const int* __restrict__ src, const int* __restrict__ dst,
                          const float* __restrict__ w, const int* __restrict__ rstart,
                          int* __restrict__ cursor, int2* __restrict__ epack, int n) {
    int i = blockIdx.x * 256 + threadIdx.x;
    if (i < n) {
        int d = dst[i];
        int pos = rstart[d] + atomicAdd(&cursor[d], 1);
        epack[pos] = make_int2(src[i], __float_as_int(w[i]));
    }
}

// ---------------------------------------------------------------- ortho prep

// Zc0 = W0 - rowmean(W0), [256 x 512]. One block per row.
__global__ void k_zc0(const float* __restrict__ W0, float* __restrict__ Zc0) {
    int r = blockIdx.x, t = threadIdx.x;
    float a = W0[r * NF + t];
    float b = W0[r * NF + 256 + t];
    float mean = block_sum_256(a + b) * (1.0f / 512.0f);
    Zc0[r * NF + t]       = a - mean;
    Zc0[r * NF + 256 + t] = b - mean;
}

// we = 0.5*convW + 0.5*I; ZcC[g] = we - rowmean(we). One block per (g,row).
__global__ void k_zcC(const float* __restrict__ convW, float* __restrict__ ZcC) {
    int g = blockIdx.x >> 8, r = blockIdx.x & 255, t = threadIdx.x;
    float v = 0.5f * convW[((size_t)g * NH + r) * NH + t] + ((r == t) ? 0.5f : 0.0f);
    float mean = block_sum_256(v) * (1.0f / 256.0f);
    ZcC[((size_t)g * NH + r) * NH + t] = v - mean;
}

// S[b] = Zc[b] @ Zc[b]^T + EPS*I   (b=0: Zc0 K=512; b>0: ZcC[b-1] K=256)
__global__ __launch_bounds__(256) void k_gram(const float* __restrict__ Zc0,
                                              const float* __restrict__ ZcC,
                                              float* __restrict__ S) {
    const int b = blockIdx.z;
    const float* A = (b == 0) ? Zc0 : (ZcC + (size_t)(b - 1) * 65536);
    const int K = (b == 0) ? 512 : 256;
    const int r0 = blockIdx.y * 64, c0 = blockIdx.x * 64;
    __shared__ float As[32][76], Bs[32][76];
    const int t = threadIdx.x, tx = t & 15, ty = t >> 4;
    const int lr = t >> 2, lk = (t & 3) * 4;
    float acc[4][4] = {};
    for (int k0 = 0; k0 < K; k0 += 32) {
        float4 a0 = *(const float4*)(A + (size_t)(r0 + lr) * K + k0 + lk);
        float4 a1 = *(const float4*)(A + (size_t)(r0 + lr) * K + k0 + lk + 16);
        As[lk + 0][lr] = a0.x; As[lk + 1][lr] = a0.y; As[lk + 2][lr] = a0.z; As[lk + 3][lr] = a0.w;
        As[lk + 16][lr] = a1.x; As[lk + 17][lr] = a1.y; As[lk + 18][lr] = a1.z; As[lk + 19][lr] = a1.w;
        float4 b0 = *(const float4*)(A + (size_t)(c0 + lr) * K + k0 + lk);
        float4 b1 = *(const float4*)(A + (size_t)(c0 + lr) * K + k0 + lk + 16);
        Bs[lk + 0][lr] = b0.x; Bs[lk + 1][lr] = b0.y; Bs[lk + 2][lr] = b0.z; Bs[lk + 3][lr] = b0.w;
        Bs[lk + 16][lr] = b1.x; Bs[lk + 17][lr] = b1.y; Bs[lk + 18][lr] = b1.z; Bs[lk + 19][lr] = b1.w;
        __syncthreads();
        #pragma unroll
        for (int kk = 0; kk < 32; kk++) {
            float a[4], bb[4];
            *(float4*)&a[0]  = *(const float4*)&As[kk][ty * 4];
            *(float4*)&bb[0] = *(const float4*)&Bs[kk][tx * 4];
            #pragma unroll
            for (int i = 0; i < 4; i++)
                #pragma unroll
                for (int j = 0; j < 4; j++) acc[i][j] = fmaf(a[i], bb[j], acc[i][j]);
        }
        __syncthreads();
    }
    #pragma unroll
    for (int i = 0; i < 4; i++)
        #pragma unroll
        for (int j = 0; j < 4; j++) {
            int r = r0 + ty * 4 + i, c = c0 + tx * 4 + j;
            float v = acc[i][j];
            if (r == c) v += EPSV;
            S[(size_t)b * 65536 + r * NH + c] = v;
        }
}

// scales[b] = 1/||S_b||_F ; scales[16+b] = 1/sqrt(||S_b||_F)
__global__ void k_fro(const float* __restrict__ S, float* __restrict__ scales) {
    __shared__ float sb[8];
    const int b = blockIdx.x, t = threadIdx.x;
    const float* p = S + (size_t)b * 65536;
    float s = 0.f;
    for (int i = t; i < 65536; i += 256) { float v = p[i]; s = fmaf(v, v, s); }
    #pragma unroll
    for (int off = 32; off; off >>= 1) s += __shfl_down(s, off, 64);
    if ((t & 63) == 0) sb[t >> 6] = s;
    __syncthreads();
    if (t == 0) {
        float nrm = sqrtf(sb[0] + sb[1] + sb[2] + sb[3]);
        scales[b]      = 1.0f / nrm;
        scales[16 + b] = rsqrtf(nrm);
    }
}

__global__ void k_initB(float* __restrict__ B) {
    int i = blockIdx.x * 256 + threadIdx.x;
    int m = i & 65535;
    B[i] = ((m >> 8) == (m & 255)) ? 1.0f : 0.0f;
}

// Batched small NN matmul, M=256, tile 64x64, Ktile 32.
// mode 0: C = A@B ; mode 1: C = 1.5*C - 0.5*scale[b]*(A@B) ; mode 2: C = scale[b]*(A@B)
__global__ __launch_bounds__(256) void k_small_nn(const float* __restrict__ A0,
                                                  const float* __restrict__ B0,
                                                  float* __restrict__ C0,
                                                  int sA, int sB, int sC,
                                                  int K, int Ncols, int mode,
                                                  const float* __restrict__ scale) {
    const int b = blockIdx.z;
    const float* A = A0 + (size_t)b * sA;
    const float* Bm = B0 + (size_t)b * sB;
    float* C = C0 + (size_t)b * sC;
    const int r0 = blockIdx.y * 64, c0 = blockIdx.x * 64;
    __shared__ float As[32][76], Bs[32][76];
    const int t = threadIdx.x, tx = t & 15, ty = t >> 4;
    const int lr = t >> 2, lk = (t & 3) * 4;
    const int bk = t >> 3, bc = (t & 7) * 8;
    float acc[4][4] = {};
    for (int k0 = 0; k0 < K; k0 += 32) {
        float4 a0 = *(const float4*)(A + (size_t)(r0 + lr) * K + k0 + lk);
        float4 a1 = *(const float4*)(A + (size_t)(r0 + lr) * K + k0 + lk + 16);
        As[lk + 0][lr] = a0.x; As[lk + 1][lr] = a0.y; As[lk + 2][lr] = a0.z; As[lk + 3][lr] = a0.w;
        As[lk + 16][lr] = a1.x; As[lk + 17][lr] = a1.y; As[lk + 18][lr] = a1.z; As[lk + 19][lr] = a1.w;
        float4 b0 = *(const float4*)(Bm + (size_t)(k0 + bk) * Ncols + c0 + bc);
        float4 b1 = *(const float4*)(Bm + (size_t)(k0 + bk) * Ncols + c0 + bc + 4);
        *(float4*)&Bs[bk][bc]     = b0;
        *(float4*)&Bs[bk][bc + 4] = b1;
        __syncthreads();
        #pragma unroll
        for (int kk = 0; kk < 32; kk++) {
            float a[4], bb[4];
            *(float4*)&a[0]  = *(const float4*)&As[kk][ty * 4];
            *(float4*)&bb[0] = *(const float4*)&Bs[kk][tx * 4];
            #pragma unroll
            for (int i = 0; i < 4; i++)
                #pragma unroll
                for (int j = 0; j < 4; j++) acc[i][j] = fmaf(a[i], bb[j], acc[i][j]);
        }
        __syncthreads();
    }
    #pragma unroll
    for (int i = 0; i < 4; i++)
        #pragma unroll
        for (int j = 0; j < 4; j++) {
            size_t idx = (size_t)(r0 + ty * 4 + i) * Ncols + c0 + tx * 4 + j;
            if (mode == 0) C[idx] = acc[i][j];
            else if (mode == 1) C[idx] = 1.5f * C[idx] - 0.5f * scale[b] * acc[i][j];
            else C[idx] = scale[b] * acc[i][j];
        }
}

// ---------------------------------------------------------------- big matmuls

// relu(X @ W^T + bias) -> h0 (fp32) and hbf (bf16 gather copy)
__global__ __launch_bounds__(256) void k_fc0(const float* __restrict__ X,
                                             const float* __restrict__ W,
                                             const float* __restrict__ bias,
                                             float* __restrict__ h0,
                                             unsigned short* __restrict__ hbf) {
    __shared__ float As[16][132], Bs[16][132];
    const int t = threadIdx.x, tx = t & 15, ty = t >> 4;
    const int r0 = blockIdx.y * 128, c0 = blockIdx.x * 128;
    const int lr = t >> 1, lk = (t & 1) * 8;
    float acc[8][8] = {};
    for (int k0 = 0; k0 < NF; k0 += 16) {
        int gr = r0 + lr; if (gr > NNODES - 1) gr = NNODES - 1;
        float4 a0 = *(const float4*)(X + (size_t)gr * NF + k0 + lk);
        float4 a1 = *(const float4*)(X + (size_t)gr * NF + k0 + lk + 4);
        As[lk + 0][lr] = a0.x; As[lk + 1][lr] = a0.y; As[lk + 2][lr] = a0.z; As[lk + 3][lr] = a0.w;
        As[lk + 4][lr] = a1.x; As[lk + 5][lr] = a1.y; As[lk + 6][lr] = a1.z; As[lk + 7][lr] = a1.w;
        float4 b0 = *(const float4*)(W + (size_t)(c0 + lr) * NF + k0 + lk);
        float4 b1 = *(const float4*)(W + (size_t)(c0 + lr) * NF + k0 + lk + 4);
        Bs[lk + 0][lr] = b0.x; Bs[lk + 1][lr] = b0.y; Bs[lk + 2][lr] = b0.z; Bs[lk + 3][lr] = b0.w;
        Bs[lk + 4][lr] = b1.x; Bs[lk + 5][lr] = b1.y; Bs[lk + 6][lr] = b1.z; Bs[lk + 7][lr] = b1.w;
        __syncthreads();
        #pragma unroll
        for (int kk = 0; kk < 16; kk++) {
            float a[8], bb[8];
            *(float4*)&a[0]  = *(const float4*)&As[kk][ty * 8];
            *(float4*)&a[4]  = *(const float4*)&As[kk][ty * 8 + 4];
            *(float4*)&bb[0] = *(const float4*)&Bs[kk][tx * 8];
            *(float4*)&bb[4] = *(const float4*)&Bs[kk][tx * 8 + 4];
            #pragma unroll
            for (int i = 0; i < 8; i++)
                #pragma unroll
                for (int j = 0; j < 8; j++) acc[i][j] = fmaf(a[i], bb[j], acc[i][j]);
        }
        __syncthreads();
    }
    float bv[8];
    #pragma unroll
    for (int j = 0; j < 8; j++) bv[j] = bias[c0 + tx * 8 + j];
    #pragma unroll
    for (int i = 0; i < 8; i++) {
        int gr = r0 + ty * 8 + i;
        if (gr >= NNODES) continue;
        size_t base = (size_t)gr * NH + c0 + tx * 8;
        float o[8];
        #pragma unroll
        for (int j = 0; j < 8; j++) o[j] = fmaxf(acc[i][j] + bv[j], 0.f);
        *(float4*)(h0 + base)     = *(float4*)&o[0];
        *(float4*)(h0 + base + 4) = *(float4*)&o[4];
        uint4 p;
        p.x = pack_bf2(o[0], o[1]); p.y = pack_bf2(o[2], o[3]);
        p.z = pack_bf2(o[4], o[5]); p.w = pack_bf2(o[6], o[7]);
        *(uint4*)(hbf + base) = p;
    }
}

// Hout = relu(theta*(Sup@T) + (1-theta)*Sup)
// out_f32 (layer 8, for logits) and/or out_bf (layers 1..7, gather copy) may be null.
__global__ __launch_bounds__(256) void k_layer(const float* __restrict__ Sup,
                                               const float* __restrict__ T,
                                               float* __restrict__ out_f32,
                                               unsigned short* __restrict__ out_bf,
                                               float theta) {
    __shared__ float As[16][132], Bs[16][132];
    const int t = threadIdx.x, tx = t & 15, ty = t >> 4;
    const int r0 = blockIdx.y * 128, c0 = blockIdx.x * 128;
    const int lr = t >> 1, lk = (t & 1) * 8;
    const int bk = t >> 4, bc = (t & 15) * 8;
    float acc[8][8] = {};
    for (int k0 = 0; k0 < NH; k0 += 16) {
        int gr = r0 + lr; if (gr > NNODES - 1) gr = NNODES - 1;
        float4 a0 = *(const float4*)(Sup + (size_t)gr * NH + k0 + lk);
        float4 a1 = *(const float4*)(Sup + (size_t)gr * NH + k0 + lk + 4);
        As[lk + 0][lr] = a0.x; As[lk + 1][lr] = a0.y; As[lk + 2][lr] = a0.z; As[lk + 3][lr] = a0.w;
        As[lk + 4][lr] = a1.x; As[lk + 5][lr] = a1.y; As[lk + 6][lr] = a1.z; As[lk + 7][lr] = a1.w;
        float4 b0 = *(const float4*)(T + (size_t)(k0 + bk) * NH + c0 + bc);
        float4 b1 = *(const float4*)(T + (size_t)(k0 + bk) * NH + c0 + bc + 4);
        *(float4*)&Bs[bk][bc]     = b0;
        *(float4*)&Bs[bk][bc + 4] = b1;
        __syncthreads();
        #pragma unroll
        for (int kk = 0; kk < 16; kk++) {
            float a[8], bb[8];
            *(float4*)&a[0]  = *(const float4*)&As[kk][ty * 8];
            *(float4*)&a[4]  = *(const float4*)&As[kk][ty * 8 + 4];
            *(float4*)&bb[0] = *(const float4*)&Bs[kk][tx * 8];
            *(float4*)&bb[4] = *(const float4*)&Bs[kk][tx * 8 + 4];
            #pragma unroll
            for (int i = 0; i < 8; i++)
                #pragma unroll
                for (int j = 0; j < 8; j++) acc[i][j] = fmaf(a[i], bb[j], acc[i][j]);
        }
        __syncthreads();
    }
    const float mtheta = 1.0f - theta;
    #pragma unroll
    for (int i = 0; i < 8; i++) {
        int gr = r0 + ty * 8 + i;
        if (gr >= NNODES) continue;
        size_t base = (size_t)gr * NH + c0 + tx * 8;
        float4 s0 = *(const float4*)(Sup + base);
        float4 s1 = *(const float4*)(Sup + base + 4);
        float o[8];
        o[0] = fmaxf(fmaf(theta, acc[i][0], mtheta * s0.x), 0.f);
        o[1] = fmaxf(fmaf(theta, acc[i][1], mtheta * s0.y), 0.f);
        o[2] = fmaxf(fmaf(theta, acc[i][2], mtheta * s0.z), 0.f);
        o[3] = fmaxf(fmaf(theta, acc[i][3], mtheta * s0.w), 0.f);
        o[4] = fmaxf(fmaf(theta, acc[i][4], mtheta * s1.x), 0.f);
        o[5] = fmaxf(fmaf(theta, acc[i][5], mtheta * s1.y), 0.f);
        o[6] = fmaxf(fmaf(theta, acc[i][6], mtheta * s1.z), 0.f);
        o[7] = fmaxf(fmaf(theta, acc[i][7], mtheta * s1.w), 0.f);
        if (out_f32) {
            *(float4*)(out_f32 + base)     = *(float4*)&o[0];
            *(float4*)(out_f32 + base + 4) = *(float4*)&o[4];
        }
        if (out_bf) {
            uint4 p;
            p.x = pack_bf2(o[0], o[1]); p.y = pack_bf2(o[2], o[3]);
            p.z = pack_bf2(o[4], o[5]); p.w = pack_bf2(o[6], o[7]);
            *(uint4*)(out_bf + base) = p;
        }
    }
}

// ---------------------------------------------------------------- SpMM

// One wave per dst node; lane owns 4 features (8B bf16 gather per lane).
// support[d,:] = 0.9 * sum_e w_e * hbf[src_e,:] + 0.1 * h0[d,:]
__global__ __launch_bounds__(256) void k_spmm(const int* __restrict__ rstart,
                                              const int* __restrict__ counts,
                                              const int2* __restrict__ epack,
                                              const unsigned short* __restrict__ hbf,
                                              const float* __restrict__ h0,
                                              float* __restrict__ support) {
    __shared__ int2 se[4][64];
    const int wv = threadIdx.x >> 6, lane = threadIdx.x & 63;
    const int node = blockIdx.x * 4 + wv;
    const int start = rstart[node], deg = counts[node];
    float a0 = 0.f, a1 = 0.f, a2 = 0.f, a3 = 0.f;
    for (int base = 0; base < deg; base += 64) {
        int j = base + lane;
        if (j < deg) se[wv][lane] = epack[start + j];
        int m = deg - base; if (m > 64) m = 64;
        for (int e = 0; e < m; e++) {
            int2 ed = se[wv][e];                       // LDS broadcast, conflict-free
            float w = __int_as_float(ed.y);
            uint2 v = *(const uint2*)(hbf + ((size_t)ed.x << 8) + (lane << 2));
            a0 = fmaf(w, __uint_as_float(v.x << 16), a0);
            a1 = fmaf(w, __uint_as_float(v.x & 0xffff0000u), a1);
            a2 = fmaf(w, __uint_as_float(v.y << 16), a2);
            a3 = fmaf(w, __uint_as_float(v.y & 0xffff0000u), a3);
        }
    }
    size_t idx = ((size_t)node << 8) + (lane << 2);
    float4 r = *(const float4*)(h0 + idx);
    float4 o;
    o.x = fmaf(0.9f, a0, 0.1f * r.x);
    o.y = fmaf(0.9f, a1, 0.1f * r.y);
    o.z = fmaf(0.9f, a2, 0.1f * r.z);
    o.w = fmaf(0.9f, a3, 0.1f * r.w);
    *(float4*)(support + idx) = o;
}

// ---------------------------------------------------------------- logits + log_softmax

__global__ __launch_bounds__(128) void k_logits(const float* __restrict__ h,
                                                const float* __restrict__ W1,
                                                const float* __restrict__ b1,
                                                float* __restrict__ out, int nrows) {
    __shared__ float hs[16][260];
    __shared__ float Ws[40][260];
    __shared__ float ls[16][44];
    __shared__ float lse[16];
    const int t = threadIdx.x;
    const int row0 = blockIdx.x * 16;
    for (int i = t; i < 40 * 64; i += 128) {
        int c = i >> 6, k4 = i & 63;
        *(float4*)&Ws[c][k4 * 4] = *(const float4*)(W1 + (size_t)c * NH + k4 * 4);
    }
    for (int i = t; i < 16 * 64; i += 128) {
        int r = i >> 6, k4 = i & 63;
        int gr = row0 + r;
        float4 v = make_float4(0.f, 0.f, 0.f, 0.f);
        if (gr < nrows) v = *(const float4*)(h + (size_t)gr * NH + k4 * 4);
        *(float4*)&hs[r][k4 * 4] = v;
    }
    __syncthreads();
    const int r = t & 15, cg = t >> 4;   // cg in 0..7, 5 classes each
    float acc[5];
    #pragma unroll
    for (int j = 0; j < 5; j++) acc[j] = b1[cg * 5 + j];
    for (int k = 0; k < NH; k++) {
        float hv = hs[r][k];
        #pragma unroll
        for (int j = 0; j < 5; j++) acc[j] = fmaf(hv, Ws[cg * 5 + j][k], acc[j]);
    }
    #pragma unroll
    for (int j = 0; j < 5; j++) ls[r][cg * 5 + j] = acc[j];
    __syncthreads();
    if (t < 16) {
        float m = -3.4e38f;
        for (int c = 0; c < NC; c++) m = fmaxf(m, ls[t][c]);
        float s = 0.f;
        for (int c = 0; c < NC; c++) s += expf(ls[t][c] - m);
        lse[t] = m + logf(s);
    }
    __syncthreads();
    for (int i = t; i < 16 * NC; i += 128) {
        int r2 = i / NC, c = i % NC;
        int gr = row0 + r2;
        if (gr < nrows) out[(size_t)gr * NC + c] = ls[r2][c] - lse[r2];
    }
}

// ---------------------------------------------------------------- launch

extern "C" void kernel_launch(void* const* d_in, const int* in_sizes, int n_in,
                              void* d_out, int out_size, void* d_ws, size_t ws_size,
                              hipStream_t stream) {
    const float* x      = (const float*)d_in[0];
    const int*   e_src  = (const int*)d_in[1];
    const int*   e_dst  = (const int*)d_in[2];
    const float* e_w    = (const float*)d_in[3];
    const float* W0     = (const float*)d_in[4];
    const float* b0     = (const float*)d_in[5];
    const float* convW  = (const float*)d_in[6];
    const float* W1     = (const float*)d_in[7];
    const float* b1     = (const float*)d_in[8];
    float* out = (float*)d_out;

    char* ws = (char*)d_ws;
    // workspace layout (bytes)
    const size_t OFF_H0     = 0;                                    // fp32 [N,256] 102.4 MB
    const size_t OFF_H      = OFF_H0 + (size_t)NNODES * NH * 4;     // fp32 [N,256] (layer-8 out)
    const size_t OFF_SUP    = OFF_H + (size_t)NNODES * NH * 4;      // fp32 [N,256]
    const size_t OFF_HBF    = OFF_SUP + (size_t)NNODES * NH * 4;    // bf16 [N,256] 51.2 MB
    const size_t OFF_EPACK  = OFF_HBF + (size_t)NNODES * NH * 2;    // int2 [E] 25.6 MB
    const size_t OFF_RSTART = OFF_EPACK + (size_t)NEDGE * 8;
    const size_t OFF_COUNTS = OFF_RSTART + (size_t)NNODES * 4;
    const size_t OFF_CURSOR = OFF_COUNTS + (size_t)NNODES * 4;
    const size_t OFF_BSUM   = OFF_CURSOR + (size_t)NNODES * 4;
    const size_t OFF_ZC0    = OFF_BSUM + 1024;
    const size_t OFF_ZCC    = OFF_ZC0 + 256 * 512 * 4;
    const size_t OFF_S      = OFF_ZCC + 8 * 65536 * 4;
    const size_t OFF_B      = OFF_S + 9 * 65536 * 4;
    const size_t OFF_T1     = OFF_B + 9 * 65536 * 4;
    const size_t OFF_T2     = OFF_T1 + 9 * 65536 * 4;
    const size_t OFF_T      = OFF_T2 + 9 * 65536 * 4;
    const size_t OFF_W0O    = OFF_T + 8 * 65536 * 4;
    const size_t OFF_SCALES = OFF_W0O + 256 * 512 * 4;

    float*  h0     = (float*)(ws + OFF_H0);
    float*  h      = (float*)(ws + OFF_H);
    float*  sup    = (float*)(ws + OFF_SUP);
    unsigned short* hbf = (unsigned short*)(ws + OFF_HBF);
    int2*   epack  = (int2*)(ws + OFF_EPACK);
    int*    rstart = (int*)(ws + OFF_RSTART);
    int*    counts = (int*)(ws + OFF_COUNTS);
    int*    cursor = (int*)(ws + OFF_CURSOR);
    int*    bsum   = (int*)(ws + OFF_BSUM);
    float*  Zc0    = (float*)(ws + OFF_ZC0);
    float*  ZcC    = (float*)(ws + OFF_ZCC);
    float*  Smat   = (float*)(ws + OFF_S);
    float*  Bb     = (float*)(ws + OFF_B);
    float*  T1b    = (float*)(ws + OFF_T1);
    float*  T2b    = (float*)(ws + OFF_T2);
    float*  tbuf   = (float*)(ws + OFF_T);
    float*  W0o    = (float*)(ws + OFF_W0O);
    float*  scales = (float*)(ws + OFF_SCALES);

    (void)in_sizes; (void)n_in; (void)out_size; (void)ws_size;

    // ---- CSR build (per call; ws is re-poisoned by harness)
    hipMemsetAsync(counts, 0, (size_t)NNODES * 4, stream);
    hipMemsetAsync(cursor, 0, (size_t)NNODES * 4, stream);
    k_hist<<<(NEDGE + 255) / 256, 256, 0, stream>>>(e_dst, counts, NEDGE);
    const int NB = (NNODES + 1023) / 1024;   // 98
    k_scan1<<<NB, 1024, 0, stream>>>(counts, rstart, bsum, NNODES);
    k_scan2<<<1, 128, 0, stream>>>(bsum, NB);
    k_scan3<<<NB, 1024, 0, stream>>>(rstart, bsum, NNODES);
    k_scatter<<<(NEDGE + 255) / 256, 256, 0, stream>>>(e_src, e_dst, e_w, rstart, cursor,
                                                       epack, NEDGE);

    // ---- ortho: batched Newton-Schulz for W0 (b=0) + 8 conv weights (b=1..8)
    k_zc0<<<256, 256, 0, stream>>>(W0, Zc0);
    k_zcC<<<8 * 256, 256, 0, stream>>>(convW, ZcC);
    k_gram<<<dim3(4, 4, 9), 256, 0, stream>>>(Zc0, ZcC, Smat);
    k_fro<<<9, 256, 0, stream>>>(Smat, scales);
    k_initB<<<9 * 256, 256, 0, stream>>>(Bb);
    for (int it = 0; it < 5; it++) {
        k_small_nn<<<dim3(4, 4, 9), 256, 0, stream>>>(Bb, Bb, T1b, 65536, 65536, 65536,
                                                      256, 256, 0, nullptr);
        k_small_nn<<<dim3(4, 4, 9), 256, 0, stream>>>(T1b, Bb, T2b, 65536, 65536, 65536,
                                                      256, 256, 0, nullptr);
        k_small_nn<<<dim3(4, 4, 9), 256, 0, stream>>>(T2b, Smat, Bb, 65536, 65536, 65536,
                                                      256, 256, 1, scales);
    }
    // W0o = (B0 @ Zc0) * rsqn[0]   [256 x 512]
    k_small_nn<<<dim3(8, 4, 1), 256, 0, stream>>>(Bb, Zc0, W0o, 0, 0, 0,
                                                  256, 512, 2, scales + 16);
    // t[g] = (B[g+1] @ ZcC[g]) * rsqn[g+1]   [8 x 256 x 256]
    k_small_nn<<<dim3(4, 4, 8), 256, 0, stream>>>(Bb + 65536, ZcC, tbuf, 65536, 65536, 65536,
                                                  256, 256, 2, scales + 17);

    // ---- fc0: h0 (fp32) + hbf (bf16 gather copy) = relu(x @ W0o^T + b0)
    k_fc0<<<dim3(2, 782), 256, 0, stream>>>(x, W0o, b0, h0, hbf);

    // ---- 8 GCNII layers
    for (int l = 1; l <= NLAY; l++) {
        k_spmm<<<NNODES / 4, 256, 0, stream>>>(rstart, counts, epack, hbf, h0, sup);
        float theta = logf(0.5f / (float)l + 1.0f);
        float* of = (l == NLAY) ? h : nullptr;
        unsigned short* ob = (l == NLAY) ? nullptr : hbf;
        k_layer<<<dim3(2, 782), 256, 0, stream>>>(sup, tbuf + (size_t)(l - 1) * 65536,
                                                  of, ob, theta);
    }

    // ---- logits + log_softmax
    k_logits<<<NNODES / 16, 128, 0, stream>>>(h, W1, b1, out, NNODES);
}

// Round 3
// 3558.451 us; speedup vs baseline: 1.7957x; 1.3154x over previous
//
#include <hip/hip_runtime.h>
#include <math.h>

// Problem constants (fixed by reference)
#define NNODES 100000
#define NEDGE  3200000
#define NF     512
#define NH     256
#define NC     40
#define NLAY   8
#define EPSV   1e-5f

typedef __attribute__((ext_vector_type(8))) short short8;   // 8 bf16 (4 VGPRs)
typedef __attribute__((ext_vector_type(4))) float floatx4;  // MFMA acc

// ---------------------------------------------------------------- utilities

__device__ __forceinline__ float block_sum_256(float v) {
    __shared__ float sb[8];
    #pragma unroll
    for (int off = 32; off; off >>= 1) v += __shfl_down(v, off, 64);
    if ((threadIdx.x & 63) == 0) sb[threadIdx.x >> 6] = v;
    __syncthreads();
    return sb[0] + sb[1] + sb[2] + sb[3];
}

// round-to-nearest-even f32 -> bf16
__device__ __forceinline__ unsigned short bf16_rte(float a) {
    unsigned int u = __float_as_uint(a);
    return (unsigned short)((u + 0x7fffu + ((u >> 16) & 1u)) >> 16);
}
__device__ __forceinline__ unsigned int pack_bf2(float a, float b) {
    unsigned int ua = __float_as_uint(a), ub = __float_as_uint(b);
    ua = (ua + 0x7fffu + ((ua >> 16) & 1u)) >> 16;
    ub = (ub + 0x7fffu + ((ub >> 16) & 1u)) & 0xffff0000u;
    return ua | ub;
}

// ---------------------------------------------------------------- CSR build

__global__ void k_hist(const int* __restrict__ dst, int* __restrict__ counts, int n) {
    int i = blockIdx.x * 256 + threadIdx.x;
    if (i < n) atomicAdd(&counts[dst[i]], 1);
}

__global__ void k_scan1(const int* __restrict__ in, int* __restrict__ out,
                        int* __restrict__ bsum, int n) {
    __shared__ int s[1024];
    int t = threadIdx.x, g = blockIdx.x * 1024 + t;
    int v = (g < n) ? in[g] : 0;
    s[t] = v; __syncthreads();
    for (int off = 1; off < 1024; off <<= 1) {
        int u = (t >= off) ? s[t - off] : 0;
        __syncthreads();
        s[t] += u;
        __syncthreads();
    }
    if (g < n) out[g] = s[t] - v;           // exclusive
    if (t == 1023) bsum[blockIdx.x] = s[1023];
}

__global__ void k_scan2(int* __restrict__ bsum, int nb) {
    __shared__ int s[128];
    int t = threadIdx.x;
    int v = (t < nb) ? bsum[t] : 0;
    s[t] = v; __syncthreads();
    for (int off = 1; off < 128; off <<= 1) {
        int u = (t >= off) ? s[t - off] : 0;
        __syncthreads();
        s[t] += u;
        __syncthreads();
    }
    if (t < nb) bsum[t] = s[t] - v;         // exclusive
}

__global__ void k_scan3(int* __restrict__ out, const int* __restrict__ bsum, int n) {
    int g = blockIdx.x * 1024 + threadIdx.x;
    if (g < n) out[g] += bsum[blockIdx.x];
}

// pack (src, weight-bits) interleaved for single ds_read_b64 broadcast later
__global__ void k_scatter(const int* __restrict__ src, const int* __restrict__ dst,
                          const float* __restrict__ w, const int* __restrict__ rstart,
                          int* __restrict__ cursor, int2* __restrict__ epack, int n) {
    int i = blockIdx.x * 256 + threadIdx.x;
    if (i < n) {
        int d = dst[i];
        int pos = rstart[d] + atomicAdd(&cursor[d], 1);
        epack[pos] = make_int2(src[i], __float_as_int(w[i]));
    }
}

// ---------------------------------------------------------------- ortho prep

__global__ void k_zc0(const float* __restrict__ W0, float* __restrict__ Zc0) {
    int r = blockIdx.x, t = threadIdx.x;
    float a = W0[r * NF + t];
    float b = W0[r * NF + 256 + t];
    float mean = block_sum_256(a + b) * (1.0f / 512.0f);
    Zc0[r * NF + t]       = a - mean;
    Zc0[r * NF + 256 + t] = b - mean;
}

__global__ void k_zcC(const float* __restrict__ convW, float* __restrict__ ZcC) {
    int g = blockIdx.x >> 8, r = blockIdx.x & 255, t = threadIdx.x;
    float v = 0.5f * convW[((size_t)g * NH + r) * NH + t] + ((r == t) ? 0.5f : 0.0f);
    float mean = block_sum_256(v) * (1.0f / 256.0f);
    ZcC[((size_t)g * NH + r) * NH + t] = v - mean;
}

// S[b] = Zc[b] @ Zc[b]^T + EPS*I   (b=0: Zc0 K=512; b>0: ZcC[b-1] K=256)
__global__ __launch_bounds__(256) void k_gram(const float* __restrict__ Zc0,
                                              const float* __restrict__ ZcC,
                                              float* __restrict__ S) {
    const int b = blockIdx.z;
    const float* A = (b == 0) ? Zc0 : (ZcC + (size_t)(b - 1) * 65536);
    const int K = (b == 0) ? 512 : 256;
    const int r0 = blockIdx.y * 64, c0 = blockIdx.x * 64;
    __shared__ float As[32][76], Bs[32][76];
    const int t = threadIdx.x, tx = t & 15, ty = t >> 4;
    const int lr = t >> 2, lk = (t & 3) * 4;
    float acc[4][4] = {};
    for (int k0 = 0; k0 < K; k0 += 32) {
        float4 a0 = *(const float4*)(A + (size_t)(r0 + lr) * K + k0 + lk);
        float4 a1 = *(const float4*)(A + (size_t)(r0 + lr) * K + k0 + lk + 16);
        As[lk + 0][lr] = a0.x; As[lk + 1][lr] = a0.y; As[lk + 2][lr] = a0.z; As[lk + 3][lr] = a0.w;
        As[lk + 16][lr] = a1.x; As[lk + 17][lr] = a1.y; As[lk + 18][lr] = a1.z; As[lk + 19][lr] = a1.w;
        float4 b0 = *(const float4*)(A + (size_t)(c0 + lr) * K + k0 + lk);
        float4 b1 = *(const float4*)(A + (size_t)(c0 + lr) * K + k0 + lk + 16);
        Bs[lk + 0][lr] = b0.x; Bs[lk + 1][lr] = b0.y; Bs[lk + 2][lr] = b0.z; Bs[lk + 3][lr] = b0.w;
        Bs[lk + 16][lr] = b1.x; Bs[lk + 17][lr] = b1.y; Bs[lk + 18][lr] = b1.z; Bs[lk + 19][lr] = b1.w;
        __syncthreads();
        #pragma unroll
        for (int kk = 0; kk < 32; kk++) {
            float a[4], bb[4];
            *(float4*)&a[0]  = *(const float4*)&As[kk][ty * 4];
            *(float4*)&bb[0] = *(const float4*)&Bs[kk][tx * 4];
            #pragma unroll
            for (int i = 0; i < 4; i++)
                #pragma unroll
                for (int j = 0; j < 4; j++) acc[i][j] = fmaf(a[i], bb[j], acc[i][j]);
        }
        __syncthreads();
    }
    #pragma unroll
    for (int i = 0; i < 4; i++)
        #pragma unroll
        for (int j = 0; j < 4; j++) {
            int r = r0 + ty * 4 + i, c = c0 + tx * 4 + j;
            float v = acc[i][j];
            if (r == c) v += EPSV;
            S[(size_t)b * 65536 + r * NH + c] = v;
        }
}

__global__ void k_fro(const float* __restrict__ S, float* __restrict__ scales) {
    __shared__ float sb[8];
    const int b = blockIdx.x, t = threadIdx.x;
    const float* p = S + (size_t)b * 65536;
    float s = 0.f;
    for (int i = t; i < 65536; i += 256) { float v = p[i]; s = fmaf(v, v, s); }
    #pragma unroll
    for (int off = 32; off; off >>= 1) s += __shfl_down(s, off, 64);
    if ((t & 63) == 0) sb[t >> 6] = s;
    __syncthreads();
    if (t == 0) {
        float nrm = sqrtf(sb[0] + sb[1] + sb[2] + sb[3]);
        scales[b]      = 1.0f / nrm;
        scales[16 + b] = rsqrtf(nrm);
    }
}

__global__ void k_initB(float* __restrict__ B) {
    int i = blockIdx.x * 256 + threadIdx.x;
    int m = i & 65535;
    B[i] = ((m >> 8) == (m & 255)) ? 1.0f : 0.0f;
}

// Batched small NN matmul, M=256, tile 64x64, Ktile 32.
// mode 0: C = A@B ; mode 1: C = 1.5*C - 0.5*scale[b]*(A@B) ; mode 2: C = scale[b]*(A@B)
__global__ __launch_bounds__(256) void k_small_nn(const float* __restrict__ A0,
                                                  const float* __restrict__ B0,
                                                  float* __restrict__ C0,
                                                  int sA, int sB, int sC,
                                                  int K, int Ncols, int mode,
                                                  const float* __restrict__ scale) {
    const int b = blockIdx.z;
    const float* A = A0 + (size_t)b * sA;
    const float* Bm = B0 + (size_t)b * sB;
    float* C = C0 + (size_t)b * sC;
    const int r0 = blockIdx.y * 64, c0 = blockIdx.x * 64;
    __shared__ float As[32][76], Bs[32][76];
    const int t = threadIdx.x, tx = t & 15, ty = t >> 4;
    const int lr = t >> 2, lk = (t & 3) * 4;
    const int bk = t >> 3, bc = (t & 7) * 8;
    float acc[4][4] = {};
    for (int k0 = 0; k0 < K; k0 += 32) {
        float4 a0 = *(const float4*)(A + (size_t)(r0 + lr) * K + k0 + lk);
        float4 a1 = *(const float4*)(A + (size_t)(r0 + lr) * K + k0 + lk + 16);
        As[lk + 0][lr] = a0.x; As[lk + 1][lr] = a0.y; As[lk + 2][lr] = a0.z; As[lk + 3][lr] = a0.w;
        As[lk + 16][lr] = a1.x; As[lk + 17][lr] = a1.y; As[lk + 18][lr] = a1.z; As[lk + 19][lr] = a1.w;
        float4 b0 = *(const float4*)(Bm + (size_t)(k0 + bk) * Ncols + c0 + bc);
        float4 b1 = *(const float4*)(Bm + (size_t)(k0 + bk) * Ncols + c0 + bc + 4);
        *(float4*)&Bs[bk][bc]     = b0;
        *(float4*)&Bs[bk][bc + 4] = b1;
        __syncthreads();
        #pragma unroll
        for (int kk = 0; kk < 32; kk++) {
            float a[4], bb[4];
            *(float4*)&a[0]  = *(const float4*)&As[kk][ty * 4];
            *(float4*)&bb[0] = *(const float4*)&Bs[kk][tx * 4];
            #pragma unroll
            for (int i = 0; i < 4; i++)
                #pragma unroll
                for (int j = 0; j < 4; j++) acc[i][j] = fmaf(a[i], bb[j], acc[i][j]);
        }
        __syncthreads();
    }
    #pragma unroll
    for (int i = 0; i < 4; i++)
        #pragma unroll
        for (int j = 0; j < 4; j++) {
            size_t idx = (size_t)(r0 + ty * 4 + i) * Ncols + c0 + tx * 4 + j;
            if (mode == 0) C[idx] = acc[i][j];
            else if (mode == 1) C[idx] = 1.5f * C[idx] - 0.5f * scale[b] * acc[i][j];
            else C[idx] = scale[b] * acc[i][j];
        }
}

// ---------------------------------------------------------------- MFMA B-operand packing
// Fragment layouts (gfx950 mfma_f32_16x16x32_bf16):
//   A: lane holds A[m=lane&15][k=(lane>>4)*8 + j], j=0..7 (16B contiguous in k)
//   B: lane holds B[k=(lane>>4)*8 + j][n=lane&15]
//   C/D: col=lane&15, row=(lane>>4)*4 + reg
// Pack layout (per layer / per weight): [c=K/64][s=2][tg=16][lane=64][j=8] bf16
// -> per-chunk 32 KB contiguous, LDS staging is a flat uint4 copy.

// M_l = theta_l * t_l + (1-theta_l) * I, folded residual. 65536 threads per layer.
__global__ void k_prepM(const float* __restrict__ tbuf, unsigned short* __restrict__ Mpack) {
    int idx = blockIdx.x * 256 + threadIdx.x;   // [l][c][s][tg][lane] == flat order
    int lane = idx & 63;
    int tg   = (idx >> 6) & 15;
    int s    = (idx >> 10) & 1;
    int c    = (idx >> 11) & 3;
    int l    = idx >> 13;
    float theta = logf(0.5f / (float)(l + 1) + 1.0f);
    float mtheta = 1.0f - theta;
    int n  = tg * 16 + (lane & 15);
    int k0 = c * 64 + s * 32 + (lane >> 4) * 8;
    const float* T = tbuf + (size_t)l * 65536;
    unsigned short o[8];
    #pragma unroll
    for (int j = 0; j < 8; j++) {
        int k = k0 + j;
        float v = theta * T[(size_t)k * 256 + n] + ((k == n) ? mtheta : 0.0f);
        o[j] = bf16_rte(v);
    }
    *(uint4*)(Mpack + (size_t)idx * 8) = *(uint4*)o;
}

// B[k][n] = W0o[n][k]  (K=512, N=256). 16384 threads.
__global__ void k_prepW0(const float* __restrict__ W0o, unsigned short* __restrict__ Wpack) {
    int idx = blockIdx.x * 256 + threadIdx.x;
    int lane = idx & 63;
    int tg   = (idx >> 6) & 15;
    int s    = (idx >> 10) & 1;
    int c    = idx >> 11;                    // 0..7
    int n  = tg * 16 + (lane & 15);
    int k0 = c * 64 + s * 32 + (lane >> 4) * 8;
    const float* p = W0o + (size_t)n * NF + k0;   // contiguous in k
    unsigned short o[8];
    #pragma unroll
    for (int j = 0; j < 8; j++) o[j] = bf16_rte(p[j]);
    *(uint4*)(Wpack + (size_t)idx * 8) = *(uint4*)o;
}

// ---------------------------------------------------------------- MFMA GEMMs

// out = relu(Sbf @ M). Block = 64 rows x 256 cols, 4 waves (wave w: cols w*64).
// K=256 (4 chunks of 64). B staged per chunk (32 KB) from pre-packed Mpack.
__global__ __launch_bounds__(256) void k_gemm_layer(const unsigned short* __restrict__ Sbf,
                                                    const unsigned short* __restrict__ Mp,
                                                    float* __restrict__ out_f32,
                                                    unsigned short* __restrict__ out_bf) {
    __shared__ unsigned short Bs[2][16][64][8];   // 32 KB
    const int t = threadIdx.x, lane = t & 63, w = t >> 6;
    const int q = lane >> 4, m = lane & 15;
    const int r0 = blockIdx.x * 64;
    floatx4 acc[4][4] = {};
    for (int c = 0; c < 4; c++) {
        const uint4* src = (const uint4*)(Mp + (size_t)c * 16384);
        uint4* dst = (uint4*)&Bs[0][0][0][0];
        #pragma unroll
        for (int i = 0; i < 8; i++) dst[t + 256 * i] = src[t + 256 * i];
        __syncthreads();
        #pragma unroll
        for (int s = 0; s < 2; s++) {
            short8 afr[4];
            #pragma unroll
            for (int i = 0; i < 4; i++) {
                int row = r0 + i * 16 + m; if (row > NNODES - 1) row = NNODES - 1;
                afr[i] = *(const short8*)(Sbf + (size_t)row * NH + c * 64 + s * 32 + q * 8);
            }
            #pragma unroll
            for (int tg = 0; tg < 4; tg++) {
                short8 bfr = *(const short8*)&Bs[s][w * 4 + tg][lane][0];
                #pragma unroll
                for (int i = 0; i < 4; i++)
                    acc[i][tg] = __builtin_amdgcn_mfma_f32_16x16x32_bf16(afr[i], bfr, acc[i][tg], 0, 0, 0);
            }
        }
        __syncthreads();
    }
    #pragma unroll
    for (int i = 0; i < 4; i++) {
        #pragma unroll
        for (int tg = 0; tg < 4; tg++) {
            int col = w * 64 + tg * 16 + m;
            #pragma unroll
            for (int r = 0; r < 4; r++) {
                int row = r0 + i * 16 + q * 4 + r;
                if (row >= NNODES) continue;
                float v = fmaxf(acc[i][tg][r], 0.f);
                size_t idx = (size_t)row * NH + col;
                if (out_f32) out_f32[idx] = v;
                if (out_bf)  out_bf[idx] = bf16_rte(v);
            }
        }
    }
}

// h_bf = h0_bf = relu(x @ W0o^T + b0). A = fp32 x converted in-register. K=512 (8 chunks).
__global__ __launch_bounds__(256) void k_fc0_mfma(const float* __restrict__ X,
                                                  const unsigned short* __restrict__ Wp,
                                                  const float* __restrict__ bias,
                                                  unsigned short* __restrict__ hbf,
                                                  unsigned short* __restrict__ h0bf) {
    __shared__ unsigned short Bs[2][16][64][8];   // 32 KB
    const int t = threadIdx.x, lane = t & 63, w = t >> 6;
    const int q = lane >> 4, m = lane & 15;
    const int r0 = blockIdx.x * 64;
    floatx4 acc[4][4] = {};
    for (int c = 0; c < 8; c++) {
        const uint4* src = (const uint4*)(Wp + (size_t)c * 16384);
        uint4* dst = (uint4*)&Bs[0][0][0][0];
        #pragma unroll
        for (int i = 0; i < 8; i++) dst[t + 256 * i] = src[t + 256 * i];
        __syncthreads();
        #pragma unroll
        for (int s = 0; s < 2; s++) {
            short8 afr[4];
            #pragma unroll
            for (int i = 0; i < 4; i++) {
                int row = r0 + i * 16 + m; if (row > NNODES - 1) row = NNODES - 1;
                const float* p = X + (size_t)row * NF + c * 64 + s * 32 + q * 8;
                float4 xa = *(const float4*)p;
                float4 xb = *(const float4*)(p + 4);
                uint4 af;
                af.x = pack_bf2(xa.x, xa.y); af.y = pack_bf2(xa.z, xa.w);
                af.z = pack_bf2(xb.x, xb.y); af.w = pack_bf2(xb.z, xb.w);
                afr[i] = *(short8*)&af;
            }
            #pragma unroll
            for (int tg = 0; tg < 4; tg++) {
                short8 bfr = *(const short8*)&Bs[s][w * 4 + tg][lane][0];
                #pragma unroll
                for (int i = 0; i < 4; i++)
                    acc[i][tg] = __builtin_amdgcn_mfma_f32_16x16x32_bf16(afr[i], bfr, acc[i][tg], 0, 0, 0);
            }
        }
        __syncthreads();
    }
    #pragma unroll
    for (int i = 0; i < 4; i++) {
        #pragma unroll
        for (int tg = 0; tg < 4; tg++) {
            int col = w * 64 + tg * 16 + m;
            float bv = bias[col];
            #pragma unroll
            for (int r = 0; r < 4; r++) {
                int row = r0 + i * 16 + q * 4 + r;
                if (row >= NNODES) continue;
                unsigned short v = bf16_rte(fmaxf(acc[i][tg][r] + bv, 0.f));
                size_t idx = (size_t)row * NH + col;
                hbf[idx] = v;
                h0bf[idx] = v;
            }
        }
    }
}

// ---------------------------------------------------------------- SpMM

// One wave per dst node; lane owns 4 features (8B bf16 gather per lane).
// supbf[d,:] = bf16( 0.9 * sum_e w_e * hbf[src_e,:] + 0.1 * h0bf[d,:] )
__global__ __launch_bounds__(256) void k_spmm(const int* __restrict__ rstart,
                                              const int* __restrict__ counts,
                                              const int2* __restrict__ epack,
                                              const unsigned short* __restrict__ hbf,
                                              const unsigned short* __restrict__ h0bf,
                                              unsigned short* __restrict__ supbf) {
    __shared__ int2 se[4][64];
    const int wv = threadIdx.x >> 6, lane = threadIdx.x & 63;
    const int node = blockIdx.x * 4 + wv;
    const int start = rstart[node], deg = counts[node];
    float a0 = 0.f, a1 = 0.f, a2 = 0.f, a3 = 0.f;
    for (int base = 0; base < deg; base += 64) {
        int j = base + lane;
        if (j < deg) se[wv][lane] = epack[start + j];
        int m = deg - base; if (m > 64) m = 64;
        for (int e = 0; e < m; e++) {
            int2 ed = se[wv][e];                       // LDS broadcast, conflict-free
            float w = __int_as_float(ed.y);
            uint2 v = *(const uint2*)(hbf + ((size_t)ed.x << 8) + (lane << 2));
            a0 = fmaf(w, __uint_as_float(v.x << 16), a0);
            a1 = fmaf(w, __uint_as_float(v.x & 0xffff0000u), a1);
            a2 = fmaf(w, __uint_as_float(v.y << 16), a2);
            a3 = fmaf(w, __uint_as_float(v.y & 0xffff0000u), a3);
        }
    }
    size_t idx = ((size_t)node << 8) + (lane << 2);
    uint2 rv = *(const uint2*)(h0bf + idx);
    float o0 = fmaf(0.9f, a0, 0.1f * __uint_as_float(rv.x << 16));
    float o1 = fmaf(0.9f, a1, 0.1f * __uint_as_float(rv.x & 0xffff0000u));
    float o2 = fmaf(0.9f, a2, 0.1f * __uint_as_float(rv.y << 16));
    float o3 = fmaf(0.9f, a3, 0.1f * __uint_as_float(rv.y & 0xffff0000u));
    uint2 ov;
    ov.x = pack_bf2(o0, o1);
    ov.y = pack_bf2(o2, o3);
    *(uint2*)(supbf + idx) = ov;
}

// ---------------------------------------------------------------- logits + log_softmax

__global__ __launch_bounds__(128) void k_logits(const float* __restrict__ h,
                                                const float* __restrict__ W1,
                                                const float* __restrict__ b1,
                                                float* __restrict__ out, int nrows) {
    __shared__ float hs[16][260];
    __shared__ float Ws[40][260];
    __shared__ float ls[16][44];
    __shared__ float lse[16];
    const int t = threadIdx.x;
    const int row0 = blockIdx.x * 16;
    for (int i = t; i < 40 * 64; i += 128) {
        int c = i >> 6, k4 = i & 63;
        *(float4*)&Ws[c][k4 * 4] = *(const float4*)(W1 + (size_t)c * NH + k4 * 4);
    }
    for (int i = t; i < 16 * 64; i += 128) {
        int r = i >> 6, k4 = i & 63;
        int gr = row0 + r;
        float4 v = make_float4(0.f, 0.f, 0.f, 0.f);
        if (gr < nrows) v = *(const float4*)(h + (size_t)gr * NH + k4 * 4);
        *(float4*)&hs[r][k4 * 4] = v;
    }
    __syncthreads();
    const int r = t & 15, cg = t >> 4;   // cg in 0..7, 5 classes each
    float acc[5];
    #pragma unroll
    for (int j = 0; j < 5; j++) acc[j] = b1[cg * 5 + j];
    for (int k = 0; k < NH; k++) {
        float hv = hs[r][k];
        #pragma unroll
        for (int j = 0; j < 5; j++) acc[j] = fmaf(hv, Ws[cg * 5 + j][k], acc[j]);
    }
    #pragma unroll
    for (int j = 0; j < 5; j++) ls[r][cg * 5 + j] = acc[j];
    __syncthreads();
    if (t < 16) {
        float m = -3.4e38f;
        for (int c = 0; c < NC; c++) m = fmaxf(m, ls[t][c]);
        float s = 0.f;
        for (int c = 0; c < NC; c++) s += expf(ls[t][c] - m);
        lse[t] = m + logf(s);
    }
    __syncthreads();
    for (int i = t; i < 16 * NC; i += 128) {
        int r2 = i / NC, c = i % NC;
        int gr = row0 + r2;
        if (gr < nrows) out[(size_t)gr * NC + c] = ls[r2][c] - lse[r2];
    }
}

// ---------------------------------------------------------------- launch

extern "C" void kernel_launch(void* const* d_in, const int* in_sizes, int n_in,
                              void* d_out, int out_size, void* d_ws, size_t ws_size,
                              hipStream_t stream) {
    const float* x      = (const float*)d_in[0];
    const int*   e_src  = (const int*)d_in[1];
    const int*   e_dst  = (const int*)d_in[2];
    const float* e_w    = (const float*)d_in[3];
    const float* W0     = (const float*)d_in[4];
    const float* b0     = (const float*)d_in[5];
    const float* convW  = (const float*)d_in[6];
    const float* W1     = (const float*)d_in[7];
    const float* b1     = (const float*)d_in[8];
    float* out = (float*)d_out;

    char* ws = (char*)d_ws;
    // workspace layout (bytes)
    const size_t OFF_H      = 0;                                    // fp32 [N,256] layer-8 out
    const size_t OFF_HBF    = OFF_H + (size_t)NNODES * NH * 4;      // bf16 [N,256]
    const size_t OFF_H0BF   = OFF_HBF + (size_t)NNODES * NH * 2;    // bf16 [N,256]
    const size_t OFF_SUPBF  = OFF_H0BF + (size_t)NNODES * NH * 2;   // bf16 [N,256]
    const size_t OFF_EPACK  = OFF_SUPBF + (size_t)NNODES * NH * 2;  // int2 [E]
    const size_t OFF_RSTART = OFF_EPACK + (size_t)NEDGE * 8;
    const size_t OFF_COUNTS = OFF_RSTART + (size_t)NNODES * 4;
    const size_t OFF_CURSOR = OFF_COUNTS + (size_t)NNODES * 4;
    const size_t OFF_BSUM   = OFF_CURSOR + (size_t)NNODES * 4;
    const size_t OFF_ZC0    = OFF_BSUM + 1024;
    const size_t OFF_ZCC    = OFF_ZC0 + 256 * 512 * 4;
    const size_t OFF_S      = OFF_ZCC + 8 * 65536 * 4;
    const size_t OFF_B      = OFF_S + 9 * 65536 * 4;
    const size_t OFF_T1     = OFF_B + 9 * 65536 * 4;
    const size_t OFF_T2     = OFF_T1 + 9 * 65536 * 4;
    const size_t OFF_T      = OFF_T2 + 9 * 65536 * 4;
    const size_t OFF_W0O    = OFF_T + 8 * 65536 * 4;
    const size_t OFF_SCALES = OFF_W0O + 256 * 512 * 4;
    const size_t OFF_MPACK  = OFF_SCALES + 1024;                    // bf16 8*65536
    const size_t OFF_WPACK  = OFF_MPACK + 8 * 65536 * 2;            // bf16 512*256

    float*  h      = (float*)(ws + OFF_H);
    unsigned short* hbf   = (unsigned short*)(ws + OFF_HBF);
    unsigned short* h0bf  = (unsigned short*)(ws + OFF_H0BF);
    unsigned short* supbf = (unsigned short*)(ws + OFF_SUPBF);
    int2*   epack  = (int2*)(ws + OFF_EPACK);
    int*    rstart = (int*)(ws + OFF_RSTART);
    int*    counts = (int*)(ws + OFF_COUNTS);
    int*    cursor = (int*)(ws + OFF_CURSOR);
    int*    bsum   = (int*)(ws + OFF_BSUM);
    float*  Zc0    = (float*)(ws + OFF_ZC0);
    float*  ZcC    = (float*)(ws + OFF_ZCC);
    float*  Smat   = (float*)(ws + OFF_S);
    float*  Bb     = (float*)(ws + OFF_B);
    float*  T1b    = (float*)(ws + OFF_T1);
    float*  T2b    = (float*)(ws + OFF_T2);
    float*  tbuf   = (float*)(ws + OFF_T);
    float*  W0o    = (float*)(ws + OFF_W0O);
    float*  scales = (float*)(ws + OFF_SCALES);
    unsigned short* Mpack = (unsigned short*)(ws + OFF_MPACK);
    unsigned short* Wpack = (unsigned short*)(ws + OFF_WPACK);

    (void)in_sizes; (void)n_in; (void)out_size; (void)ws_size;

    // ---- CSR build (per call; ws is re-poisoned by harness)
    hipMemsetAsync(counts, 0, (size_t)NNODES * 4, stream);
    hipMemsetAsync(cursor, 0, (size_t)NNODES * 4, stream);
    k_hist<<<(NEDGE + 255) / 256, 256, 0, stream>>>(e_dst, counts, NEDGE);
    const int NB = (NNODES + 1023) / 1024;   // 98
    k_scan1<<<NB, 1024, 0, stream>>>(counts, rstart, bsum, NNODES);
    k_scan2<<<1, 128, 0, stream>>>(bsum, NB);
    k_scan3<<<NB, 1024, 0, stream>>>(rstart, bsum, NNODES);
    k_scatter<<<(NEDGE + 255) / 256, 256, 0, stream>>>(e_src, e_dst, e_w, rstart, cursor,
                                                       epack, NEDGE);

    // ---- ortho: batched Newton-Schulz for W0 (b=0) + 8 conv weights (b=1..8)
    k_zc0<<<256, 256, 0, stream>>>(W0, Zc0);
    k_zcC<<<8 * 256, 256, 0, stream>>>(convW, ZcC);
    k_gram<<<dim3(4, 4, 9), 256, 0, stream>>>(Zc0, ZcC, Smat);
    k_fro<<<9, 256, 0, stream>>>(Smat, scales);
    k_initB<<<9 * 256, 256, 0, stream>>>(Bb);
    for (int it = 0; it < 5; it++) {
        k_small_nn<<<dim3(4, 4, 9), 256, 0, stream>>>(Bb, Bb, T1b, 65536, 65536, 65536,
                                                      256, 256, 0, nullptr);
        k_small_nn<<<dim3(4, 4, 9), 256, 0, stream>>>(T1b, Bb, T2b, 65536, 65536, 65536,
                                                      256, 256, 0, nullptr);
        k_small_nn<<<dim3(4, 4, 9), 256, 0, stream>>>(T2b, Smat, Bb, 65536, 65536, 65536,
                                                      256, 256, 1, scales);
    }
    // W0o = (B0 @ Zc0) * rsqn[0]   [256 x 512]
    k_small_nn<<<dim3(8, 4, 1), 256, 0, stream>>>(Bb, Zc0, W0o, 0, 0, 0,
                                                  256, 512, 2, scales + 16);
    // t[g] = (B[g+1] @ ZcC[g]) * rsqn[g+1]   [8 x 256 x 256]
    k_small_nn<<<dim3(4, 4, 8), 256, 0, stream>>>(Bb + 65536, ZcC, tbuf, 65536, 65536, 65536,
                                                  256, 256, 2, scales + 17);

    // ---- pack B-operands for MFMA
    k_prepM<<<256, 256, 0, stream>>>(tbuf, Mpack);
    k_prepW0<<<64, 256, 0, stream>>>(W0o, Wpack);

    // ---- fc0 (MFMA): hbf = h0bf = relu(x @ W0o^T + b0)
    const int GB = (NNODES + 63) / 64;   // 1563
    k_fc0_mfma<<<GB, 256, 0, stream>>>(x, Wpack, b0, hbf, h0bf);

    // ---- 8 GCNII layers
    for (int l = 1; l <= NLAY; l++) {
        k_spmm<<<NNODES / 4, 256, 0, stream>>>(rstart, counts, epack, hbf, h0bf, supbf);
        float* of = (l == NLAY) ? h : nullptr;
        unsigned short* ob = (l == NLAY) ? nullptr : hbf;
        k_gemm_layer<<<GB, 256, 0, stream>>>(supbf, Mpack + (size_t)(l - 1) * 65536, of, ob);
    }

    // ---- logits + log_softmax
    k_logits<<<NNODES / 16, 128, 0, stream>>>(h, W1, b1, out, NNODES);
}

// Round 4
// 3467.426 us; speedup vs baseline: 1.8429x; 1.0263x over previous
//
#include <hip/hip_runtime.h>
#include <math.h>

// Problem constants (fixed by reference)
#define NNODES 100000
#define NEDGE  3200000
#define NF     512
#define NH     256
#define NC     40
#define NLAY   8
#define EPSV   1e-5f

typedef __attribute__((ext_vector_type(8))) short short8;   // 8 bf16 (4 VGPRs)
typedef __attribute__((ext_vector_type(4))) float floatx4;  // MFMA acc

// ---------------------------------------------------------------- utilities

__device__ __forceinline__ float block_sum_256(float v) {
    __shared__ float sb[8];
    #pragma unroll
    for (int off = 32; off; off >>= 1) v += __shfl_down(v, off, 64);
    if ((threadIdx.x & 63) == 0) sb[threadIdx.x >> 6] = v;
    __syncthreads();
    return sb[0] + sb[1] + sb[2] + sb[3];
}

// round-to-nearest-even f32 -> bf16
__device__ __forceinline__ unsigned short bf16_rte(float a) {
    unsigned int u = __float_as_uint(a);
    return (unsigned short)((u + 0x7fffu + ((u >> 16) & 1u)) >> 16);
}
__device__ __forceinline__ unsigned int pack_bf2(float a, float b) {
    unsigned int ua = __float_as_uint(a), ub = __float_as_uint(b);
    ua = (ua + 0x7fffu + ((ua >> 16) & 1u)) >> 16;
    ub = (ub + 0x7fffu + ((ub >> 16) & 1u)) & 0xffff0000u;
    return ua | ub;
}

// ---------------------------------------------------------------- CSR build

__global__ void k_hist(const int* __restrict__ dst, int* __restrict__ counts, int n) {
    int i = blockIdx.x * 256 + threadIdx.x;
    if (i < n) atomicAdd(&counts[dst[i]], 1);
}

__global__ void k_scan1(const int* __restrict__ in, int* __restrict__ out,
                        int* __restrict__ bsum, int n) {
    __shared__ int s[1024];
    int t = threadIdx.x, g = blockIdx.x * 1024 + t;
    int v = (g < n) ? in[g] : 0;
    s[t] = v; __syncthreads();
    for (int off = 1; off < 1024; off <<= 1) {
        int u = (t >= off) ? s[t - off] : 0;
        __syncthreads();
        s[t] += u;
        __syncthreads();
    }
    if (g < n) out[g] = s[t] - v;           // exclusive
    if (t == 1023) bsum[blockIdx.x] = s[1023];
}

__global__ void k_scan2(int* __restrict__ bsum, int nb) {
    __shared__ int s[128];
    int t = threadIdx.x;
    int v = (t < nb) ? bsum[t] : 0;
    s[t] = v; __syncthreads();
    for (int off = 1; off < 128; off <<= 1) {
        int u = (t >= off) ? s[t - off] : 0;
        __syncthreads();
        s[t] += u;
        __syncthreads();
    }
    if (t < nb) bsum[t] = s[t] - v;         // exclusive
}

__global__ void k_scan3(int* __restrict__ out, const int* __restrict__ bsum, int n) {
    int g = blockIdx.x * 1024 + threadIdx.x;
    if (g < n) out[g] += bsum[blockIdx.x];
}

// pack (src, weight-bits) interleaved for single ds_read_b64 broadcast later
__global__ void k_scatter(const int* __restrict__ src, const int* __restrict__ dst,
                          const float* __restrict__ w, const int* __restrict__ rstart,
                          int* __restrict__ cursor, int2* __restrict__ epack, int n) {
    int i = blockIdx.x * 256 + threadIdx.x;
    if (i < n) {
        int d = dst[i];
        int pos = rstart[d] + atomicAdd(&cursor[d], 1);
        epack[pos] = make_int2(src[i], __float_as_int(w[i]));
    }
}

// ---------------------------------------------------------------- ortho prep

__global__ void k_zc0(const float* __restrict__ W0, float* __restrict__ Zc0) {
    int r = blockIdx.x, t = threadIdx.x;
    float a = W0[r * NF + t];
    float b = W0[r * NF + 256 + t];
    float mean = block_sum_256(a + b) * (1.0f / 512.0f);
    Zc0[r * NF + t]       = a - mean;
    Zc0[r * NF + 256 + t] = b - mean;
}

__global__ void k_zcC(const float* __restrict__ convW, float* __restrict__ ZcC) {
    int g = blockIdx.x >> 8, r = blockIdx.x & 255, t = threadIdx.x;
    float v = 0.5f * convW[((size_t)g * NH + r) * NH + t] + ((r == t) ? 0.5f : 0.0f);
    float mean = block_sum_256(v) * (1.0f / 256.0f);
    ZcC[((size_t)g * NH + r) * NH + t] = v - mean;
}

// S[b] = Zc[b] @ Zc[b]^T + EPS*I   (b=0: Zc0 K=512; b>0: ZcC[b-1] K=256)
__global__ __launch_bounds__(256) void k_gram(const float* __restrict__ Zc0,
                                              const float* __restrict__ ZcC,
                                              float* __restrict__ S) {
    const int b = blockIdx.z;
    const float* A = (b == 0) ? Zc0 : (ZcC + (size_t)(b - 1) * 65536);
    const int K = (b == 0) ? 512 : 256;
    const int r0 = blockIdx.y * 64, c0 = blockIdx.x * 64;
    __shared__ float As[32][76], Bs[32][76];
    const int t = threadIdx.x, tx = t & 15, ty = t >> 4;
    const int lr = t >> 2, lk = (t & 3) * 4;
    float acc[4][4] = {};
    for (int k0 = 0; k0 < K; k0 += 32) {
        float4 a0 = *(const float4*)(A + (size_t)(r0 + lr) * K + k0 + lk);
        float4 a1 = *(const float4*)(A + (size_t)(r0 + lr) * K + k0 + lk + 16);
        As[lk + 0][lr] = a0.x; As[lk + 1][lr] = a0.y; As[lk + 2][lr] = a0.z; As[lk + 3][lr] = a0.w;
        As[lk + 16][lr] = a1.x; As[lk + 17][lr] = a1.y; As[lk + 18][lr] = a1.z; As[lk + 19][lr] = a1.w;
        float4 b0 = *(const float4*)(A + (size_t)(c0 + lr) * K + k0 + lk);
        float4 b1 = *(const float4*)(A + (size_t)(c0 + lr) * K + k0 + lk + 16);
        Bs[lk + 0][lr] = b0.x; Bs[lk + 1][lr] = b0.y; Bs[lk + 2][lr] = b0.z; Bs[lk + 3][lr] = b0.w;
        Bs[lk + 16][lr] = b1.x; Bs[lk + 17][lr] = b1.y; Bs[lk + 18][lr] = b1.z; Bs[lk + 19][lr] = b1.w;
        __syncthreads();
        #pragma unroll
        for (int kk = 0; kk < 32; kk++) {
            float a[4], bb[4];
            *(float4*)&a[0]  = *(const float4*)&As[kk][ty * 4];
            *(float4*)&bb[0] = *(const float4*)&Bs[kk][tx * 4];
            #pragma unroll
            for (int i = 0; i < 4; i++)
                #pragma unroll
                for (int j = 0; j < 4; j++) acc[i][j] = fmaf(a[i], bb[j], acc[i][j]);
        }
        __syncthreads();
    }
    #pragma unroll
    for (int i = 0; i < 4; i++)
        #pragma unroll
        for (int j = 0; j < 4; j++) {
            int r = r0 + ty * 4 + i, c = c0 + tx * 4 + j;
            float v = acc[i][j];
            if (r == c) v += EPSV;
            S[(size_t)b * 65536 + r * NH + c] = v;
        }
}

__global__ void k_fro(const float* __restrict__ S, float* __restrict__ scales) {
    __shared__ float sb[8];
    const int b = blockIdx.x, t = threadIdx.x;
    const float* p = S + (size_t)b * 65536;
    float s = 0.f;
    for (int i = t; i < 65536; i += 256) { float v = p[i]; s = fmaf(v, v, s); }
    #pragma unroll
    for (int off = 32; off; off >>= 1) s += __shfl_down(s, off, 64);
    if ((t & 63) == 0) sb[t >> 6] = s;
    __syncthreads();
    if (t == 0) {
        float nrm = sqrtf(sb[0] + sb[1] + sb[2] + sb[3]);
        scales[b]      = 1.0f / nrm;
        scales[16 + b] = rsqrtf(nrm);
    }
}

// B1 = 1.5*I - 0.5*invn*S  (closed-form first Newton-Schulz iteration)
__global__ void k_initB1(const float* __restrict__ S, const float* __restrict__ scales,
                         float* __restrict__ B) {
    int i = blockIdx.x * 256 + threadIdx.x;     // 9*65536
    int b = i >> 16, m = i & 65535;
    float v = -0.5f * scales[b] * S[i];
    if ((m >> 8) == (m & 255)) v += 1.5f;
    B[i] = v;
}

// Batch-18: b<9 -> T1[b] = B[b]@B[b] ; b>=9 -> T2[b-9] = B[b-9]@S[b-9]
// (B^3*S = (B^2)(B*S) by associativity; the two products are independent.)
__global__ __launch_bounds__(256) void k_ns_pair(const float* __restrict__ Bb,
                                                 const float* __restrict__ Smat,
                                                 float* __restrict__ T1b,
                                                 float* __restrict__ T2b) {
    const int b = blockIdx.z;
    const int bb = (b < 9) ? b : b - 9;
    const float* A  = Bb + (size_t)bb * 65536;
    const float* Bm = (b < 9) ? A : (Smat + (size_t)bb * 65536);
    float* C = (b < 9) ? (T1b + (size_t)bb * 65536) : (T2b + (size_t)bb * 65536);
    const int r0 = blockIdx.y * 64, c0 = blockIdx.x * 64;
    __shared__ float As[32][76], Bs[32][76];
    const int t = threadIdx.x, tx = t & 15, ty = t >> 4;
    const int lr = t >> 2, lk = (t & 3) * 4;
    const int bk = t >> 3, bc = (t & 7) * 8;
    float acc[4][4] = {};
    for (int k0 = 0; k0 < 256; k0 += 32) {
        float4 a0 = *(const float4*)(A + (size_t)(r0 + lr) * 256 + k0 + lk);
        float4 a1 = *(const float4*)(A + (size_t)(r0 + lr) * 256 + k0 + lk + 16);
        As[lk + 0][lr] = a0.x; As[lk + 1][lr] = a0.y; As[lk + 2][lr] = a0.z; As[lk + 3][lr] = a0.w;
        As[lk + 16][lr] = a1.x; As[lk + 17][lr] = a1.y; As[lk + 18][lr] = a1.z; As[lk + 19][lr] = a1.w;
        float4 b0 = *(const float4*)(Bm + (size_t)(k0 + bk) * 256 + c0 + bc);
        float4 b1 = *(const float4*)(Bm + (size_t)(k0 + bk) * 256 + c0 + bc + 4);
        *(float4*)&Bs[bk][bc]     = b0;
        *(float4*)&Bs[bk][bc + 4] = b1;
        __syncthreads();
        #pragma unroll
        for (int kk = 0; kk < 32; kk++) {
            float a[4], bb2[4];
            *(float4*)&a[0]   = *(const float4*)&As[kk][ty * 4];
            *(float4*)&bb2[0] = *(const float4*)&Bs[kk][tx * 4];
            #pragma unroll
            for (int i = 0; i < 4; i++)
                #pragma unroll
                for (int j = 0; j < 4; j++) acc[i][j] = fmaf(a[i], bb2[j], acc[i][j]);
        }
        __syncthreads();
    }
    #pragma unroll
    for (int i = 0; i < 4; i++)
        #pragma unroll
        for (int j = 0; j < 4; j++)
            C[(size_t)(r0 + ty * 4 + i) * 256 + c0 + tx * 4 + j] = acc[i][j];
}

// Batched small NN matmul, M=256, tile 64x64, Ktile 32.
// mode 1: C = 1.5*C - 0.5*scale[b]*(A@B) ; mode 2: C = scale[b]*(A@B)
__global__ __launch_bounds__(256) void k_small_nn(const float* __restrict__ A0,
                                                  const float* __restrict__ B0,
                                                  float* __restrict__ C0,
                                                  int sA, int sB, int sC,
                                                  int K, int Ncols, int mode,
                                                  const float* __restrict__ scale) {
    const int b = blockIdx.z;
    const float* A = A0 + (size_t)b * sA;
    const float* Bm = B0 + (size_t)b * sB;
    float* C = C0 + (size_t)b * sC;
    const int r0 = blockIdx.y * 64, c0 = blockIdx.x * 64;
    __shared__ float As[32][76], Bs[32][76];
    const int t = threadIdx.x, tx = t & 15, ty = t >> 4;
    const int lr = t >> 2, lk = (t & 3) * 4;
    const int bk = t >> 3, bc = (t & 7) * 8;
    float acc[4][4] = {};
    for (int k0 = 0; k0 < K; k0 += 32) {
        float4 a0 = *(const float4*)(A + (size_t)(r0 + lr) * K + k0 + lk);
        float4 a1 = *(const float4*)(A + (size_t)(r0 + lr) * K + k0 + lk + 16);
        As[lk + 0][lr] = a0.x; As[lk + 1][lr] = a0.y; As[lk + 2][lr] = a0.z; As[lk + 3][lr] = a0.w;
        As[lk + 16][lr] = a1.x; As[lk + 17][lr] = a1.y; As[lk + 18][lr] = a1.z; As[lk + 19][lr] = a1.w;
        float4 b0 = *(const float4*)(Bm + (size_t)(k0 + bk) * Ncols + c0 + bc);
        float4 b1 = *(const float4*)(Bm + (size_t)(k0 + bk) * Ncols + c0 + bc + 4);
        *(float4*)&Bs[bk][bc]     = b0;
        *(float4*)&Bs[bk][bc + 4] = b1;
        __syncthreads();
        #pragma unroll
        for (int kk = 0; kk < 32; kk++) {
            float a[4], bb[4];
            *(float4*)&a[0]  = *(const float4*)&As[kk][ty * 4];
            *(float4*)&bb[0] = *(const float4*)&Bs[kk][tx * 4];
            #pragma unroll
            for (int i = 0; i < 4; i++)
                #pragma unroll
                for (int j = 0; j < 4; j++) acc[i][j] = fmaf(a[i], bb[j], acc[i][j]);
        }
        __syncthreads();
    }
    #pragma unroll
    for (int i = 0; i < 4; i++)
        #pragma unroll
        for (int j = 0; j < 4; j++) {
            size_t idx = (size_t)(r0 + ty * 4 + i) * Ncols + c0 + tx * 4 + j;
            if (mode == 1) C[idx] = 1.5f * C[idx] - 0.5f * scale[b] * acc[i][j];
            else C[idx] = scale[b] * acc[i][j];
        }
}

// ---------------------------------------------------------------- MFMA B-operand packing
// Fragment layouts (gfx950 mfma_f32_16x16x32_bf16):
//   A: lane holds A[m=lane&15][k=(lane>>4)*8 + j], j=0..7
//   B: lane holds B[k=(lane>>4)*8 + j][n=lane&15]
//   C/D: col=lane&15, row=(lane>>4)*4 + reg
// Pack layout: [c=K/64][s=2][tg=16][lane=64][j=8] bf16 (per-chunk 32 KB contiguous)

__global__ void k_prepM(const float* __restrict__ tbuf, unsigned short* __restrict__ Mpack) {
    int idx = blockIdx.x * 256 + threadIdx.x;
    int lane = idx & 63;
    int tg   = (idx >> 6) & 15;
    int s    = (idx >> 10) & 1;
    int c    = (idx >> 11) & 3;
    int l    = idx >> 13;
    float theta = logf(0.5f / (float)(l + 1) + 1.0f);
    float mtheta = 1.0f - theta;
    int n  = tg * 16 + (lane & 15);
    int k0 = c * 64 + s * 32 + (lane >> 4) * 8;
    const float* T = tbuf + (size_t)l * 65536;
    unsigned short o[8];
    #pragma unroll
    for (int j = 0; j < 8; j++) {
        int k = k0 + j;
        float v = theta * T[(size_t)k * 256 + n] + ((k == n) ? mtheta : 0.0f);
        o[j] = bf16_rte(v);
    }
    *(uint4*)(Mpack + (size_t)idx * 8) = *(uint4*)o;
}

__global__ void k_prepW0(const float* __restrict__ W0o, unsigned short* __restrict__ Wpack) {
    int idx = blockIdx.x * 256 + threadIdx.x;
    int lane = idx & 63;
    int tg   = (idx >> 6) & 15;
    int s    = (idx >> 10) & 1;
    int c    = idx >> 11;                    // 0..7
    int n  = tg * 16 + (lane & 15);
    int k0 = c * 64 + s * 32 + (lane >> 4) * 8;
    const float* p = W0o + (size_t)n * NF + k0;
    unsigned short o[8];
    #pragma unroll
    for (int j = 0; j < 8; j++) o[j] = bf16_rte(p[j]);
    *(uint4*)(Wpack + (size_t)idx * 8) = *(uint4*)o;
}

// ---------------------------------------------------------------- fc0 (MFMA)

// h0bf = bf16(relu(x @ W0o^T + b0)). K=512 (8 chunks).
__global__ __launch_bounds__(256) void k_fc0_mfma(const float* __restrict__ X,
                                                  const unsigned short* __restrict__ Wp,
                                                  const float* __restrict__ bias,
                                                  unsigned short* __restrict__ h0bf) {
    __shared__ unsigned short Bs[2][16][64][8];   // 32 KB
    const int t = threadIdx.x, lane = t & 63, w = t >> 6;
    const int q = lane >> 4, m = lane & 15;
    const int r0 = blockIdx.x * 64;
    floatx4 acc[4][4] = {};
    for (int c = 0; c < 8; c++) {
        const uint4* src = (const uint4*)(Wp + (size_t)c * 16384);
        uint4* dst = (uint4*)&Bs[0][0][0][0];
        #pragma unroll
        for (int i = 0; i < 8; i++) dst[t + 256 * i] = src[t + 256 * i];
        __syncthreads();
        #pragma unroll
        for (int s = 0; s < 2; s++) {
            short8 afr[4];
            #pragma unroll
            for (int i = 0; i < 4; i++) {
                int row = r0 + i * 16 + m; if (row > NNODES - 1) row = NNODES - 1;
                const float* p = X + (size_t)row * NF + c * 64 + s * 32 + q * 8;
                float4 xa = *(const float4*)p;
                float4 xb = *(const float4*)(p + 4);
                uint4 af;
                af.x = pack_bf2(xa.x, xa.y); af.y = pack_bf2(xa.z, xa.w);
                af.z = pack_bf2(xb.x, xb.y); af.w = pack_bf2(xb.z, xb.w);
                afr[i] = *(short8*)&af;
            }
            #pragma unroll
            for (int tg = 0; tg < 4; tg++) {
                short8 bfr = *(const short8*)&Bs[s][w * 4 + tg][lane][0];
                #pragma unroll
                for (int i = 0; i < 4; i++)
                    acc[i][tg] = __builtin_amdgcn_mfma_f32_16x16x32_bf16(afr[i], bfr, acc[i][tg], 0, 0, 0);
            }
        }
        __syncthreads();
    }
    #pragma unroll
    for (int i = 0; i < 4; i++) {
        #pragma unroll
        for (int tg = 0; tg < 4; tg++) {
            int col = w * 64 + tg * 16 + m;
            float bv = bias[col];
            #pragma unroll
            for (int r = 0; r < 4; r++) {
                int row = r0 + i * 16 + q * 4 + r;
                if (row >= NNODES) continue;
                h0bf[(size_t)row * NH + col] = bf16_rte(fmaxf(acc[i][tg][r] + bv, 0.f));
            }
        }
    }
}

// ---------------------------------------------------------------- fused layer
// Phase 1: gather sup rows (64 dst nodes) -> LDS bf16 A-tile (+8 pad, 2-way = free)
// Phase 2: hout = bf16(relu(Atile @ M)), M B-fragments read straight from L2.
__global__ __launch_bounds__(256) void k_fused_layer(const int* __restrict__ rstart,
                                                     const int* __restrict__ counts,
                                                     const int2* __restrict__ epack,
                                                     const unsigned short* __restrict__ hin,
                                                     const unsigned short* __restrict__ h0bf,
                                                     const unsigned short* __restrict__ Mp,
                                                     unsigned short* __restrict__ hout) {
    __shared__ unsigned short Abf[64][264];       // 33792 B
    __shared__ int2 se[4][64];                    // 2048 B
    const int t = threadIdx.x, lane = t & 63, w = t >> 6;
    const int r0 = blockIdx.x * 64;

    // ---- phase 1: each wave computes sup for 16 dst nodes
    for (int nn = 0; nn < 16; nn++) {
        const int node = r0 + w * 16 + nn;
        const bool valid = node < NNODES;
        const int start = valid ? rstart[node] : 0;
        const int deg   = valid ? counts[node] : 0;
        float a0 = 0.f, a1 = 0.f, a2 = 0.f, a3 = 0.f;
        for (int base = 0; base < deg; base += 64) {
            int j = base + lane;
            if (j < deg) se[w][lane] = epack[start + j];
            int mm = deg - base; if (mm > 64) mm = 64;
            int e = 0;
            for (; e + 8 <= mm; e += 8) {
                int   si[8]; float ww[8];
                #pragma unroll
                for (int u = 0; u < 8; u++) {
                    int2 ed = se[w][e + u];
                    si[u] = ed.x; ww[u] = __int_as_float(ed.y);
                }
                uint2 v[8];
                #pragma unroll
                for (int u = 0; u < 8; u++)
                    v[u] = *(const uint2*)(hin + ((size_t)si[u] << 8) + (lane << 2));
                #pragma unroll
                for (int u = 0; u < 8; u++) {
                    a0 = fmaf(ww[u], __uint_as_float(v[u].x << 16), a0);
                    a1 = fmaf(ww[u], __uint_as_float(v[u].x & 0xffff0000u), a1);
                    a2 = fmaf(ww[u], __uint_as_float(v[u].y << 16), a2);
                    a3 = fmaf(ww[u], __uint_as_float(v[u].y & 0xffff0000u), a3);
                }
            }
            for (; e < mm; e++) {
                int2 ed = se[w][e];
                float ww = __int_as_float(ed.y);
                uint2 v = *(const uint2*)(hin + ((size_t)ed.x << 8) + (lane << 2));
                a0 = fmaf(ww, __uint_as_float(v.x << 16), a0);
                a1 = fmaf(ww, __uint_as_float(v.x & 0xffff0000u), a1);
                a2 = fmaf(ww, __uint_as_float(v.y << 16), a2);
                a3 = fmaf(ww, __uint_as_float(v.y & 0xffff0000u), a3);
            }
        }
        uint2 ov = make_uint2(0u, 0u);
        if (valid) {
            size_t idx = ((size_t)node << 8) + (lane << 2);
            uint2 rv = *(const uint2*)(h0bf + idx);
            float o0 = fmaf(0.9f, a0, 0.1f * __uint_as_float(rv.x << 16));
            float o1 = fmaf(0.9f, a1, 0.1f * __uint_as_float(rv.x & 0xffff0000u));
            float o2 = fmaf(0.9f, a2, 0.1f * __uint_as_float(rv.y << 16));
            float o3 = fmaf(0.9f, a3, 0.1f * __uint_as_float(rv.y & 0xffff0000u));
            ov.x = pack_bf2(o0, o1);
            ov.y = pack_bf2(o2, o3);
        }
        *(uint2*)&Abf[w * 16 + nn][lane * 4] = ov;
    }
    __syncthreads();

    // ---- phase 2: MFMA GEMM, B-fragments from global (L2-resident Mpack)
    const int q = lane >> 4, m = lane & 15;
    floatx4 acc[4][4] = {};
    #pragma unroll
    for (int c = 0; c < 4; c++) {
        #pragma unroll
        for (int s = 0; s < 2; s++) {
            short8 afr[4];
            #pragma unroll
            for (int i = 0; i < 4; i++)
                afr[i] = *(const short8*)&Abf[i * 16 + m][c * 64 + s * 32 + q * 8];
            #pragma unroll
            for (int tg = 0; tg < 4; tg++) {
                short8 bfr = *(const short8*)(Mp + (size_t)c * 16384 + s * 8192
                                              + (w * 4 + tg) * 512 + lane * 8);
                #pragma unroll
                for (int i = 0; i < 4; i++)
                    acc[i][tg] = __builtin_amdgcn_mfma_f32_16x16x32_bf16(afr[i], bfr, acc[i][tg], 0, 0, 0);
            }
        }
    }
    #pragma unroll
    for (int i = 0; i < 4; i++) {
        #pragma unroll
        for (int tg = 0; tg < 4; tg++) {
            int col = w * 64 + tg * 16 + m;
            #pragma unroll
            for (int r = 0; r < 4; r++) {
                int row = r0 + i * 16 + q * 4 + r;
                if (row >= NNODES) continue;
                hout[(size_t)row * NH + col] = bf16_rte(fmaxf(acc[i][tg][r], 0.f));
            }
        }
    }
}

// ---------------------------------------------------------------- logits + log_softmax (bf16 h)

__global__ __launch_bounds__(128) void k_logits(const unsigned short* __restrict__ hb,
                                                const float* __restrict__ W1,
                                                const float* __restrict__ b1,
                                                float* __restrict__ out, int nrows) {
    __shared__ float hs[16][260];
    __shared__ float Ws[40][260];
    __shared__ float ls[16][44];
    __shared__ float lse[16];
    const int t = threadIdx.x;
    const int row0 = blockIdx.x * 16;
    for (int i = t; i < 40 * 64; i += 128) {
        int c = i >> 6, k4 = i & 63;
        *(float4*)&Ws[c][k4 * 4] = *(const float4*)(W1 + (size_t)c * NH + k4 * 4);
    }
    for (int i = t; i < 16 * 32; i += 128) {
        int r = i >> 5, k8 = i & 31;
        int gr = row0 + r;
        uint4 v = make_uint4(0u, 0u, 0u, 0u);
        if (gr < nrows) v = *(const uint4*)(hb + ((size_t)gr << 8) + k8 * 8);
        float* d = &hs[r][k8 * 8];
        d[0] = __uint_as_float(v.x << 16); d[1] = __uint_as_float(v.x & 0xffff0000u);
        d[2] = __uint_as_float(v.y << 16); d[3] = __uint_as_float(v.y & 0xffff0000u);
        d[4] = __uint_as_float(v.z << 16); d[5] = __uint_as_float(v.z & 0xffff0000u);
        d[6] = __uint_as_float(v.w << 16); d[7] = __uint_as_float(v.w & 0xffff0000u);
    }
    __syncthreads();
    const int r = t & 15, cg = t >> 4;   // cg in 0..7, 5 classes each
    float acc[5];
    #pragma unroll
    for (int j = 0; j < 5; j++) acc[j] = b1[cg * 5 + j];
    for (int k = 0; k < NH; k++) {
        float hv = hs[r][k];
        #pragma unroll
        for (int j = 0; j < 5; j++) acc[j] = fmaf(hv, Ws[cg * 5 + j][k], acc[j]);
    }
    #pragma unroll
    for (int j = 0; j < 5; j++) ls[r][cg * 5 + j] = acc[j];
    __syncthreads();
    if (t < 16) {
        float m = -3.4e38f;
        for (int c = 0; c < NC; c++) m = fmaxf(m, ls[t][c]);
        float s = 0.f;
        for (int c = 0; c < NC; c++) s += expf(ls[t][c] - m);
        lse[t] = m + logf(s);
    }
    __syncthreads();
    for (int i = t; i < 16 * NC; i += 128) {
        int r2 = i / NC, c = i % NC;
        int gr = row0 + r2;
        if (gr < nrows) out[(size_t)gr * NC + c] = ls[r2][c] - lse[r2];
    }
}

// ---------------------------------------------------------------- launch

extern "C" void kernel_launch(void* const* d_in, const int* in_sizes, int n_in,
                              void* d_out, int out_size, void* d_ws, size_t ws_size,
                              hipStream_t stream) {
    const float* x      = (const float*)d_in[0];
    const int*   e_src  = (const int*)d_in[1];
    const int*   e_dst  = (const int*)d_in[2];
    const float* e_w    = (const float*)d_in[3];
    const float* W0     = (const float*)d_in[4];
    const float* b0     = (const float*)d_in[5];
    const float* convW  = (const float*)d_in[6];
    const float* W1     = (const float*)d_in[7];
    const float* b1     = (const float*)d_in[8];
    float* out = (float*)d_out;

    char* ws = (char*)d_ws;
    const size_t OFF_H0BF   = 0;                                    // bf16 [N,256]
    const size_t OFF_HA     = OFF_H0BF + (size_t)NNODES * NH * 2;   // bf16 [N,256]
    const size_t OFF_HB     = OFF_HA + (size_t)NNODES * NH * 2;     // bf16 [N,256]
    const size_t OFF_EPACK  = OFF_HB + (size_t)NNODES * NH * 2;     // int2 [E]
    const size_t OFF_RSTART = OFF_EPACK + (size_t)NEDGE * 8;
    const size_t OFF_COUNTS = OFF_RSTART + (size_t)NNODES * 4;
    const size_t OFF_CURSOR = OFF_COUNTS + (size_t)NNODES * 4;
    const size_t OFF_BSUM   = OFF_CURSOR + (size_t)NNODES * 4;
    const size_t OFF_ZC0    = OFF_BSUM + 1024;
    const size_t OFF_ZCC    = OFF_ZC0 + 256 * 512 * 4;
    const size_t OFF_S      = OFF_ZCC + 8 * 65536 * 4;
    const size_t OFF_B      = OFF_S + 9 * 65536 * 4;
    const size_t OFF_T1     = OFF_B + 9 * 65536 * 4;
    const size_t OFF_T2     = OFF_T1 + 9 * 65536 * 4;
    const size_t OFF_T      = OFF_T2 + 9 * 65536 * 4;
    const size_t OFF_W0O    = OFF_T + 8 * 65536 * 4;
    const size_t OFF_SCALES = OFF_W0O + 256 * 512 * 4;
    const size_t OFF_MPACK  = OFF_SCALES + 1024;
    const size_t OFF_WPACK  = OFF_MPACK + 8 * 65536 * 2;

    unsigned short* h0bf = (unsigned short*)(ws + OFF_H0BF);
    unsigned short* hA   = (unsigned short*)(ws + OFF_HA);
    unsigned short* hB   = (unsigned short*)(ws + OFF_HB);
    int2*   epack  = (int2*)(ws + OFF_EPACK);
    int*    rstart = (int*)(ws + OFF_RSTART);
    int*    counts = (int*)(ws + OFF_COUNTS);
    int*    cursor = (int*)(ws + OFF_CURSOR);
    int*    bsum   = (int*)(ws + OFF_BSUM);
    float*  Zc0    = (float*)(ws + OFF_ZC0);
    float*  ZcC    = (float*)(ws + OFF_ZCC);
    float*  Smat   = (float*)(ws + OFF_S);
    float*  Bb     = (float*)(ws + OFF_B);
    float*  T1b    = (float*)(ws + OFF_T1);
    float*  T2b    = (float*)(ws + OFF_T2);
    float*  tbuf   = (float*)(ws + OFF_T);
    float*  W0o    = (float*)(ws + OFF_W0O);
    float*  scales = (float*)(ws + OFF_SCALES);
    unsigned short* Mpack = (unsigned short*)(ws + OFF_MPACK);
    unsigned short* Wpack = (unsigned short*)(ws + OFF_WPACK);

    (void)in_sizes; (void)n_in; (void)out_size; (void)ws_size;

    // ---- CSR build
    hipMemsetAsync(counts, 0, (size_t)NNODES * 4, stream);
    hipMemsetAsync(cursor, 0, (size_t)NNODES * 4, stream);
    k_hist<<<(NEDGE + 255) / 256, 256, 0, stream>>>(e_dst, counts, NEDGE);
    const int NB = (NNODES + 1023) / 1024;   // 98
    k_scan1<<<NB, 1024, 0, stream>>>(counts, rstart, bsum, NNODES);
    k_scan2<<<1, 128, 0, stream>>>(bsum, NB);
    k_scan3<<<NB, 1024, 0, stream>>>(rstart, bsum, NNODES);
    k_scatter<<<(NEDGE + 255) / 256, 256, 0, stream>>>(e_src, e_dst, e_w, rstart, cursor,
                                                       epack, NEDGE);

    // ---- ortho: batched Newton-Schulz (T=5; first iteration closed-form)
    k_zc0<<<256, 256, 0, stream>>>(W0, Zc0);
    k_zcC<<<8 * 256, 256, 0, stream>>>(convW, ZcC);
    k_gram<<<dim3(4, 4, 9), 256, 0, stream>>>(Zc0, ZcC, Smat);
    k_fro<<<9, 256, 0, stream>>>(Smat, scales);
    k_initB1<<<9 * 256, 256, 0, stream>>>(Smat, scales, Bb);
    for (int it = 1; it < 5; it++) {
        k_ns_pair<<<dim3(4, 4, 18), 256, 0, stream>>>(Bb, Smat, T1b, T2b);
        k_small_nn<<<dim3(4, 4, 9), 256, 0, stream>>>(T1b, T2b, Bb, 65536, 65536, 65536,
                                                      256, 256, 1, scales);
    }
    // W0o = (B0 @ Zc0) * rsqn[0]; t[g] = (B[g+1] @ ZcC[g]) * rsqn[g+1]
    k_small_nn<<<dim3(8, 4, 1), 256, 0, stream>>>(Bb, Zc0, W0o, 0, 0, 0,
                                                  256, 512, 2, scales + 16);
    k_small_nn<<<dim3(4, 4, 8), 256, 0, stream>>>(Bb + 65536, ZcC, tbuf, 65536, 65536, 65536,
                                                  256, 256, 2, scales + 17);

    // ---- pack B-operands for MFMA
    k_prepM<<<256, 256, 0, stream>>>(tbuf, Mpack);
    k_prepW0<<<64, 256, 0, stream>>>(W0o, Wpack);

    // ---- fc0 (MFMA): h0bf = relu(x @ W0o^T + b0)  (layer 1 gathers h0bf directly)
    const int GB = (NNODES + 63) / 64;   // 1563
    k_fc0_mfma<<<GB, 256, 0, stream>>>(x, Wpack, b0, h0bf);

    // ---- 8 fused GCNII layers (spmm + residual + GEMM + relu)
    const unsigned short* hin = h0bf;
    unsigned short* bufs[2] = { hA, hB };
    for (int l = 1; l <= NLAY; l++) {
        unsigned short* hout = bufs[(l - 1) & 1];
        k_fused_layer<<<GB, 256, 0, stream>>>(rstart, counts, epack, hin, h0bf,
                                              Mpack + (size_t)(l - 1) * 65536, hout);
        hin = hout;
    }

    // ---- logits + log_softmax (reads bf16 h)
    k_logits<<<NNODES / 16, 128, 0, stream>>>(hin, W1, b1, out, NNODES);
}

// Round 5
// 3307.028 us; speedup vs baseline: 1.9323x; 1.0485x over previous
//
#include <hip/hip_runtime.h>
#include <math.h>

// Problem constants (fixed by reference)
#define NNODES 100000
#define NEDGE  3200000
#define NF     512
#define NH     256
#define NC     40
#define NLAY   8
#define EPSV   1e-5f

typedef __attribute__((ext_vector_type(8))) short short8;   // 8 bf16 (4 VGPRs)
typedef __attribute__((ext_vector_type(4))) float floatx4;  // MFMA acc

// ---------------------------------------------------------------- utilities

__device__ __forceinline__ float block_sum_256(float v) {
    __shared__ float sb[8];
    #pragma unroll
    for (int off = 32; off; off >>= 1) v += __shfl_down(v, off, 64);
    if ((threadIdx.x & 63) == 0) sb[threadIdx.x >> 6] = v;
    __syncthreads();
    return sb[0] + sb[1] + sb[2] + sb[3];
}

// round-to-nearest-even f32 -> bf16
__device__ __forceinline__ unsigned short bf16_rte(float a) {
    unsigned int u = __float_as_uint(a);
    return (unsigned short)((u + 0x7fffu + ((u >> 16) & 1u)) >> 16);
}
__device__ __forceinline__ unsigned int pack_bf2(float a, float b) {
    unsigned int ua = __float_as_uint(a), ub = __float_as_uint(b);
    ua = (ua + 0x7fffu + ((ua >> 16) & 1u)) >> 16;
    ub = (ub + 0x7fffu + ((ub >> 16) & 1u)) & 0xffff0000u;
    return ua | ub;
}

// ---------------------------------------------------------------- CSR build

__global__ void k_hist(const int* __restrict__ dst, int* __restrict__ counts, int n) {
    int i = blockIdx.x * 256 + threadIdx.x;
    if (i < n) atomicAdd(&counts[dst[i]], 1);
}

__global__ void k_scan1(const int* __restrict__ in, int* __restrict__ out,
                        int* __restrict__ bsum, int n) {
    __shared__ int s[1024];
    int t = threadIdx.x, g = blockIdx.x * 1024 + t;
    int v = (g < n) ? in[g] : 0;
    s[t] = v; __syncthreads();
    for (int off = 1; off < 1024; off <<= 1) {
        int u = (t >= off) ? s[t - off] : 0;
        __syncthreads();
        s[t] += u;
        __syncthreads();
    }
    if (g < n) out[g] = s[t] - v;           // exclusive
    if (t == 1023) bsum[blockIdx.x] = s[1023];
}

__global__ void k_scan2(int* __restrict__ bsum, int nb) {
    __shared__ int s[128];
    int t = threadIdx.x;
    int v = (t < nb) ? bsum[t] : 0;
    s[t] = v; __syncthreads();
    for (int off = 1; off < 128; off <<= 1) {
        int u = (t >= off) ? s[t - off] : 0;
        __syncthreads();
        s[t] += u;
        __syncthreads();
    }
    if (t < nb) bsum[t] = s[t] - v;         // exclusive
}

__global__ void k_scan3(int* __restrict__ out, const int* __restrict__ bsum, int n) {
    int g = blockIdx.x * 1024 + threadIdx.x;
    if (g < n) out[g] += bsum[blockIdx.x];
}

// pack (src, weight-bits) interleaved for single ds_read_b64 broadcast later
__global__ void k_scatter(const int* __restrict__ src, const int* __restrict__ dst,
                          const float* __restrict__ w, const int* __restrict__ rstart,
                          int* __restrict__ cursor, int2* __restrict__ epack, int n) {
    int i = blockIdx.x * 256 + threadIdx.x;
    if (i < n) {
        int d = dst[i];
        int pos = rstart[d] + atomicAdd(&cursor[d], 1);
        epack[pos] = make_int2(src[i], __float_as_int(w[i]));
    }
}

// ---------------------------------------------------------------- ortho prep

__global__ void k_zc0(const float* __restrict__ W0, float* __restrict__ Zc0) {
    int r = blockIdx.x, t = threadIdx.x;
    float a = W0[r * NF + t];
    float b = W0[r * NF + 256 + t];
    float mean = block_sum_256(a + b) * (1.0f / 512.0f);
    Zc0[r * NF + t]       = a - mean;
    Zc0[r * NF + 256 + t] = b - mean;
}

__global__ void k_zcC(const float* __restrict__ convW, float* __restrict__ ZcC) {
    int g = blockIdx.x >> 8, r = blockIdx.x & 255, t = threadIdx.x;
    float v = 0.5f * convW[((size_t)g * NH + r) * NH + t] + ((r == t) ? 0.5f : 0.0f);
    float mean = block_sum_256(v) * (1.0f / 256.0f);
    ZcC[((size_t)g * NH + r) * NH + t] = v - mean;
}

// S[b] = Zc[b] @ Zc[b]^T + EPS*I   (b=0: Zc0 K=512; b>0: ZcC[b-1] K=256)
__global__ __launch_bounds__(256) void k_gram(const float* __restrict__ Zc0,
                                              const float* __restrict__ ZcC,
                                              float* __restrict__ S) {
    const int b = blockIdx.z;
    const float* A = (b == 0) ? Zc0 : (ZcC + (size_t)(b - 1) * 65536);
    const int K = (b == 0) ? 512 : 256;
    const int r0 = blockIdx.y * 64, c0 = blockIdx.x * 64;
    __shared__ float As[32][76], Bs[32][76];
    const int t = threadIdx.x, tx = t & 15, ty = t >> 4;
    const int lr = t >> 2, lk = (t & 3) * 4;
    float acc[4][4] = {};
    for (int k0 = 0; k0 < K; k0 += 32) {
        float4 a0 = *(const float4*)(A + (size_t)(r0 + lr) * K + k0 + lk);
        float4 a1 = *(const float4*)(A + (size_t)(r0 + lr) * K + k0 + lk + 16);
        As[lk + 0][lr] = a0.x; As[lk + 1][lr] = a0.y; As[lk + 2][lr] = a0.z; As[lk + 3][lr] = a0.w;
        As[lk + 16][lr] = a1.x; As[lk + 17][lr] = a1.y; As[lk + 18][lr] = a1.z; As[lk + 19][lr] = a1.w;
        float4 b0 = *(const float4*)(A + (size_t)(c0 + lr) * K + k0 + lk);
        float4 b1 = *(const float4*)(A + (size_t)(c0 + lr) * K + k0 + lk + 16);
        Bs[lk + 0][lr] = b0.x; Bs[lk + 1][lr] = b0.y; Bs[lk + 2][lr] = b0.z; Bs[lk + 3][lr] = b0.w;
        Bs[lk + 16][lr] = b1.x; Bs[lk + 17][lr] = b1.y; Bs[lk + 18][lr] = b1.z; Bs[lk + 19][lr] = b1.w;
        __syncthreads();
        #pragma unroll
        for (int kk = 0; kk < 32; kk++) {
            float a[4], bb[4];
            *(float4*)&a[0]  = *(const float4*)&As[kk][ty * 4];
            *(float4*)&bb[0] = *(const float4*)&Bs[kk][tx * 4];
            #pragma unroll
            for (int i = 0; i < 4; i++)
                #pragma unroll
                for (int j = 0; j < 4; j++) acc[i][j] = fmaf(a[i], bb[j], acc[i][j]);
        }
        __syncthreads();
    }
    #pragma unroll
    for (int i = 0; i < 4; i++)
        #pragma unroll
        for (int j = 0; j < 4; j++) {
            int r = r0 + ty * 4 + i, c = c0 + tx * 4 + j;
            float v = acc[i][j];
            if (r == c) v += EPSV;
            S[(size_t)b * 65536 + r * NH + c] = v;
        }
}

__global__ void k_fro(const float* __restrict__ S, float* __restrict__ scales) {
    __shared__ float sb[8];
    const int b = blockIdx.x, t = threadIdx.x;
    const float* p = S + (size_t)b * 65536;
    float s = 0.f;
    for (int i = t; i < 65536; i += 256) { float v = p[i]; s = fmaf(v, v, s); }
    #pragma unroll
    for (int off = 32; off; off >>= 1) s += __shfl_down(s, off, 64);
    if ((t & 63) == 0) sb[t >> 6] = s;
    __syncthreads();
    if (t == 0) {
        float nrm = sqrtf(sb[0] + sb[1] + sb[2] + sb[3]);
        scales[b]      = 1.0f / nrm;
        scales[16 + b] = rsqrtf(nrm);
    }
}

// B1 = 1.5*I - 0.5*invn*S  (closed-form first Newton-Schulz iteration)
__global__ void k_initB1(const float* __restrict__ S, const float* __restrict__ scales,
                         float* __restrict__ B) {
    int i = blockIdx.x * 256 + threadIdx.x;     // 9*65536
    int b = i >> 16, m = i & 65535;
    float v = -0.5f * scales[b] * S[i];
    if ((m >> 8) == (m & 255)) v += 1.5f;
    B[i] = v;
}

// Batch-18: b<9 -> T1[b] = B[b]@B[b] ; b>=9 -> T2[b-9] = B[b-9]@S[b-9]
__global__ __launch_bounds__(256) void k_ns_pair(const float* __restrict__ Bb,
                                                 const float* __restrict__ Smat,
                                                 float* __restrict__ T1b,
                                                 float* __restrict__ T2b) {
    const int b = blockIdx.z;
    const int bb = (b < 9) ? b : b - 9;
    const float* A  = Bb + (size_t)bb * 65536;
    const float* Bm = (b < 9) ? A : (Smat + (size_t)bb * 65536);
    float* C = (b < 9) ? (T1b + (size_t)bb * 65536) : (T2b + (size_t)bb * 65536);
    const int r0 = blockIdx.y * 64, c0 = blockIdx.x * 64;
    __shared__ float As[32][76], Bs[32][76];
    const int t = threadIdx.x, tx = t & 15, ty = t >> 4;
    const int lr = t >> 2, lk = (t & 3) * 4;
    const int bk = t >> 3, bc = (t & 7) * 8;
    float acc[4][4] = {};
    for (int k0 = 0; k0 < 256; k0 += 32) {
        float4 a0 = *(const float4*)(A + (size_t)(r0 + lr) * 256 + k0 + lk);
        float4 a1 = *(const float4*)(A + (size_t)(r0 + lr) * 256 + k0 + lk + 16);
        As[lk + 0][lr] = a0.x; As[lk + 1][lr] = a0.y; As[lk + 2][lr] = a0.z; As[lk + 3][lr] = a0.w;
        As[lk + 16][lr] = a1.x; As[lk + 17][lr] = a1.y; As[lk + 18][lr] = a1.z; As[lk + 19][lr] = a1.w;
        float4 b0 = *(const float4*)(Bm + (size_t)(k0 + bk) * 256 + c0 + bc);
        float4 b1 = *(const float4*)(Bm + (size_t)(k0 + bk) * 256 + c0 + bc + 4);
        *(float4*)&Bs[bk][bc]     = b0;
        *(float4*)&Bs[bk][bc + 4] = b1;
        __syncthreads();
        #pragma unroll
        for (int kk = 0; kk < 32; kk++) {
            float a[4], bb2[4];
            *(float4*)&a[0]   = *(const float4*)&As[kk][ty * 4];
            *(float4*)&bb2[0] = *(const float4*)&Bs[kk][tx * 4];
            #pragma unroll
            for (int i = 0; i < 4; i++)
                #pragma unroll
                for (int j = 0; j < 4; j++) acc[i][j] = fmaf(a[i], bb2[j], acc[i][j]);
        }
        __syncthreads();
    }
    #pragma unroll
    for (int i = 0; i < 4; i++)
        #pragma unroll
        for (int j = 0; j < 4; j++)
            C[(size_t)(r0 + ty * 4 + i) * 256 + c0 + tx * 4 + j] = acc[i][j];
}

// Batched small NN matmul, M=256, tile 64x64, Ktile 32.
// mode 1: C = 1.5*C - 0.5*scale[b]*(A@B) ; mode 2: C = scale[b]*(A@B)
__global__ __launch_bounds__(256) void k_small_nn(const float* __restrict__ A0,
                                                  const float* __restrict__ B0,
                                                  float* __restrict__ C0,
                                                  int sA, int sB, int sC,
                                                  int K, int Ncols, int mode,
                                                  const float* __restrict__ scale) {
    const int b = blockIdx.z;
    const float* A = A0 + (size_t)b * sA;
    const float* Bm = B0 + (size_t)b * sB;
    float* C = C0 + (size_t)b * sC;
    const int r0 = blockIdx.y * 64, c0 = blockIdx.x * 64;
    __shared__ float As[32][76], Bs[32][76];
    const int t = threadIdx.x, tx = t & 15, ty = t >> 4;
    const int lr = t >> 2, lk = (t & 3) * 4;
    const int bk = t >> 3, bc = (t & 7) * 8;
    float acc[4][4] = {};
    for (int k0 = 0; k0 < K; k0 += 32) {
        float4 a0 = *(const float4*)(A + (size_t)(r0 + lr) * K + k0 + lk);
        float4 a1 = *(const float4*)(A + (size_t)(r0 + lr) * K + k0 + lk + 16);
        As[lk + 0][lr] = a0.x; As[lk + 1][lr] = a0.y; As[lk + 2][lr] = a0.z; As[lk + 3][lr] = a0.w;
        As[lk + 16][lr] = a1.x; As[lk + 17][lr] = a1.y; As[lk + 18][lr] = a1.z; As[lk + 19][lr] = a1.w;
        float4 b0 = *(const float4*)(Bm + (size_t)(k0 + bk) * Ncols + c0 + bc);
        float4 b1 = *(const float4*)(Bm + (size_t)(k0 + bk) * Ncols + c0 + bc + 4);
        *(float4*)&Bs[bk][bc]     = b0;
        *(float4*)&Bs[bk][bc + 4] = b1;
        __syncthreads();
        #pragma unroll
        for (int kk = 0; kk < 32; kk++) {
            float a[4], bb[4];
            *(float4*)&a[0]  = *(const float4*)&As[kk][ty * 4];
            *(float4*)&bb[0] = *(const float4*)&Bs[kk][tx * 4];
            #pragma unroll
            for (int i = 0; i < 4; i++)
                #pragma unroll
                for (int j = 0; j < 4; j++) acc[i][j] = fmaf(a[i], bb[j], acc[i][j]);
        }
        __syncthreads();
    }
    #pragma unroll
    for (int i = 0; i < 4; i++)
        #pragma unroll
        for (int j = 0; j < 4; j++) {
            size_t idx = (size_t)(r0 + ty * 4 + i) * Ncols + c0 + tx * 4 + j;
            if (mode == 1) C[idx] = 1.5f * C[idx] - 0.5f * scale[b] * acc[i][j];
            else C[idx] = scale[b] * acc[i][j];
        }
}

// ---------------------------------------------------------------- MFMA B-operand packing
// Fragment layouts (gfx950 mfma_f32_16x16x32_bf16):
//   A: lane holds A[m=lane&15][k=(lane>>4)*8 + j], j=0..7
//   B: lane holds B[k=(lane>>4)*8 + j][n=lane&15]
//   C/D: col=lane&15, row=(lane>>4)*4 + reg
// Pack layout: [c=K/64][s=2][tg=16][lane=64][j=8] bf16 (per-chunk 32 KB contiguous)

__global__ void k_prepM(const float* __restrict__ tbuf, unsigned short* __restrict__ Mpack) {
    int idx = blockIdx.x * 256 + threadIdx.x;
    int lane = idx & 63;
    int tg   = (idx >> 6) & 15;
    int s    = (idx >> 10) & 1;
    int c    = (idx >> 11) & 3;
    int l    = idx >> 13;
    float theta = logf(0.5f / (float)(l + 1) + 1.0f);
    float mtheta = 1.0f - theta;
    int n  = tg * 16 + (lane & 15);
    int k0 = c * 64 + s * 32 + (lane >> 4) * 8;
    const float* T = tbuf + (size_t)l * 65536;
    unsigned short o[8];
    #pragma unroll
    for (int j = 0; j < 8; j++) {
        int k = k0 + j;
        float v = theta * T[(size_t)k * 256 + n] + ((k == n) ? mtheta : 0.0f);
        o[j] = bf16_rte(v);
    }
    *(uint4*)(Mpack + (size_t)idx * 8) = *(uint4*)o;
}

__global__ void k_prepW0(const float* __restrict__ W0o, unsigned short* __restrict__ Wpack) {
    int idx = blockIdx.x * 256 + threadIdx.x;
    int lane = idx & 63;
    int tg   = (idx >> 6) & 15;
    int s    = (idx >> 10) & 1;
    int c    = idx >> 11;                    // 0..7
    int n  = tg * 16 + (lane & 15);
    int k0 = c * 64 + s * 32 + (lane >> 4) * 8;
    const float* p = W0o + (size_t)n * NF + k0;
    unsigned short o[8];
    #pragma unroll
    for (int j = 0; j < 8; j++) o[j] = bf16_rte(p[j]);
    *(uint4*)(Wpack + (size_t)idx * 8) = *(uint4*)o;
}

// ---------------------------------------------------------------- fc0 (MFMA)

// h0bf = bf16(relu(x @ W0o^T + b0)). K=512 (8 chunks).
__global__ __launch_bounds__(256) void k_fc0_mfma(const float* __restrict__ X,
                                                  const unsigned short* __restrict__ Wp,
                                                  const float* __restrict__ bias,
                                                  unsigned short* __restrict__ h0bf) {
    __shared__ unsigned short Bs[2][16][64][8];   // 32 KB
    const int t = threadIdx.x, lane = t & 63, w = t >> 6;
    const int q = lane >> 4, m = lane & 15;
    const int r0 = blockIdx.x * 64;
    floatx4 acc[4][4] = {};
    for (int c = 0; c < 8; c++) {
        const uint4* src = (const uint4*)(Wp + (size_t)c * 16384);
        uint4* dst = (uint4*)&Bs[0][0][0][0];
        #pragma unroll
        for (int i = 0; i < 8; i++) dst[t + 256 * i] = src[t + 256 * i];
        __syncthreads();
        #pragma unroll
        for (int s = 0; s < 2; s++) {
            short8 afr[4];
            #pragma unroll
            for (int i = 0; i < 4; i++) {
                int row = r0 + i * 16 + m; if (row > NNODES - 1) row = NNODES - 1;
                const float* p = X + (size_t)row * NF + c * 64 + s * 32 + q * 8;
                float4 xa = *(const float4*)p;
                float4 xb = *(const float4*)(p + 4);
                uint4 af;
                af.x = pack_bf2(xa.x, xa.y); af.y = pack_bf2(xa.z, xa.w);
                af.z = pack_bf2(xb.x, xb.y); af.w = pack_bf2(xb.z, xb.w);
                afr[i] = *(short8*)&af;
            }
            #pragma unroll
            for (int tg = 0; tg < 4; tg++) {
                short8 bfr = *(const short8*)&Bs[s][w * 4 + tg][lane][0];
                #pragma unroll
                for (int i = 0; i < 4; i++)
                    acc[i][tg] = __builtin_amdgcn_mfma_f32_16x16x32_bf16(afr[i], bfr, acc[i][tg], 0, 0, 0);
            }
        }
        __syncthreads();
    }
    #pragma unroll
    for (int i = 0; i < 4; i++) {
        #pragma unroll
        for (int tg = 0; tg < 4; tg++) {
            int col = w * 64 + tg * 16 + m;
            float bv = bias[col];
            #pragma unroll
            for (int r = 0; r < 4; r++) {
                int row = r0 + i * 16 + q * 4 + r;
                if (row >= NNODES) continue;
                h0bf[(size_t)row * NH + col] = bf16_rte(fmaxf(acc[i][tg][r] + bv, 0.f));
            }
        }
    }
}

// ---------------------------------------------------------------- SpMM (split, unroll-8)

// One wave per dst node; lane owns 4 features (8B bf16 gather per lane).
// supbf[d,:] = bf16( 0.9 * sum_e w_e * hin[src_e,:] + 0.1 * h0bf[d,:] )
__global__ __launch_bounds__(256) void k_spmm(const int* __restrict__ rstart,
                                              const int* __restrict__ counts,
                                              const int2* __restrict__ epack,
                                              const unsigned short* __restrict__ hin,
                                              const unsigned short* __restrict__ h0bf,
                                              unsigned short* __restrict__ supbf) {
    __shared__ int2 se[4][64];
    const int wv = threadIdx.x >> 6, lane = threadIdx.x & 63;
    const int node = blockIdx.x * 4 + wv;
    const int start = rstart[node], deg = counts[node];
    float a0 = 0.f, a1 = 0.f, a2 = 0.f, a3 = 0.f;
    for (int base = 0; base < deg; base += 64) {
        int j = base + lane;
        if (j < deg) se[wv][lane] = epack[start + j];
        int m = deg - base; if (m > 64) m = 64;
        int e = 0;
        for (; e + 8 <= m; e += 8) {
            float ww[8]; uint2 v[8];
            #pragma unroll
            for (int u = 0; u < 8; u++) {
                int2 ed = se[wv][e + u];
                ww[u] = __int_as_float(ed.y);
                v[u] = *(const uint2*)(hin + ((size_t)ed.x << 8) + (lane << 2));
            }
            #pragma unroll
            for (int u = 0; u < 8; u++) {
                a0 = fmaf(ww[u], __uint_as_float(v[u].x << 16), a0);
                a1 = fmaf(ww[u], __uint_as_float(v[u].x & 0xffff0000u), a1);
                a2 = fmaf(ww[u], __uint_as_float(v[u].y << 16), a2);
                a3 = fmaf(ww[u], __uint_as_float(v[u].y & 0xffff0000u), a3);
            }
        }
        for (; e < m; e++) {
            int2 ed = se[wv][e];
            float ww = __int_as_float(ed.y);
            uint2 v = *(const uint2*)(hin + ((size_t)ed.x << 8) + (lane << 2));
            a0 = fmaf(ww, __uint_as_float(v.x << 16), a0);
            a1 = fmaf(ww, __uint_as_float(v.x & 0xffff0000u), a1);
            a2 = fmaf(ww, __uint_as_float(v.y << 16), a2);
            a3 = fmaf(ww, __uint_as_float(v.y & 0xffff0000u), a3);
        }
    }
    size_t idx = ((size_t)node << 8) + (lane << 2);
    uint2 rv = *(const uint2*)(h0bf + idx);
    float o0 = fmaf(0.9f, a0, 0.1f * __uint_as_float(rv.x << 16));
    float o1 = fmaf(0.9f, a1, 0.1f * __uint_as_float(rv.x & 0xffff0000u));
    float o2 = fmaf(0.9f, a2, 0.1f * __uint_as_float(rv.y << 16));
    float o3 = fmaf(0.9f, a3, 0.1f * __uint_as_float(rv.y & 0xffff0000u));
    uint2 ov;
    ov.x = pack_bf2(o0, o1);
    ov.y = pack_bf2(o2, o3);
    *(uint2*)(supbf + idx) = ov;
}

// ---------------------------------------------------------------- layer GEMM (MFMA, no LDS)

// hout = bf16(relu(Sbf @ M)). Block = 64 rows x 256 cols, 4 waves.
// A-fragments from L1/L2-resident Sbf tile; B-fragments from L2-resident Mpack chunk.
__global__ __launch_bounds__(256) void k_gemm_layer(const unsigned short* __restrict__ Sbf,
                                                    const unsigned short* __restrict__ Mp,
                                                    unsigned short* __restrict__ hout) {
    const int t = threadIdx.x, lane = t & 63, w = t >> 6;
    const int q = lane >> 4, m = lane & 15;
    const int r0 = blockIdx.x * 64;
    floatx4 acc[4][4] = {};
    #pragma unroll
    for (int c = 0; c < 4; c++) {
        #pragma unroll
        for (int s = 0; s < 2; s++) {
            short8 afr[4];
            #pragma unroll
            for (int i = 0; i < 4; i++) {
                int row = r0 + i * 16 + m; if (row > NNODES - 1) row = NNODES - 1;
                afr[i] = *(const short8*)(Sbf + (size_t)row * NH + c * 64 + s * 32 + q * 8);
            }
            #pragma unroll
            for (int tg = 0; tg < 4; tg++) {
                short8 bfr = *(const short8*)(Mp + (size_t)c * 16384 + s * 8192
                                              + (w * 4 + tg) * 512 + lane * 8);
                #pragma unroll
                for (int i = 0; i < 4; i++)
                    acc[i][tg] = __builtin_amdgcn_mfma_f32_16x16x32_bf16(afr[i], bfr, acc[i][tg], 0, 0, 0);
            }
        }
    }
    #pragma unroll
    for (int i = 0; i < 4; i++) {
        #pragma unroll
        for (int tg = 0; tg < 4; tg++) {
            int col = w * 64 + tg * 16 + m;
            #pragma unroll
            for (int r = 0; r < 4; r++) {
                int row = r0 + i * 16 + q * 4 + r;
                if (row >= NNODES) continue;
                hout[(size_t)row * NH + col] = bf16_rte(fmaxf(acc[i][tg][r], 0.f));
            }
        }
    }
}

// ---------------------------------------------------------------- logits + log_softmax (bf16 h)

__global__ __launch_bounds__(128) void k_logits(const unsigned short* __restrict__ hb,
                                                const float* __restrict__ W1,
                                                const float* __restrict__ b1,
                                                float* __restrict__ out, int nrows) {
    __shared__ float hs[16][260];
    __shared__ float Ws[40][260];
    __shared__ float ls[16][44];
    __shared__ float lse[16];
    const int t = threadIdx.x;
    const int row0 = blockIdx.x * 16;
    for (int i = t; i < 40 * 64; i += 128) {
        int c = i >> 6, k4 = i & 63;
        *(float4*)&Ws[c][k4 * 4] = *(const float4*)(W1 + (size_t)c * NH + k4 * 4);
    }
    for (int i = t; i < 16 * 32; i += 128) {
        int r = i >> 5, k8 = i & 31;
        int gr = row0 + r;
        uint4 v = make_uint4(0u, 0u, 0u, 0u);
        if (gr < nrows) v = *(const uint4*)(hb + ((size_t)gr << 8) + k8 * 8);
        float* d = &hs[r][k8 * 8];
        d[0] = __uint_as_float(v.x << 16); d[1] = __uint_as_float(v.x & 0xffff0000u);
        d[2] = __uint_as_float(v.y << 16); d[3] = __uint_as_float(v.y & 0xffff0000u);
        d[4] = __uint_as_float(v.z << 16); d[5] = __uint_as_float(v.z & 0xffff0000u);
        d[6] = __uint_as_float(v.w << 16); d[7] = __uint_as_float(v.w & 0xffff0000u);
    }
    __syncthreads();
    const int r = t & 15, cg = t >> 4;   // cg in 0..7, 5 classes each
    float acc[5];
    #pragma unroll
    for (int j = 0; j < 5; j++) acc[j] = b1[cg * 5 + j];
    for (int k = 0; k < NH; k++) {
        float hv = hs[r][k];
        #pragma unroll
        for (int j = 0; j < 5; j++) acc[j] = fmaf(hv, Ws[cg * 5 + j][k], acc[j]);
    }
    #pragma unroll
    for (int j = 0; j < 5; j++) ls[r][cg * 5 + j] = acc[j];
    __syncthreads();
    if (t < 16) {
        float m = -3.4e38f;
        for (int c = 0; c < NC; c++) m = fmaxf(m, ls[t][c]);
        float s = 0.f;
        for (int c = 0; c < NC; c++) s += expf(ls[t][c] - m);
        lse[t] = m + logf(s);
    }
    __syncthreads();
    for (int i = t; i < 16 * NC; i += 128) {
        int r2 = i / NC, c = i % NC;
        int gr = row0 + r2;
        if (gr < nrows) out[(size_t)gr * NC + c] = ls[r2][c] - lse[r2];
    }
}

// ---------------------------------------------------------------- launch

extern "C" void kernel_launch(void* const* d_in, const int* in_sizes, int n_in,
                              void* d_out, int out_size, void* d_ws, size_t ws_size,
                              hipStream_t stream) {
    const float* x      = (const float*)d_in[0];
    const int*   e_src  = (const int*)d_in[1];
    const int*   e_dst  = (const int*)d_in[2];
    const float* e_w    = (const float*)d_in[3];
    const float* W0     = (const float*)d_in[4];
    const float* b0     = (const float*)d_in[5];
    const float* convW  = (const float*)d_in[6];
    const float* W1     = (const float*)d_in[7];
    const float* b1     = (const float*)d_in[8];
    float* out = (float*)d_out;

    char* ws = (char*)d_ws;
    const size_t OFF_H0BF   = 0;                                    // bf16 [N,256]
    const size_t OFF_HA     = OFF_H0BF + (size_t)NNODES * NH * 2;   // bf16 [N,256]
    const size_t OFF_HB     = OFF_HA + (size_t)NNODES * NH * 2;     // bf16 [N,256]
    const size_t OFF_SUPBF  = OFF_HB + (size_t)NNODES * NH * 2;     // bf16 [N,256]
    const size_t OFF_EPACK  = OFF_SUPBF + (size_t)NNODES * NH * 2;  // int2 [E]
    const size_t OFF_RSTART = OFF_EPACK + (size_t)NEDGE * 8;
    const size_t OFF_COUNTS = OFF_RSTART + (size_t)NNODES * 4;
    const size_t OFF_CURSOR = OFF_COUNTS + (size_t)NNODES * 4;
    const size_t OFF_BSUM   = OFF_CURSOR + (size_t)NNODES * 4;
    const size_t OFF_ZC0    = OFF_BSUM + 1024;
    const size_t OFF_ZCC    = OFF_ZC0 + 256 * 512 * 4;
    const size_t OFF_S      = OFF_ZCC + 8 * 65536 * 4;
    const size_t OFF_B      = OFF_S + 9 * 65536 * 4;
    const size_t OFF_T1     = OFF_B + 9 * 65536 * 4;
    const size_t OFF_T2     = OFF_T1 + 9 * 65536 * 4;
    const size_t OFF_T      = OFF_T2 + 9 * 65536 * 4;
    const size_t OFF_W0O    = OFF_T + 8 * 65536 * 4;
    const size_t OFF_SCALES = OFF_W0O + 256 * 512 * 4;
    const size_t OFF_MPACK  = OFF_SCALES + 1024;
    const size_t OFF_WPACK  = OFF_MPACK + 8 * 65536 * 2;

    unsigned short* h0bf  = (unsigned short*)(ws + OFF_H0BF);
    unsigned short* hA    = (unsigned short*)(ws + OFF_HA);
    unsigned short* hB    = (unsigned short*)(ws + OFF_HB);
    unsigned short* supbf = (unsigned short*)(ws + OFF_SUPBF);
    int2*   epack  = (int2*)(ws + OFF_EPACK);
    int*    rstart = (int*)(ws + OFF_RSTART);
    int*    counts = (int*)(ws + OFF_COUNTS);
    int*    cursor = (int*)(ws + OFF_CURSOR);
    int*    bsum   = (int*)(ws + OFF_BSUM);
    float*  Zc0    = (float*)(ws + OFF_ZC0);
    float*  ZcC    = (float*)(ws + OFF_ZCC);
    float*  Smat   = (float*)(ws + OFF_S);
    float*  Bb     = (float*)(ws + OFF_B);
    float*  T1b    = (float*)(ws + OFF_T1);
    float*  T2b    = (float*)(ws + OFF_T2);
    float*  tbuf   = (float*)(ws + OFF_T);
    float*  W0o    = (float*)(ws + OFF_W0O);
    float*  scales = (float*)(ws + OFF_SCALES);
    unsigned short* Mpack = (unsigned short*)(ws + OFF_MPACK);
    unsigned short* Wpack = (unsigned short*)(ws + OFF_WPACK);

    (void)in_sizes; (void)n_in; (void)out_size; (void)ws_size;

    // ---- CSR build
    hipMemsetAsync(counts, 0, (size_t)NNODES * 4, stream);
    hipMemsetAsync(cursor, 0, (size_t)NNODES * 4, stream);
    k_hist<<<(NEDGE + 255) / 256, 256, 0, stream>>>(e_dst, counts, NEDGE);
    const int NB = (NNODES + 1023) / 1024;   // 98
    k_scan1<<<NB, 1024, 0, stream>>>(counts, rstart, bsum, NNODES);
    k_scan2<<<1, 128, 0, stream>>>(bsum, NB);
    k_scan3<<<NB, 1024, 0, stream>>>(rstart, bsum, NNODES);
    k_scatter<<<(NEDGE + 255) / 256, 256, 0, stream>>>(e_src, e_dst, e_w, rstart, cursor,
                                                       epack, NEDGE);

    // ---- ortho: batched Newton-Schulz (T=5; first iteration closed-form)
    k_zc0<<<256, 256, 0, stream>>>(W0, Zc0);
    k_zcC<<<8 * 256, 256, 0, stream>>>(convW, ZcC);
    k_gram<<<dim3(4, 4, 9), 256, 0, stream>>>(Zc0, ZcC, Smat);
    k_fro<<<9, 256, 0, stream>>>(Smat, scales);
    k_initB1<<<9 * 256, 256, 0, stream>>>(Smat, scales, Bb);
    for (int it = 1; it < 5; it++) {
        k_ns_pair<<<dim3(4, 4, 18), 256, 0, stream>>>(Bb, Smat, T1b, T2b);
        k_small_nn<<<dim3(4, 4, 9), 256, 0, stream>>>(T1b, T2b, Bb, 65536, 65536, 65536,
                                                      256, 256, 1, scales);
    }
    // W0o = (B0 @ Zc0) * rsqn[0]; t[g] = (B[g+1] @ ZcC[g]) * rsqn[g+1]
    k_small_nn<<<dim3(8, 4, 1), 256, 0, stream>>>(Bb, Zc0, W0o, 0, 0, 0,
                                                  256, 512, 2, scales + 16);
    k_small_nn<<<dim3(4, 4, 8), 256, 0, stream>>>(Bb + 65536, ZcC, tbuf, 65536, 65536, 65536,
                                                  256, 256, 2, scales + 17);

    // ---- pack B-operands for MFMA
    k_prepM<<<256, 256, 0, stream>>>(tbuf, Mpack);
    k_prepW0<<<64, 256, 0, stream>>>(W0o, Wpack);

    // ---- fc0 (MFMA): h0bf = relu(x @ W0o^T + b0)  (layer 1 gathers h0bf directly)
    const int GB = (NNODES + 63) / 64;   // 1563
    k_fc0_mfma<<<GB, 256, 0, stream>>>(x, Wpack, b0, h0bf);

    // ---- 8 GCNII layers: spmm (gather+residual, bf16) then GEMM (MFMA, no LDS)
    const unsigned short* hin = h0bf;
    unsigned short* bufs[2] = { hA, hB };
    for (int l = 1; l <= NLAY; l++) {
        k_spmm<<<NNODES / 4, 256, 0, stream>>>(rstart, counts, epack, hin, h0bf, supbf);
        unsigned short* hout = bufs[(l - 1) & 1];
        k_gemm_layer<<<GB, 256, 0, stream>>>(supbf, Mpack + (size_t)(l - 1) * 65536, hout);
        hin = hout;
    }

    // ---- logits + log_softmax (reads bf16 h)
    k_logits<<<NNODES / 16, 128, 0, stream>>>(hin, W1, b1, out, NNODES);
}

// Round 6
// 2578.490 us; speedup vs baseline: 2.4782x; 1.2825x over previous
//
#include <hip/hip_runtime.h>
#include <math.h>

// Problem constants (fixed by reference)
#define NNODES 100000
#define NEDGE  3200000
#define NF     512
#define NH     256
#define NC     40
#define NLAY   8
#define EPSV   1e-5f

typedef __attribute__((ext_vector_type(8))) short short8;   // 8 bf16 (4 VGPRs)
typedef __attribute__((ext_vector_type(4))) float floatx4;  // MFMA acc

// Feature permutation (epilogue-natural uint8 store order):
//   pos(col) = (col&0xC0) | ((col&15)<<2) | ((col>>4)&3)
//   col(pos) = (pos&0xC0) | ((pos&3)<<4) | ((pos>>2)&15)
// All u8 h-buffers, sup, and Mpack k-rows live in pos space; layer-8 output and
// logits use natural order.

// ---------------------------------------------------------------- utilities

__device__ __forceinline__ float block_sum_256(float v) {
    __shared__ float sb[8];
    #pragma unroll
    for (int off = 32; off; off >>= 1) v += __shfl_down(v, off, 64);
    if ((threadIdx.x & 63) == 0) sb[threadIdx.x >> 6] = v;
    __syncthreads();
    return sb[0] + sb[1] + sb[2] + sb[3];
}

// round-to-nearest-even f32 -> bf16
__device__ __forceinline__ unsigned short bf16_rte(float a) {
    unsigned int u = __float_as_uint(a);
    return (unsigned short)((u + 0x7fffu + ((u >> 16) & 1u)) >> 16);
}
__device__ __forceinline__ unsigned int pack_bf2(float a, float b) {
    unsigned int ua = __float_as_uint(a), ub = __float_as_uint(b);
    ua = (ua + 0x7fffu + ((ua >> 16) & 1u)) >> 16;
    ub = (ub + 0x7fffu + ((ub >> 16) & 1u)) & 0xffff0000u;
    return ua | ub;
}

// ---------------------------------------------------------------- CSR build

__global__ void k_hist(const int* __restrict__ dst, int* __restrict__ counts, int n) {
    int i = blockIdx.x * 256 + threadIdx.x;
    if (i < n) atomicAdd(&counts[dst[i]], 1);
}

__global__ void k_scan1(const int* __restrict__ in, int* __restrict__ out,
                        int* __restrict__ bsum, int n) {
    __shared__ int s[1024];
    int t = threadIdx.x, g = blockIdx.x * 1024 + t;
    int v = (g < n) ? in[g] : 0;
    s[t] = v; __syncthreads();
    for (int off = 1; off < 1024; off <<= 1) {
        int u = (t >= off) ? s[t - off] : 0;
        __syncthreads();
        s[t] += u;
        __syncthreads();
    }
    if (g < n) out[g] = s[t] - v;           // exclusive
    if (t == 1023) bsum[blockIdx.x] = s[1023];
}

__global__ void k_scan2(int* __restrict__ bsum, int nb) {
    __shared__ int s[128];
    int t = threadIdx.x;
    int v = (t < nb) ? bsum[t] : 0;
    s[t] = v; __syncthreads();
    for (int off = 1; off < 128; off <<= 1) {
        int u = (t >= off) ? s[t - off] : 0;
        __syncthreads();
        s[t] += u;
        __syncthreads();
    }
    if (t < nb) bsum[t] = s[t] - v;         // exclusive
}

__global__ void k_scan3(int* __restrict__ out, const int* __restrict__ bsum, int n) {
    int g = blockIdx.x * 1024 + threadIdx.x;
    if (g < n) out[g] += bsum[blockIdx.x];
}

// pack edge as (src:17 | w_e8m7:15); w >= 0 so sign dropped; bf16-precision weight
__global__ void k_scatter(const int* __restrict__ src, const int* __restrict__ dst,
                          const float* __restrict__ w, const int* __restrict__ rstart,
                          int* __restrict__ cursor, unsigned int* __restrict__ epack, int n) {
    int i = blockIdx.x * 256 + threadIdx.x;
    if (i < n) {
        int d = dst[i];
        int pos = rstart[d] + atomicAdd(&cursor[d], 1);
        unsigned int wb = bf16_rte(w[i]) & 0x7FFFu;
        epack[pos] = ((unsigned int)src[i] << 15) | wb;
    }
}

// ---------------------------------------------------------------- ortho prep

__global__ void k_zc0(const float* __restrict__ W0, float* __restrict__ Zc0) {
    int r = blockIdx.x, t = threadIdx.x;
    float a = W0[r * NF + t];
    float b = W0[r * NF + 256 + t];
    float mean = block_sum_256(a + b) * (1.0f / 512.0f);
    Zc0[r * NF + t]       = a - mean;
    Zc0[r * NF + 256 + t] = b - mean;
}

__global__ void k_zcC(const float* __restrict__ convW, float* __restrict__ ZcC) {
    int g = blockIdx.x >> 8, r = blockIdx.x & 255, t = threadIdx.x;
    float v = 0.5f * convW[((size_t)g * NH + r) * NH + t] + ((r == t) ? 0.5f : 0.0f);
    float mean = block_sum_256(v) * (1.0f / 256.0f);
    ZcC[((size_t)g * NH + r) * NH + t] = v - mean;
}

// S[b] = Zc[b] @ Zc[b]^T + EPS*I   (b=0: Zc0 K=512; b>0: ZcC[b-1] K=256)
__global__ __launch_bounds__(256) void k_gram(const float* __restrict__ Zc0,
                                              const float* __restrict__ ZcC,
                                              float* __restrict__ S) {
    const int b = blockIdx.z;
    const float* A = (b == 0) ? Zc0 : (ZcC + (size_t)(b - 1) * 65536);
    const int K = (b == 0) ? 512 : 256;
    const int r0 = blockIdx.y * 64, c0 = blockIdx.x * 64;
    __shared__ float As[32][76], Bs[32][76];
    const int t = threadIdx.x, tx = t & 15, ty = t >> 4;
    const int lr = t >> 2, lk = (t & 3) * 4;
    float acc[4][4] = {};
    for (int k0 = 0; k0 < K; k0 += 32) {
        float4 a0 = *(const float4*)(A + (size_t)(r0 + lr) * K + k0 + lk);
        float4 a1 = *(const float4*)(A + (size_t)(r0 + lr) * K + k0 + lk + 16);
        As[lk + 0][lr] = a0.x; As[lk + 1][lr] = a0.y; As[lk + 2][lr] = a0.z; As[lk + 3][lr] = a0.w;
        As[lk + 16][lr] = a1.x; As[lk + 17][lr] = a1.y; As[lk + 18][lr] = a1.z; As[lk + 19][lr] = a1.w;
        float4 b0 = *(const float4*)(A + (size_t)(c0 + lr) * K + k0 + lk);
        float4 b1 = *(const float4*)(A + (size_t)(c0 + lr) * K + k0 + lk + 16);
        Bs[lk + 0][lr] = b0.x; Bs[lk + 1][lr] = b0.y; Bs[lk + 2][lr] = b0.z; Bs[lk + 3][lr] = b0.w;
        Bs[lk + 16][lr] = b1.x; Bs[lk + 17][lr] = b1.y; Bs[lk + 18][lr] = b1.z; Bs[lk + 19][lr] = b1.w;
        __syncthreads();
        #pragma unroll
        for (int kk = 0; kk < 32; kk++) {
            float a[4], bb[4];
            *(float4*)&a[0]  = *(const float4*)&As[kk][ty * 4];
            *(float4*)&bb[0] = *(const float4*)&Bs[kk][tx * 4];
            #pragma unroll
            for (int i = 0; i < 4; i++)
                #pragma unroll
                for (int j = 0; j < 4; j++) acc[i][j] = fmaf(a[i], bb[j], acc[i][j]);
        }
        __syncthreads();
    }
    #pragma unroll
    for (int i = 0; i < 4; i++)
        #pragma unroll
        for (int j = 0; j < 4; j++) {
            int r = r0 + ty * 4 + i, c = c0 + tx * 4 + j;
            float v = acc[i][j];
            if (r == c) v += EPSV;
            S[(size_t)b * 65536 + r * NH + c] = v;
        }
}

__global__ void k_fro(const float* __restrict__ S, float* __restrict__ scales) {
    __shared__ float sb[8];
    const int b = blockIdx.x, t = threadIdx.x;
    const float* p = S + (size_t)b * 65536;
    float s = 0.f;
    for (int i = t; i < 65536; i += 256) { float v = p[i]; s = fmaf(v, v, s); }
    #pragma unroll
    for (int off = 32; off; off >>= 1) s += __shfl_down(s, off, 64);
    if ((t & 63) == 0) sb[t >> 6] = s;
    __syncthreads();
    if (t == 0) {
        float nrm = sqrtf(sb[0] + sb[1] + sb[2] + sb[3]);
        scales[b]      = 1.0f / nrm;
        scales[16 + b] = rsqrtf(nrm);
    }
}

// B1 = 1.5*I - 0.5*invn*S  (closed-form first Newton-Schulz iteration)
__global__ void k_initB1(const float* __restrict__ S, const float* __restrict__ scales,
                         float* __restrict__ B) {
    int i = blockIdx.x * 256 + threadIdx.x;     // 9*65536
    int b = i >> 16, m = i & 65535;
    float v = -0.5f * scales[b] * S[i];
    if ((m >> 8) == (m & 255)) v += 1.5f;
    B[i] = v;
}

// Batch-18: b<9 -> T1[b] = B[b]@B[b] ; b>=9 -> T2[b-9] = B[b-9]@S[b-9]
__global__ __launch_bounds__(256) void k_ns_pair(const float* __restrict__ Bb,
                                                 const float* __restrict__ Smat,
                                                 float* __restrict__ T1b,
                                                 float* __restrict__ T2b) {
    const int b = blockIdx.z;
    const int bb = (b < 9) ? b : b - 9;
    const float* A  = Bb + (size_t)bb * 65536;
    const float* Bm = (b < 9) ? A : (Smat + (size_t)bb * 65536);
    float* C = (b < 9) ? (T1b + (size_t)bb * 65536) : (T2b + (size_t)bb * 65536);
    const int r0 = blockIdx.y * 64, c0 = blockIdx.x * 64;
    __shared__ float As[32][76], Bs[32][76];
    const int t = threadIdx.x, tx = t & 15, ty = t >> 4;
    const int lr = t >> 2, lk = (t & 3) * 4;
    const int bk = t >> 3, bc = (t & 7) * 8;
    float acc[4][4] = {};
    for (int k0 = 0; k0 < 256; k0 += 32) {
        float4 a0 = *(const float4*)(A + (size_t)(r0 + lr) * 256 + k0 + lk);
        float4 a1 = *(const float4*)(A + (size_t)(r0 + lr) * 256 + k0 + lk + 16);
        As[lk + 0][lr] = a0.x; As[lk + 1][lr] = a0.y; As[lk + 2][lr] = a0.z; As[lk + 3][lr] = a0.w;
        As[lk + 16][lr] = a1.x; As[lk + 17][lr] = a1.y; As[lk + 18][lr] = a1.z; As[lk + 19][lr] = a1.w;
        float4 b0 = *(const float4*)(Bm + (size_t)(k0 + bk) * 256 + c0 + bc);
        float4 b1 = *(const float4*)(Bm + (size_t)(k0 + bk) * 256 + c0 + bc + 4);
        *(float4*)&Bs[bk][bc]     = b0;
        *(float4*)&Bs[bk][bc + 4] = b1;
        __syncthreads();
        #pragma unroll
        for (int kk = 0; kk < 32; kk++) {
            float a[4], bb2[4];
            *(float4*)&a[0]   = *(const float4*)&As[kk][ty * 4];
            *(float4*)&bb2[0] = *(const float4*)&Bs[kk][tx * 4];
            #pragma unroll
            for (int i = 0; i < 4; i++)
                #pragma unroll
                for (int j = 0; j < 4; j++) acc[i][j] = fmaf(a[i], bb2[j], acc[i][j]);
        }
        __syncthreads();
    }
    #pragma unroll
    for (int i = 0; i < 4; i++)
        #pragma unroll
        for (int j = 0; j < 4; j++)
            C[(size_t)(r0 + ty * 4 + i) * 256 + c0 + tx * 4 + j] = acc[i][j];
}

// Batched small NN matmul, M=256, tile 64x64, Ktile 32.
// mode 1: C = 1.5*C - 0.5*scale[b]*(A@B) ; mode 2: C = scale[b]*(A@B)
__global__ __launch_bounds__(256) void k_small_nn(const float* __restrict__ A0,
                                                  const float* __restrict__ B0,
                                                  float* __restrict__ C0,
                                                  int sA, int sB, int sC,
                                                  int K, int Ncols, int mode,
                                                  const float* __restrict__ scale) {
    const int b = blockIdx.z;
    const float* A = A0 + (size_t)b * sA;
    const float* Bm = B0 + (size_t)b * sB;
    float* C = C0 + (size_t)b * sC;
    const int r0 = blockIdx.y * 64, c0 = blockIdx.x * 64;
    __shared__ float As[32][76], Bs[32][76];
    const int t = threadIdx.x, tx = t & 15, ty = t >> 4;
    const int lr = t >> 2, lk = (t & 3) * 4;
    const int bk = t >> 3, bc = (t & 7) * 8;
    float acc[4][4] = {};
    for (int k0 = 0; k0 < K; k0 += 32) {
        float4 a0 = *(const float4*)(A + (size_t)(r0 + lr) * K + k0 + lk);
        float4 a1 = *(const float4*)(A + (size_t)(r0 + lr) * K + k0 + lk + 16);
        As[lk + 0][lr] = a0.x; As[lk + 1][lr] = a0.y; As[lk + 2][lr] = a0.z; As[lk + 3][lr] = a0.w;
        As[lk + 16][lr] = a1.x; As[lk + 17][lr] = a1.y; As[lk + 18][lr] = a1.z; As[lk + 19][lr] = a1.w;
        float4 b0 = *(const float4*)(Bm + (size_t)(k0 + bk) * Ncols + c0 + bc);
        float4 b1 = *(const float4*)(Bm + (size_t)(k0 + bk) * Ncols + c0 + bc + 4);
        *(float4*)&Bs[bk][bc]     = b0;
        *(float4*)&Bs[bk][bc + 4] = b1;
        __syncthreads();
        #pragma unroll
        for (int kk = 0; kk < 32; kk++) {
            float a[4], bb[4];
            *(float4*)&a[0]  = *(const float4*)&As[kk][ty * 4];
            *(float4*)&bb[0] = *(const float4*)&Bs[kk][tx * 4];
            #pragma unroll
            for (int i = 0; i < 4; i++)
                #pragma unroll
                for (int j = 0; j < 4; j++) acc[i][j] = fmaf(a[i], bb[j], acc[i][j]);
        }
        __syncthreads();
    }
    #pragma unroll
    for (int i = 0; i < 4; i++)
        #pragma unroll
        for (int j = 0; j < 4; j++) {
            size_t idx = (size_t)(r0 + ty * 4 + i) * Ncols + c0 + tx * 4 + j;
            if (mode == 1) C[idx] = 1.5f * C[idx] - 0.5f * scale[b] * acc[i][j];
            else C[idx] = scale[b] * acc[i][j];
        }
}

// ---------------------------------------------------------------- MFMA B-operand packing
// Fragment layouts (gfx950 mfma_f32_16x16x32_bf16):
//   A: lane holds A[m=lane&15][k=(lane>>4)*8 + j], j=0..7
//   B: lane holds B[k=(lane>>4)*8 + j][n=lane&15]
//   C/D: col=lane&15, row=(lane>>4)*4 + reg
// Pack layout: [c=K/64][s=2][tg=16][lane=64][j=8] bf16 (per-chunk 32 KB contiguous)

// Mpack k-index is in pos space: Mpack[k_pos][n] = M[col(k_pos)][n]
__global__ void k_prepM(const float* __restrict__ tbuf, unsigned short* __restrict__ Mpack) {
    int idx = blockIdx.x * 256 + threadIdx.x;
    int lane = idx & 63;
    int tg   = (idx >> 6) & 15;
    int s    = (idx >> 10) & 1;
    int c    = (idx >> 11) & 3;
    int l    = idx >> 13;
    float theta = logf(0.5f / (float)(l + 1) + 1.0f);
    float mtheta = 1.0f - theta;
    int n  = tg * 16 + (lane & 15);
    int k0 = c * 64 + s * 32 + (lane >> 4) * 8;
    const float* T = tbuf + (size_t)l * 65536;
    unsigned short o[8];
    #pragma unroll
    for (int j = 0; j < 8; j++) {
        int kp = k0 + j;
        int kn = (kp & 0xC0) | ((kp & 3) << 4) | ((kp >> 2) & 15);   // col(pos)
        float v = theta * T[(size_t)kn * 256 + n] + ((kn == n) ? mtheta : 0.0f);
        o[j] = bf16_rte(v);
    }
    *(uint4*)(Mpack + (size_t)idx * 8) = *(uint4*)o;
}

// fc0 k-space = x features (natural, no perm)
__global__ void k_prepW0(const float* __restrict__ W0o, unsigned short* __restrict__ Wpack) {
    int idx = blockIdx.x * 256 + threadIdx.x;
    int lane = idx & 63;
    int tg   = (idx >> 6) & 15;
    int s    = (idx >> 10) & 1;
    int c    = idx >> 11;                    // 0..7
    int n  = tg * 16 + (lane & 15);
    int k0 = c * 64 + s * 32 + (lane >> 4) * 8;
    const float* p = W0o + (size_t)n * NF + k0;
    unsigned short o[8];
    #pragma unroll
    for (int j = 0; j < 8; j++) o[j] = bf16_rte(p[j]);
    *(uint4*)(Wpack + (size_t)idx * 8) = *(uint4*)o;
}

// ---------------------------------------------------------------- u8 epilogue helper
// (inlined in fc0/gemm): per-row max -> scale -> uint8 quant, pos-space dword stores.

// ---------------------------------------------------------------- fc0 (MFMA)

// h0u8/h0scale = quant(relu(x @ W0o^T + b0)). K=512 (8 chunks).
__global__ __launch_bounds__(256) void k_fc0_mfma(const float* __restrict__ X,
                                                  const unsigned short* __restrict__ Wp,
                                                  const float* __restrict__ bias,
                                                  unsigned char* __restrict__ h0u8,
                                                  float* __restrict__ h0scale) {
    __shared__ unsigned short Bs[2][16][64][8];   // 32 KB
    __shared__ int rmax[64];
    const int t = threadIdx.x, lane = t & 63, w = t >> 6;
    const int q = lane >> 4, m = lane & 15;
    const int r0 = blockIdx.x * 64;
    if (t < 64) rmax[t] = 0;
    floatx4 acc[4][4] = {};
    for (int c = 0; c < 8; c++) {
        const uint4* src = (const uint4*)(Wp + (size_t)c * 16384);
        uint4* dst = (uint4*)&Bs[0][0][0][0];
        #pragma unroll
        for (int i = 0; i < 8; i++) dst[t + 256 * i] = src[t + 256 * i];
        __syncthreads();
        #pragma unroll
        for (int s = 0; s < 2; s++) {
            short8 afr[4];
            #pragma unroll
            for (int i = 0; i < 4; i++) {
                int row = r0 + i * 16 + m; if (row > NNODES - 1) row = NNODES - 1;
                const float* p = X + (size_t)row * NF + c * 64 + s * 32 + q * 8;
                float4 xa = *(const float4*)p;
                float4 xb = *(const float4*)(p + 4);
                uint4 af;
                af.x = pack_bf2(xa.x, xa.y); af.y = pack_bf2(xa.z, xa.w);
                af.z = pack_bf2(xb.x, xb.y); af.w = pack_bf2(xb.z, xb.w);
                afr[i] = *(short8*)&af;
            }
            #pragma unroll
            for (int tg = 0; tg < 4; tg++) {
                short8 bfr = *(const short8*)&Bs[s][w * 4 + tg][lane][0];
                #pragma unroll
                for (int i = 0; i < 4; i++)
                    acc[i][tg] = __builtin_amdgcn_mfma_f32_16x16x32_bf16(afr[i], bfr, acc[i][tg], 0, 0, 0);
            }
        }
        __syncthreads();
    }
    // bias + relu in place
    #pragma unroll
    for (int tg = 0; tg < 4; tg++) {
        float bv = bias[w * 64 + tg * 16 + m];
        #pragma unroll
        for (int i = 0; i < 4; i++)
            #pragma unroll
            for (int r = 0; r < 4; r++)
                acc[i][tg][r] = fmaxf(acc[i][tg][r] + bv, 0.f);
    }
    // row max (phase A)
    #pragma unroll
    for (int i = 0; i < 4; i++)
        #pragma unroll
        for (int r = 0; r < 4; r++) {
            float mx = fmaxf(fmaxf(acc[i][0][r], acc[i][1][r]),
                             fmaxf(acc[i][2][r], acc[i][3][r]));
            mx = fmaxf(mx, __shfl_xor(mx, 1));
            mx = fmaxf(mx, __shfl_xor(mx, 2));
            mx = fmaxf(mx, __shfl_xor(mx, 4));
            mx = fmaxf(mx, __shfl_xor(mx, 8));
            if (m == 0) atomicMax(&rmax[i * 16 + q * 4 + r], __float_as_int(mx));
        }
    __syncthreads();
    // quantize + store (phase B)
    #pragma unroll
    for (int i = 0; i < 4; i++)
        #pragma unroll
        for (int r = 0; r < 4; r++) {
            int row = r0 + i * 16 + q * 4 + r;
            if (row >= NNODES) continue;
            float rm = __int_as_float(rmax[i * 16 + q * 4 + r]);
            float qs = rm > 0.f ? 255.0f / rm : 0.f;
            unsigned int b0 = (unsigned int)fmaf(acc[i][0][r], qs, 0.5f);
            unsigned int b1 = (unsigned int)fmaf(acc[i][1][r], qs, 0.5f);
            unsigned int b2 = (unsigned int)fmaf(acc[i][2][r], qs, 0.5f);
            unsigned int b3 = (unsigned int)fmaf(acc[i][3][r], qs, 0.5f);
            *(unsigned int*)(h0u8 + (size_t)row * NH + w * 64 + m * 4) =
                b0 | (b1 << 8) | (b2 << 16) | (b3 << 24);
        }
    if (t < 64 && r0 + t < NNODES)
        h0scale[r0 + t] = __int_as_float(rmax[t]) * (1.0f / 255.0f);
}

// ---------------------------------------------------------------- SpMM (uint8 gather)

// One wave per dst node; lane owns 4 pos-features (4B gather per lane).
// supbf[d,:] = bf16( 0.9*sum_e w_e*h[src_e,:] + 0.1*h0[d,:] ), h/h0 uint8+rowscale.
__global__ __launch_bounds__(256) void k_spmm(const int* __restrict__ rstart,
                                              const int* __restrict__ counts,
                                              const unsigned int* __restrict__ epack,
                                              const unsigned char* __restrict__ hu8,
                                              const float* __restrict__ hscale,
                                              const unsigned char* __restrict__ h0u8,
                                              const float* __restrict__ h0scale,
                                              unsigned short* __restrict__ supbf) {
    __shared__ int2 se[4][64];
    const int wv = threadIdx.x >> 6, lane = threadIdx.x & 63;
    const int node = blockIdx.x * 4 + wv;
    const int start = rstart[node], deg = counts[node];
    float a0 = 0.f, a1 = 0.f, a2 = 0.f, a3 = 0.f;
    for (int base = 0; base < deg; base += 64) {
        int j = base + lane;
        if (j < deg) {
            unsigned int u = epack[start + j];
            int s = (int)(u >> 15);
            float wt = __uint_as_float((u & 0x7FFFu) << 16);   // e8m7, sign 0
            se[wv][lane] = make_int2(s, __float_as_int(wt * hscale[s] * 0.9f));
        }
        int mm = deg - base; if (mm > 64) mm = 64;
        int e = 0;
        for (; e + 8 <= mm; e += 8) {
            float ww[8]; unsigned int g[8];
            #pragma unroll
            for (int u = 0; u < 8; u++) {
                int2 ed = se[wv][e + u];
                ww[u] = __int_as_float(ed.y);
                g[u] = *(const unsigned int*)(hu8 + ((size_t)ed.x << 8) + (lane << 2));
            }
            #pragma unroll
            for (int u = 0; u < 8; u++) {
                a0 = fmaf(ww[u], (float)(g[u] & 0xFFu), a0);
                a1 = fmaf(ww[u], (float)((g[u] >> 8) & 0xFFu), a1);
                a2 = fmaf(ww[u], (float)((g[u] >> 16) & 0xFFu), a2);
                a3 = fmaf(ww[u], (float)(g[u] >> 24), a3);
            }
        }
        for (; e < mm; e++) {
            int2 ed = se[wv][e];
            float ww = __int_as_float(ed.y);
            unsigned int g = *(const unsigned int*)(hu8 + ((size_t)ed.x << 8) + (lane << 2));
            a0 = fmaf(ww, (float)(g & 0xFFu), a0);
            a1 = fmaf(ww, (float)((g >> 8) & 0xFFu), a1);
            a2 = fmaf(ww, (float)((g >> 16) & 0xFFu), a2);
            a3 = fmaf(ww, (float)(g >> 24), a3);
        }
    }
    unsigned int rg = *(const unsigned int*)(h0u8 + ((size_t)node << 8) + (lane << 2));
    float rs = h0scale[node] * 0.1f;
    float o0 = fmaf(rs, (float)(rg & 0xFFu), a0);
    float o1 = fmaf(rs, (float)((rg >> 8) & 0xFFu), a1);
    float o2 = fmaf(rs, (float)((rg >> 16) & 0xFFu), a2);
    float o3 = fmaf(rs, (float)(rg >> 24), a3);
    uint2 ov;
    ov.x = pack_bf2(o0, o1);
    ov.y = pack_bf2(o2, o3);
    *(uint2*)(supbf + ((size_t)node << 8) + (lane << 2)) = ov;
}

// ---------------------------------------------------------------- layer GEMM (MFMA, no LDS staging)

// D = relu(Sbf @ M). l=1..7: quantize rows to uint8+scale (pos space).
// l=8 (out_bf != null): bf16 natural store for logits.
__global__ __launch_bounds__(256) void k_gemm_layer(const unsigned short* __restrict__ Sbf,
                                                    const unsigned short* __restrict__ Mp,
                                                    unsigned char* __restrict__ out_u8,
                                                    float* __restrict__ out_scale,
                                                    unsigned short* __restrict__ out_bf) {
    __shared__ int rmax[64];
    const int t = threadIdx.x, lane = t & 63, w = t >> 6;
    const int q = lane >> 4, m = lane & 15;
    const int r0 = blockIdx.x * 64;
    if (t < 64) rmax[t] = 0;
    floatx4 acc[4][4] = {};
    #pragma unroll
    for (int c = 0; c < 4; c++) {
        #pragma unroll
        for (int s = 0; s < 2; s++) {
            short8 afr[4];
            #pragma unroll
            for (int i = 0; i < 4; i++) {
                int row = r0 + i * 16 + m; if (row > NNODES - 1) row = NNODES - 1;
                afr[i] = *(const short8*)(Sbf + (size_t)row * NH + c * 64 + s * 32 + q * 8);
            }
            #pragma unroll
            for (int tg = 0; tg < 4; tg++) {
                short8 bfr = *(const short8*)(Mp + (size_t)c * 16384 + s * 8192
                                              + (w * 4 + tg) * 512 + lane * 8);
                #pragma unroll
                for (int i = 0; i < 4; i++)
                    acc[i][tg] = __builtin_amdgcn_mfma_f32_16x16x32_bf16(afr[i], bfr, acc[i][tg], 0, 0, 0);
            }
        }
    }
    // relu in place
    #pragma unroll
    for (int i = 0; i < 4; i++)
        #pragma unroll
        for (int tg = 0; tg < 4; tg++)
            #pragma unroll
            for (int r = 0; r < 4; r++)
                acc[i][tg][r] = fmaxf(acc[i][tg][r], 0.f);

    if (out_bf) {   // layer 8: natural bf16 scatter
        #pragma unroll
        for (int i = 0; i < 4; i++)
            #pragma unroll
            for (int tg = 0; tg < 4; tg++) {
                int col = w * 64 + tg * 16 + m;
                #pragma unroll
                for (int r = 0; r < 4; r++) {
                    int row = r0 + i * 16 + q * 4 + r;
                    if (row >= NNODES) continue;
                    out_bf[(size_t)row * NH + col] = bf16_rte(acc[i][tg][r]);
                }
            }
        return;
    }
    // phase A: row max
    __syncthreads();   // rmax init visible
    #pragma unroll
    for (int i = 0; i < 4; i++)
        #pragma unroll
        for (int r = 0; r < 4; r++) {
            float mx = fmaxf(fmaxf(acc[i][0][r], acc[i][1][r]),
                             fmaxf(acc[i][2][r], acc[i][3][r]));
            mx = fmaxf(mx, __shfl_xor(mx, 1));
            mx = fmaxf(mx, __shfl_xor(mx, 2));
            mx = fmaxf(mx, __shfl_xor(mx, 4));
            mx = fmaxf(mx, __shfl_xor(mx, 8));
            if (m == 0) atomicMax(&rmax[i * 16 + q * 4 + r], __float_as_int(mx));
        }
    __syncthreads();
    // phase B: quantize + pos-space dword stores
    #pragma unroll
    for (int i = 0; i < 4; i++)
        #pragma unroll
        for (int r = 0; r < 4; r++) {
            int row = r0 + i * 16 + q * 4 + r;
            if (row >= NNODES) continue;
            float rm = __int_as_float(rmax[i * 16 + q * 4 + r]);
            float qs = rm > 0.f ? 255.0f / rm : 0.f;
            unsigned int b0 = (unsigned int)fmaf(acc[i][0][r], qs, 0.5f);
            unsigned int b1 = (unsigned int)fmaf(acc[i][1][r], qs, 0.5f);
            unsigned int b2 = (unsigned int)fmaf(acc[i][2][r], qs, 0.5f);
            unsigned int b3 = (unsigned int)fmaf(acc[i][3][r], qs, 0.5f);
            *(unsigned int*)(out_u8 + (size_t)row * NH + w * 64 + m * 4) =
                b0 | (b1 << 8) | (b2 << 16) | (b3 << 24);
        }
    if (t < 64 && r0 + t < NNODES)
        out_scale[r0 + t] = __int_as_float(rmax[t]) * (1.0f / 255.0f);
}

// ---------------------------------------------------------------- logits + log_softmax (bf16 h, natural)

__global__ __launch_bounds__(128) void k_logits(const unsigned short* __restrict__ hb,
                                                const float* __restrict__ W1,
                                                const float* __restrict__ b1,
                                                float* __restrict__ out, int nrows) {
    __shared__ float hs[16][260];
    __shared__ float Ws[40][260];
    __shared__ float ls[16][44];
    __shared__ float lse[16];
    const int t = threadIdx.x;
    const int row0 = blockIdx.x * 16;
    for (int i = t; i < 40 * 64; i += 128) {
        int c = i >> 6, k4 = i & 63;
        *(float4*)&Ws[c][k4 * 4] = *(const float4*)(W1 + (size_t)c * NH + k4 * 4);
    }
    for (int i = t; i < 16 * 32; i += 128) {
        int r = i >> 5, k8 = i & 31;
        int gr = row0 + r;
        uint4 v = make_uint4(0u, 0u, 0u, 0u);
        if (gr < nrows) v = *(const uint4*)(hb + ((size_t)gr << 8) + k8 * 8);
        float* d = &hs[r][k8 * 8];
        d[0] = __uint_as_float(v.x << 16); d[1] = __uint_as_float(v.x & 0xffff0000u);
        d[2] = __uint_as_float(v.y << 16); d[3] = __uint_as_float(v.y & 0xffff0000u);
        d[4] = __uint_as_float(v.z << 16); d[5] = __uint_as_float(v.z & 0xffff0000u);
        d[6] = __uint_as_float(v.w << 16); d[7] = __uint_as_float(v.w & 0xffff0000u);
    }
    __syncthreads();
    const int r = t & 15, cg = t >> 4;   // cg in 0..7, 5 classes each
    float acc[5];
    #pragma unroll
    for (int j = 0; j < 5; j++) acc[j] = b1[cg * 5 + j];
    for (int k = 0; k < NH; k++) {
        float hv = hs[r][k];
        #pragma unroll
        for (int j = 0; j < 5; j++) acc[j] = fmaf(hv, Ws[cg * 5 + j][k], acc[j]);
    }
    #pragma unroll
    for (int j = 0; j < 5; j++) ls[r][cg * 5 + j] = acc[j];
    __syncthreads();
    if (t < 16) {
        float m = -3.4e38f;
        for (int c = 0; c < NC; c++) m = fmaxf(m, ls[t][c]);
        float s = 0.f;
        for (int c = 0; c < NC; c++) s += expf(ls[t][c] - m);
        lse[t] = m + logf(s);
    }
    __syncthreads();
    for (int i = t; i < 16 * NC; i += 128) {
        int r2 = i / NC, c = i % NC;
        int gr = row0 + r2;
        if (gr < nrows) out[(size_t)gr * NC + c] = ls[r2][c] - lse[r2];
    }
}

// ---------------------------------------------------------------- launch

extern "C" void kernel_launch(void* const* d_in, const int* in_sizes, int n_in,
                              void* d_out, int out_size, void* d_ws, size_t ws_size,
                              hipStream_t stream) {
    const float* x      = (const float*)d_in[0];
    const int*   e_src  = (const int*)d_in[1];
    const int*   e_dst  = (const int*)d_in[2];
    const float* e_w    = (const float*)d_in[3];
    const float* W0     = (const float*)d_in[4];
    const float* b0     = (const float*)d_in[5];
    const float* convW  = (const float*)d_in[6];
    const float* W1     = (const float*)d_in[7];
    const float* b1     = (const float*)d_in[8];
    float* out = (float*)d_out;

    char* ws = (char*)d_ws;
    const size_t OFF_H0U8   = 0;                                    // u8 [N,256] 25.6 MB
    const size_t OFF_HU8A   = OFF_H0U8 + (size_t)NNODES * NH;       // u8 [N,256]
    const size_t OFF_HU8B   = OFF_HU8A + (size_t)NNODES * NH;       // u8 [N,256]
    const size_t OFF_H0SC   = OFF_HU8B + (size_t)NNODES * NH;       // f32 [N]
    const size_t OFF_SCA    = OFF_H0SC + (size_t)NNODES * 4;
    const size_t OFF_SCB    = OFF_SCA + (size_t)NNODES * 4;
    const size_t OFF_SUPBF  = OFF_SCB + (size_t)NNODES * 4;         // bf16 [N,256] 51.2 MB
    const size_t OFF_HBF    = OFF_SUPBF + (size_t)NNODES * NH * 2;  // bf16 [N,256] (layer-8)
    const size_t OFF_EPACK  = OFF_HBF + (size_t)NNODES * NH * 2;    // u32 [E] 12.8 MB
    const size_t OFF_RSTART = OFF_EPACK + (size_t)NEDGE * 4;
    const size_t OFF_COUNTS = OFF_RSTART + (size_t)NNODES * 4;
    const size_t OFF_CURSOR = OFF_COUNTS + (size_t)NNODES * 4;
    const size_t OFF_BSUM   = OFF_CURSOR + (size_t)NNODES * 4;
    const size_t OFF_ZC0    = OFF_BSUM + 1024;
    const size_t OFF_ZCC    = OFF_ZC0 + 256 * 512 * 4;
    const size_t OFF_S      = OFF_ZCC + 8 * 65536 * 4;
    const size_t OFF_B      = OFF_S + 9 * 65536 * 4;
    const size_t OFF_T1     = OFF_B + 9 * 65536 * 4;
    const size_t OFF_T2     = OFF_T1 + 9 * 65536 * 4;
    const size_t OFF_T      = OFF_T2 + 9 * 65536 * 4;
    const size_t OFF_W0O    = OFF_T + 8 * 65536 * 4;
    const size_t OFF_SCALES = OFF_W0O + 256 * 512 * 4;
    const size_t OFF_MPACK  = OFF_SCALES + 1024;
    const size_t OFF_WPACK  = OFF_MPACK + 8 * 65536 * 2;

    unsigned char* h0u8 = (unsigned char*)(ws + OFF_H0U8);
    unsigned char* hu8A = (unsigned char*)(ws + OFF_HU8A);
    unsigned char* hu8B = (unsigned char*)(ws + OFF_HU8B);
    float* h0sc = (float*)(ws + OFF_H0SC);
    float* scA  = (float*)(ws + OFF_SCA);
    float* scB  = (float*)(ws + OFF_SCB);
    unsigned short* supbf = (unsigned short*)(ws + OFF_SUPBF);
    unsigned short* hbf   = (unsigned short*)(ws + OFF_HBF);
    unsigned int* epack  = (unsigned int*)(ws + OFF_EPACK);
    int*    rstart = (int*)(ws + OFF_RSTART);
    int*    counts = (int*)(ws + OFF_COUNTS);
    int*    cursor = (int*)(ws + OFF_CURSOR);
    int*    bsum   = (int*)(ws + OFF_BSUM);
    float*  Zc0    = (float*)(ws + OFF_ZC0);
    float*  ZcC    = (float*)(ws + OFF_ZCC);
    float*  Smat   = (float*)(ws + OFF_S);
    float*  Bb     = (float*)(ws + OFF_B);
    float*  T1b    = (float*)(ws + OFF_T1);
    float*  T2b    = (float*)(ws + OFF_T2);
    float*  tbuf   = (float*)(ws + OFF_T);
    float*  W0o    = (float*)(ws + OFF_W0O);
    float*  scales = (float*)(ws + OFF_SCALES);
    unsigned short* Mpack = (unsigned short*)(ws + OFF_MPACK);
    unsigned short* Wpack = (unsigned short*)(ws + OFF_WPACK);

    (void)in_sizes; (void)n_in; (void)out_size; (void)ws_size;

    // ---- CSR build
    hipMemsetAsync(counts, 0, (size_t)NNODES * 4, stream);
    hipMemsetAsync(cursor, 0, (size_t)NNODES * 4, stream);
    k_hist<<<(NEDGE + 255) / 256, 256, 0, stream>>>(e_dst, counts, NEDGE);
    const int NB = (NNODES + 1023) / 1024;   // 98
    k_scan1<<<NB, 1024, 0, stream>>>(counts, rstart, bsum, NNODES);
    k_scan2<<<1, 128, 0, stream>>>(bsum, NB);
    k_scan3<<<NB, 1024, 0, stream>>>(rstart, bsum, NNODES);
    k_scatter<<<(NEDGE + 255) / 256, 256, 0, stream>>>(e_src, e_dst, e_w, rstart, cursor,
                                                       epack, NEDGE);

    // ---- ortho: batched Newton-Schulz (T=5; first iteration closed-form)
    k_zc0<<<256, 256, 0, stream>>>(W0, Zc0);
    k_zcC<<<8 * 256, 256, 0, stream>>>(convW, ZcC);
    k_gram<<<dim3(4, 4, 9), 256, 0, stream>>>(Zc0, ZcC, Smat);
    k_fro<<<9, 256, 0, stream>>>(Smat, scales);
    k_initB1<<<9 * 256, 256, 0, stream>>>(Smat, scales, Bb);
    for (int it = 1; it < 5; it++) {
        k_ns_pair<<<dim3(4, 4, 18), 256, 0, stream>>>(Bb, Smat, T1b, T2b);
        k_small_nn<<<dim3(4, 4, 9), 256, 0, stream>>>(T1b, T2b, Bb, 65536, 65536, 65536,
                                                      256, 256, 1, scales);
    }
    // W0o = (B0 @ Zc0) * rsqn[0]; t[g] = (B[g+1] @ ZcC[g]) * rsqn[g+1]
    k_small_nn<<<dim3(8, 4, 1), 256, 0, stream>>>(Bb, Zc0, W0o, 0, 0, 0,
                                                  256, 512, 2, scales + 16);
    k_small_nn<<<dim3(4, 4, 8), 256, 0, stream>>>(Bb + 65536, ZcC, tbuf, 65536, 65536, 65536,
                                                  256, 256, 2, scales + 17);

    // ---- pack B-operands for MFMA
    k_prepM<<<256, 256, 0, stream>>>(tbuf, Mpack);
    k_prepW0<<<64, 256, 0, stream>>>(W0o, Wpack);

    // ---- fc0 (MFMA): h0u8/h0sc = quant(relu(x @ W0o^T + b0))
    const int GB = (NNODES + 63) / 64;   // 1563
    k_fc0_mfma<<<GB, 256, 0, stream>>>(x, Wpack, b0, h0u8, h0sc);

    // ---- 8 GCNII layers: u8 gather spmm -> bf16 sup -> MFMA GEMM -> u8 (or bf16 l=8)
    const unsigned char* hin = h0u8;
    const float* hinsc = h0sc;
    unsigned char* u8bufs[2] = { hu8A, hu8B };
    float* scbufs[2] = { scA, scB };
    for (int l = 1; l <= NLAY; l++) {
        k_spmm<<<NNODES / 4, 256, 0, stream>>>(rstart, counts, epack, hin, hinsc,
                                               h0u8, h0sc, supbf);
        const unsigned short* Mp = Mpack + (size_t)(l - 1) * 65536;
        if (l == NLAY) {
            k_gemm_layer<<<GB, 256, 0, stream>>>(supbf, Mp, nullptr, nullptr, hbf);
        } else {
            unsigned char* ou = u8bufs[(l - 1) & 1];
            float* os = scbufs[(l - 1) & 1];
            k_gemm_layer<<<GB, 256, 0, stream>>>(supbf, Mp, ou, os, nullptr);
            hin = ou; hinsc = os;
        }
    }

    // ---- logits + log_softmax (reads bf16 h, natural order)
    k_logits<<<NNODES / 16, 128, 0, stream>>>(hbf, W1, b1, out, NNODES);
}

// Round 7
// 2432.394 us; speedup vs baseline: 2.6271x; 1.0601x over previous
//
#include <hip/hip_runtime.h>
#include <math.h>

// Problem constants (fixed by reference)
#define NNODES 100000
#define NEDGE  3200000
#define NF     512
#define NH     256
#define NC     40
#define NLAY   8
#define EPSV   1e-5f

typedef __attribute__((ext_vector_type(8))) short short8;   // 8 bf16 (4 VGPRs)
typedef __attribute__((ext_vector_type(4))) float floatx4;  // MFMA acc

// Feature permutation (epilogue-natural uint8 store order):
//   pos(col) = (col&0xC0) | ((col&15)<<2) | ((col>>4)&3)
//   col(pos) = (pos&0xC0) | ((pos&3)<<4) | ((pos>>2)&15)
// All u8 h-buffers, sup, and Mpack k-rows live in pos space; layer-8 output and
// logits use natural order.

// ---------------------------------------------------------------- utilities

__device__ __forceinline__ float block_sum_256(float v) {
    __shared__ float sb[8];
    #pragma unroll
    for (int off = 32; off; off >>= 1) v += __shfl_down(v, off, 64);
    if ((threadIdx.x & 63) == 0) sb[threadIdx.x >> 6] = v;
    __syncthreads();
    return sb[0] + sb[1] + sb[2] + sb[3];
}

// round-to-nearest-even f32 -> bf16
__device__ __forceinline__ unsigned short bf16_rte(float a) {
    unsigned int u = __float_as_uint(a);
    return (unsigned short)((u + 0x7fffu + ((u >> 16) & 1u)) >> 16);
}
__device__ __forceinline__ unsigned int pack_bf2(float a, float b) {
    unsigned int ua = __float_as_uint(a), ub = __float_as_uint(b);
    ua = (ua + 0x7fffu + ((ua >> 16) & 1u)) >> 16;
    ub = (ub + 0x7fffu + ((ub >> 16) & 1u)) & 0xffff0000u;
    return ua | ub;
}

// ---------------------------------------------------------------- CSR build

__global__ void k_hist(const int* __restrict__ dst, int* __restrict__ counts, int n) {
    int i = blockIdx.x * 256 + threadIdx.x;
    if (i < n) atomicAdd(&counts[dst[i]], 1);
}

__global__ void k_scan1(const int* __restrict__ in, int* __restrict__ out,
                        int* __restrict__ bsum, int n) {
    __shared__ int s[1024];
    int t = threadIdx.x, g = blockIdx.x * 1024 + t;
    int v = (g < n) ? in[g] : 0;
    s[t] = v; __syncthreads();
    for (int off = 1; off < 1024; off <<= 1) {
        int u = (t >= off) ? s[t - off] : 0;
        __syncthreads();
        s[t] += u;
        __syncthreads();
    }
    if (g < n) out[g] = s[t] - v;           // exclusive
    if (t == 1023) bsum[blockIdx.x] = s[1023];
}

__global__ void k_scan2(int* __restrict__ bsum, int nb) {
    __shared__ int s[128];
    int t = threadIdx.x;
    int v = (t < nb) ? bsum[t] : 0;
    s[t] = v; __syncthreads();
    for (int off = 1; off < 128; off <<= 1) {
        int u = (t >= off) ? s[t - off] : 0;
        __syncthreads();
        s[t] += u;
        __syncthreads();
    }
    if (t < nb) bsum[t] = s[t] - v;         // exclusive
}

__global__ void k_scan3(int* __restrict__ out, const int* __restrict__ bsum, int n) {
    int g = blockIdx.x * 1024 + threadIdx.x;
    if (g < n) out[g] += bsum[blockIdx.x];
}

// pack edge as (src:17 | w_e8m7:15); w >= 0 so sign dropped; bf16-precision weight
__global__ void k_scatter(const int* __restrict__ src, const int* __restrict__ dst,
                          const float* __restrict__ w, const int* __restrict__ rstart,
                          int* __restrict__ cursor, unsigned int* __restrict__ epack, int n) {
    int i = blockIdx.x * 256 + threadIdx.x;
    if (i < n) {
        int d = dst[i];
        int pos = rstart[d] + atomicAdd(&cursor[d], 1);
        unsigned int wb = bf16_rte(w[i]) & 0x7FFFu;
        epack[pos] = ((unsigned int)src[i] << 15) | wb;
    }
}

// ---------------------------------------------------------------- x -> bf16 (coalesced)

__global__ void k_xbf16(const float* __restrict__ X, unsigned short* __restrict__ Xb, long n8) {
    long i = (long)blockIdx.x * 256 + threadIdx.x;   // one uint4 (8 bf16) per thread
    if (i >= n8) return;
    const float* p = X + i * 8;
    float4 a = *(const float4*)p;
    float4 b = *(const float4*)(p + 4);
    uint4 o;
    o.x = pack_bf2(a.x, a.y); o.y = pack_bf2(a.z, a.w);
    o.z = pack_bf2(b.x, b.y); o.w = pack_bf2(b.z, b.w);
    *(uint4*)(Xb + i * 8) = o;
}

// ---------------------------------------------------------------- ortho prep

__global__ void k_zc0(const float* __restrict__ W0, float* __restrict__ Zc0) {
    int r = blockIdx.x, t = threadIdx.x;
    float a = W0[r * NF + t];
    float b = W0[r * NF + 256 + t];
    float mean = block_sum_256(a + b) * (1.0f / 512.0f);
    Zc0[r * NF + t]       = a - mean;
    Zc0[r * NF + 256 + t] = b - mean;
}

__global__ void k_zcC(const float* __restrict__ convW, float* __restrict__ ZcC) {
    int g = blockIdx.x >> 8, r = blockIdx.x & 255, t = threadIdx.x;
    float v = 0.5f * convW[((size_t)g * NH + r) * NH + t] + ((r == t) ? 0.5f : 0.0f);
    float mean = block_sum_256(v) * (1.0f / 256.0f);
    ZcC[((size_t)g * NH + r) * NH + t] = v - mean;
}

// S[b] = Zc[b] @ Zc[b]^T + EPS*I   (b=0: Zc0 K=512; b>0: ZcC[b-1] K=256)
__global__ __launch_bounds__(256) void k_gram(const float* __restrict__ Zc0,
                                              const float* __restrict__ ZcC,
                                              float* __restrict__ S) {
    const int b = blockIdx.z;
    const float* A = (b == 0) ? Zc0 : (ZcC + (size_t)(b - 1) * 65536);
    const int K = (b == 0) ? 512 : 256;
    const int r0 = blockIdx.y * 64, c0 = blockIdx.x * 64;
    __shared__ float As[32][76], Bs[32][76];
    const int t = threadIdx.x, tx = t & 15, ty = t >> 4;
    const int lr = t >> 2, lk = (t & 3) * 4;
    float acc[4][4] = {};
    for (int k0 = 0; k0 < K; k0 += 32) {
        float4 a0 = *(const float4*)(A + (size_t)(r0 + lr) * K + k0 + lk);
        float4 a1 = *(const float4*)(A + (size_t)(r0 + lr) * K + k0 + lk + 16);
        As[lk + 0][lr] = a0.x; As[lk + 1][lr] = a0.y; As[lk + 2][lr] = a0.z; As[lk + 3][lr] = a0.w;
        As[lk + 16][lr] = a1.x; As[lk + 17][lr] = a1.y; As[lk + 18][lr] = a1.z; As[lk + 19][lr] = a1.w;
        float4 b0 = *(const float4*)(A + (size_t)(c0 + lr) * K + k0 + lk);
        float4 b1 = *(const float4*)(A + (size_t)(c0 + lr) * K + k0 + lk + 16);
        Bs[lk + 0][lr] = b0.x; Bs[lk + 1][lr] = b0.y; Bs[lk + 2][lr] = b0.z; Bs[lk + 3][lr] = b0.w;
        Bs[lk + 16][lr] = b1.x; Bs[lk + 17][lr] = b1.y; Bs[lk + 18][lr] = b1.z; Bs[lk + 19][lr] = b1.w;
        __syncthreads();
        #pragma unroll
        for (int kk = 0; kk < 32; kk++) {
            float a[4], bb[4];
            *(float4*)&a[0]  = *(const float4*)&As[kk][ty * 4];
            *(float4*)&bb[0] = *(const float4*)&Bs[kk][tx * 4];
            #pragma unroll
            for (int i = 0; i < 4; i++)
                #pragma unroll
                for (int j = 0; j < 4; j++) acc[i][j] = fmaf(a[i], bb[j], acc[i][j]);
        }
        __syncthreads();
    }
    #pragma unroll
    for (int i = 0; i < 4; i++)
        #pragma unroll
        for (int j = 0; j < 4; j++) {
            int r = r0 + ty * 4 + i, c = c0 + tx * 4 + j;
            float v = acc[i][j];
            if (r == c) v += EPSV;
            S[(size_t)b * 65536 + r * NH + c] = v;
        }
}

__global__ void k_fro(const float* __restrict__ S, float* __restrict__ scales) {
    __shared__ float sb[8];
    const int b = blockIdx.x, t = threadIdx.x;
    const float* p = S + (size_t)b * 65536;
    float s = 0.f;
    for (int i = t; i < 65536; i += 256) { float v = p[i]; s = fmaf(v, v, s); }
    #pragma unroll
    for (int off = 32; off; off >>= 1) s += __shfl_down(s, off, 64);
    if ((t & 63) == 0) sb[t >> 6] = s;
    __syncthreads();
    if (t == 0) {
        float nrm = sqrtf(sb[0] + sb[1] + sb[2] + sb[3]);
        scales[b]      = 1.0f / nrm;
        scales[16 + b] = rsqrtf(nrm);
    }
}

// B1 = 1.5*I - 0.5*invn*S  (closed-form first Newton-Schulz iteration)
__global__ void k_initB1(const float* __restrict__ S, const float* __restrict__ scales,
                         float* __restrict__ B) {
    int i = blockIdx.x * 256 + threadIdx.x;     // 9*65536
    int b = i >> 16, m = i & 65535;
    float v = -0.5f * scales[b] * S[i];
    if ((m >> 8) == (m & 255)) v += 1.5f;
    B[i] = v;
}

// Batch-18: b<9 -> T1[b] = B[b]@B[b] ; b>=9 -> T2[b-9] = B[b-9]@S[b-9]
__global__ __launch_bounds__(256) void k_ns_pair(const float* __restrict__ Bb,
                                                 const float* __restrict__ Smat,
                                                 float* __restrict__ T1b,
                                                 float* __restrict__ T2b) {
    const int b = blockIdx.z;
    const int bb = (b < 9) ? b : b - 9;
    const float* A  = Bb + (size_t)bb * 65536;
    const float* Bm = (b < 9) ? A : (Smat + (size_t)bb * 65536);
    float* C = (b < 9) ? (T1b + (size_t)bb * 65536) : (T2b + (size_t)bb * 65536);
    const int r0 = blockIdx.y * 64, c0 = blockIdx.x * 64;
    __shared__ float As[32][76], Bs[32][76];
    const int t = threadIdx.x, tx = t & 15, ty = t >> 4;
    const int lr = t >> 2, lk = (t & 3) * 4;
    const int bk = t >> 3, bc = (t & 7) * 8;
    float acc[4][4] = {};
    for (int k0 = 0; k0 < 256; k0 += 32) {
        float4 a0 = *(const float4*)(A + (size_t)(r0 + lr) * 256 + k0 + lk);
        float4 a1 = *(const float4*)(A + (size_t)(r0 + lr) * 256 + k0 + lk + 16);
        As[lk + 0][lr] = a0.x; As[lk + 1][lr] = a0.y; As[lk + 2][lr] = a0.z; As[lk + 3][lr] = a0.w;
        As[lk + 16][lr] = a1.x; As[lk + 17][lr] = a1.y; As[lk + 18][lr] = a1.z; As[lk + 19][lr] = a1.w;
        float4 b0 = *(const float4*)(Bm + (size_t)(k0 + bk) * 256 + c0 + bc);
        float4 b1 = *(const float4*)(Bm + (size_t)(k0 + bk) * 256 + c0 + bc + 4);
        *(float4*)&Bs[bk][bc]     = b0;
        *(float4*)&Bs[bk][bc + 4] = b1;
        __syncthreads();
        #pragma unroll
        for (int kk = 0; kk < 32; kk++) {
            float a[4], bb2[4];
            *(float4*)&a[0]   = *(const float4*)&As[kk][ty * 4];
            *(float4*)&bb2[0] = *(const float4*)&Bs[kk][tx * 4];
            #pragma unroll
            for (int i = 0; i < 4; i++)
                #pragma unroll
                for (int j = 0; j < 4; j++) acc[i][j] = fmaf(a[i], bb2[j], acc[i][j]);
        }
        __syncthreads();
    }
    #pragma unroll
    for (int i = 0; i < 4; i++)
        #pragma unroll
        for (int j = 0; j < 4; j++)
            C[(size_t)(r0 + ty * 4 + i) * 256 + c0 + tx * 4 + j] = acc[i][j];
}

// Batched small NN matmul, M=256, tile 64x64, Ktile 32.
// mode 1: C = 1.5*C - 0.5*scale[b]*(A@B) ; mode 2: C = scale[b]*(A@B)
__global__ __launch_bounds__(256) void k_small_nn(const float* __restrict__ A0,
                                                  const float* __restrict__ B0,
                                                  float* __restrict__ C0,
                                                  int sA, int sB, int sC,
                                                  int K, int Ncols, int mode,
                                                  const float* __restrict__ scale) {
    const int b = blockIdx.z;
    const float* A = A0 + (size_t)b * sA;
    const float* Bm = B0 + (size_t)b * sB;
    float* C = C0 + (size_t)b * sC;
    const int r0 = blockIdx.y * 64, c0 = blockIdx.x * 64;
    __shared__ float As[32][76], Bs[32][76];
    const int t = threadIdx.x, tx = t & 15, ty = t >> 4;
    const int lr = t >> 2, lk = (t & 3) * 4;
    const int bk = t >> 3, bc = (t & 7) * 8;
    float acc[4][4] = {};
    for (int k0 = 0; k0 < K; k0 += 32) {
        float4 a0 = *(const float4*)(A + (size_t)(r0 + lr) * K + k0 + lk);
        float4 a1 = *(const float4*)(A + (size_t)(r0 + lr) * K + k0 + lk + 16);
        As[lk + 0][lr] = a0.x; As[lk + 1][lr] = a0.y; As[lk + 2][lr] = a0.z; As[lk + 3][lr] = a0.w;
        As[lk + 16][lr] = a1.x; As[lk + 17][lr] = a1.y; As[lk + 18][lr] = a1.z; As[lk + 19][lr] = a1.w;
        float4 b0 = *(const float4*)(Bm + (size_t)(k0 + bk) * Ncols + c0 + bc);
        float4 b1 = *(const float4*)(Bm + (size_t)(k0 + bk) * Ncols + c0 + bc + 4);
        *(float4*)&Bs[bk][bc]     = b0;
        *(float4*)&Bs[bk][bc + 4] = b1;
        __syncthreads();
        #pragma unroll
        for (int kk = 0; kk < 32; kk++) {
            float a[4], bb[4];
            *(float4*)&a[0]  = *(const float4*)&As[kk][ty * 4];
            *(float4*)&bb[0] = *(const float4*)&Bs[kk][tx * 4];
            #pragma unroll
            for (int i = 0; i < 4; i++)
                #pragma unroll
                for (int j = 0; j < 4; j++) acc[i][j] = fmaf(a[i], bb[j], acc[i][j]);
        }
        __syncthreads();
    }
    #pragma unroll
    for (int i = 0; i < 4; i++)
        #pragma unroll
        for (int j = 0; j < 4; j++) {
            size_t idx = (size_t)(r0 + ty * 4 + i) * Ncols + c0 + tx * 4 + j;
            if (mode == 1) C[idx] = 1.5f * C[idx] - 0.5f * scale[b] * acc[i][j];
            else C[idx] = scale[b] * acc[i][j];
        }
}

// ---------------------------------------------------------------- MFMA B-operand packing
// Fragment layouts (gfx950 mfma_f32_16x16x32_bf16):
//   A: lane holds A[m=lane&15][k=(lane>>4)*8 + j], j=0..7
//   B: lane holds B[k=(lane>>4)*8 + j][n=lane&15]
//   C/D: col=lane&15, row=(lane>>4)*4 + reg
// Pack layout: [c=K/64][s=2][tg=16][lane=64][j=8] bf16 (per-chunk 32 KB contiguous)

// Mpack k-index is in pos space: Mpack[k_pos][n] = M[col(k_pos)][n]
__global__ void k_prepM(const float* __restrict__ tbuf, unsigned short* __restrict__ Mpack) {
    int idx = blockIdx.x * 256 + threadIdx.x;
    int lane = idx & 63;
    int tg   = (idx >> 6) & 15;
    int s    = (idx >> 10) & 1;
    int c    = (idx >> 11) & 3;
    int l    = idx >> 13;
    float theta = logf(0.5f / (float)(l + 1) + 1.0f);
    float mtheta = 1.0f - theta;
    int n  = tg * 16 + (lane & 15);
    int k0 = c * 64 + s * 32 + (lane >> 4) * 8;
    const float* T = tbuf + (size_t)l * 65536;
    unsigned short o[8];
    #pragma unroll
    for (int j = 0; j < 8; j++) {
        int kp = k0 + j;
        int kn = (kp & 0xC0) | ((kp & 3) << 4) | ((kp >> 2) & 15);   // col(pos)
        float v = theta * T[(size_t)kn * 256 + n] + ((kn == n) ? mtheta : 0.0f);
        o[j] = bf16_rte(v);
    }
    *(uint4*)(Mpack + (size_t)idx * 8) = *(uint4*)o;
}

// fc0 k-space = x features (natural, no perm)
__global__ void k_prepW0(const float* __restrict__ W0o, unsigned short* __restrict__ Wpack) {
    int idx = blockIdx.x * 256 + threadIdx.x;
    int lane = idx & 63;
    int tg   = (idx >> 6) & 15;
    int s    = (idx >> 10) & 1;
    int c    = idx >> 11;                    // 0..7
    int n  = tg * 16 + (lane & 15);
    int k0 = c * 64 + s * 32 + (lane >> 4) * 8;
    const float* p = W0o + (size_t)n * NF + k0;
    unsigned short o[8];
    #pragma unroll
    for (int j = 0; j < 8; j++) o[j] = bf16_rte(p[j]);
    *(uint4*)(Wpack + (size_t)idx * 8) = *(uint4*)o;
}

// ---------------------------------------------------------------- fc0 (MFMA, LDS-free)

// h0u8/h0scale = quant(relu(xbf @ W0o^T + b0)). K=512 (8 chunks).
// A-fragments direct from bf16 x; B-fragments direct from L2-resident Wpack.
__global__ __launch_bounds__(256) void k_fc0_mfma(const unsigned short* __restrict__ Xb,
                                                  const unsigned short* __restrict__ Wp,
                                                  const float* __restrict__ bias,
                                                  unsigned char* __restrict__ h0u8,
                                                  float* __restrict__ h0scale) {
    __shared__ int rmax[64];
    const int t = threadIdx.x, lane = t & 63, w = t >> 6;
    const int q = lane >> 4, m = lane & 15;
    const int r0 = blockIdx.x * 64;
    if (t < 64) rmax[t] = 0;
    floatx4 acc[4][4] = {};
    #pragma unroll
    for (int c = 0; c < 8; c++) {
        #pragma unroll
        for (int s = 0; s < 2; s++) {
            short8 afr[4];
            #pragma unroll
            for (int i = 0; i < 4; i++) {
                int row = r0 + i * 16 + m; if (row > NNODES - 1) row = NNODES - 1;
                afr[i] = *(const short8*)(Xb + (size_t)row * NF + c * 64 + s * 32 + q * 8);
            }
            #pragma unroll
            for (int tg = 0; tg < 4; tg++) {
                short8 bfr = *(const short8*)(Wp + (size_t)c * 16384 + s * 8192
                                              + (w * 4 + tg) * 512 + lane * 8);
                #pragma unroll
                for (int i = 0; i < 4; i++)
                    acc[i][tg] = __builtin_amdgcn_mfma_f32_16x16x32_bf16(afr[i], bfr, acc[i][tg], 0, 0, 0);
            }
        }
    }
    // bias + relu in place
    #pragma unroll
    for (int tg = 0; tg < 4; tg++) {
        float bv = bias[w * 64 + tg * 16 + m];
        #pragma unroll
        for (int i = 0; i < 4; i++)
            #pragma unroll
            for (int r = 0; r < 4; r++)
                acc[i][tg][r] = fmaxf(acc[i][tg][r] + bv, 0.f);
    }
    __syncthreads();   // rmax init visible
    // row max (phase A)
    #pragma unroll
    for (int i = 0; i < 4; i++)
        #pragma unroll
        for (int r = 0; r < 4; r++) {
            float mx = fmaxf(fmaxf(acc[i][0][r], acc[i][1][r]),
                             fmaxf(acc[i][2][r], acc[i][3][r]));
            mx = fmaxf(mx, __shfl_xor(mx, 1));
            mx = fmaxf(mx, __shfl_xor(mx, 2));
            mx = fmaxf(mx, __shfl_xor(mx, 4));
            mx = fmaxf(mx, __shfl_xor(mx, 8));
            if (m == 0) atomicMax(&rmax[i * 16 + q * 4 + r], __float_as_int(mx));
        }
    __syncthreads();
    // quantize + store (phase B)
    #pragma unroll
    for (int i = 0; i < 4; i++)
        #pragma unroll
        for (int r = 0; r < 4; r++) {
            int row = r0 + i * 16 + q * 4 + r;
            if (row >= NNODES) continue;
            float rm = __int_as_float(rmax[i * 16 + q * 4 + r]);
            float qs = rm > 0.f ? 255.0f / rm : 0.f;
            unsigned int b0 = (unsigned int)fmaf(acc[i][0][r], qs, 0.5f);
            unsigned int b1 = (unsigned int)fmaf(acc[i][1][r], qs, 0.5f);
            unsigned int b2 = (unsigned int)fmaf(acc[i][2][r], qs, 0.5f);
            unsigned int b3 = (unsigned int)fmaf(acc[i][3][r], qs, 0.5f);
            *(unsigned int*)(h0u8 + (size_t)row * NH + w * 64 + m * 4) =
                b0 | (b1 << 8) | (b2 << 16) | (b3 << 24);
        }
    if (t < 64 && r0 + t < NNODES)
        h0scale[r0 + t] = __int_as_float(rmax[t]) * (1.0f / 255.0f);
}

// ---------------------------------------------------------------- SpMM (uint8 gather)

// One wave per dst node; lane owns 4 pos-features (4B gather per lane).
// supbf[d,:] = bf16( 0.9*sum_e w_e*h[src_e,:] + 0.1*h0[d,:] ), h/h0 uint8+rowscale.
__global__ __launch_bounds__(256) void k_spmm(const int* __restrict__ rstart,
                                              const int* __restrict__ counts,
                                              const unsigned int* __restrict__ epack,
                                              const unsigned char* __restrict__ hu8,
                                              const float* __restrict__ hscale,
                                              const unsigned char* __restrict__ h0u8,
                                              const float* __restrict__ h0scale,
                                              unsigned short* __restrict__ supbf) {
    __shared__ int2 se[4][64];
    const int wv = threadIdx.x >> 6, lane = threadIdx.x & 63;
    const int node = blockIdx.x * 4 + wv;
    const int start = rstart[node], deg = counts[node];
    float a0 = 0.f, a1 = 0.f, a2 = 0.f, a3 = 0.f;
    for (int base = 0; base < deg; base += 64) {
        int j = base + lane;
        if (j < deg) {
            unsigned int u = epack[start + j];
            int s = (int)(u >> 15);
            float wt = __uint_as_float((u & 0x7FFFu) << 16);   // e8m7, sign 0
            se[wv][lane] = make_int2(s, __float_as_int(wt * hscale[s] * 0.9f));
        }
        int mm = deg - base; if (mm > 64) mm = 64;
        int e = 0;
        for (; e + 8 <= mm; e += 8) {
            float ww[8]; unsigned int g[8];
            #pragma unroll
            for (int u = 0; u < 8; u++) {
                int2 ed = se[wv][e + u];
                ww[u] = __int_as_float(ed.y);
                g[u] = *(const unsigned int*)(hu8 + ((size_t)ed.x << 8) + (lane << 2));
            }
            #pragma unroll
            for (int u = 0; u < 8; u++) {
                a0 = fmaf(ww[u], (float)(g[u] & 0xFFu), a0);
                a1 = fmaf(ww[u], (float)((g[u] >> 8) & 0xFFu), a1);
                a2 = fmaf(ww[u], (float)((g[u] >> 16) & 0xFFu), a2);
                a3 = fmaf(ww[u], (float)(g[u] >> 24), a3);
            }
        }
        for (; e < mm; e++) {
            int2 ed = se[wv][e];
            float ww = __int_as_float(ed.y);
            unsigned int g = *(const unsigned int*)(hu8 + ((size_t)ed.x << 8) + (lane << 2));
            a0 = fmaf(ww, (float)(g & 0xFFu), a0);
            a1 = fmaf(ww, (float)((g >> 8) & 0xFFu), a1);
            a2 = fmaf(ww, (float)((g >> 16) & 0xFFu), a2);
            a3 = fmaf(ww, (float)(g >> 24), a3);
        }
    }
    unsigned int rg = *(const unsigned int*)(h0u8 + ((size_t)node << 8) + (lane << 2));
    float rs = h0scale[node] * 0.1f;
    float o0 = fmaf(rs, (float)(rg & 0xFFu), a0);
    float o1 = fmaf(rs, (float)((rg >> 8) & 0xFFu), a1);
    float o2 = fmaf(rs, (float)((rg >> 16) & 0xFFu), a2);
    float o3 = fmaf(rs, (float)(rg >> 24), a3);
    uint2 ov;
    ov.x = pack_bf2(o0, o1);
    ov.y = pack_bf2(o2, o3);
    *(uint2*)(supbf + ((size_t)node << 8) + (lane << 2)) = ov;
}

// ---------------------------------------------------------------- layer GEMM (MFMA, no LDS staging)

// D = relu(Sbf @ M). l=1..7: quantize rows to uint8+scale (pos space).
// l=8 (out_bf != null): bf16 natural store for logits.
__global__ __launch_bounds__(256) void k_gemm_layer(const unsigned short* __restrict__ Sbf,
                                                    const unsigned short* __restrict__ Mp,
                                                    unsigned char* __restrict__ out_u8,
                                                    float* __restrict__ out_scale,
                                                    unsigned short* __restrict__ out_bf) {
    __shared__ int rmax[64];
    const int t = threadIdx.x, lane = t & 63, w = t >> 6;
    const int q = lane >> 4, m = lane & 15;
    const int r0 = blockIdx.x * 64;
    if (t < 64) rmax[t] = 0;
    floatx4 acc[4][4] = {};
    #pragma unroll
    for (int c = 0; c < 4; c++) {
        #pragma unroll
        for (int s = 0; s < 2; s++) {
            short8 afr[4];
            #pragma unroll
            for (int i = 0; i < 4; i++) {
                int row = r0 + i * 16 + m; if (row > NNODES - 1) row = NNODES - 1;
                afr[i] = *(const short8*)(Sbf + (size_t)row * NH + c * 64 + s * 32 + q * 8);
            }
            #pragma unroll
            for (int tg = 0; tg < 4; tg++) {
                short8 bfr = *(const short8*)(Mp + (size_t)c * 16384 + s * 8192
                                              + (w * 4 + tg) * 512 + lane * 8);
                #pragma unroll
                for (int i = 0; i < 4; i++)
                    acc[i][tg] = __builtin_amdgcn_mfma_f32_16x16x32_bf16(afr[i], bfr, acc[i][tg], 0, 0, 0);
            }
        }
    }
    // relu in place
    #pragma unroll
    for (int i = 0; i < 4; i++)
        #pragma unroll
        for (int tg = 0; tg < 4; tg++)
            #pragma unroll
            for (int r = 0; r < 4; r++)
                acc[i][tg][r] = fmaxf(acc[i][tg][r], 0.f);

    if (out_bf) {   // layer 8: natural bf16 scatter
        #pragma unroll
        for (int i = 0; i < 4; i++)
            #pragma unroll
            for (int tg = 0; tg < 4; tg++) {
                int col = w * 64 + tg * 16 + m;
                #pragma unroll
                for (int r = 0; r < 4; r++) {
                    int row = r0 + i * 16 + q * 4 + r;
                    if (row >= NNODES) continue;
                    out_bf[(size_t)row * NH + col] = bf16_rte(acc[i][tg][r]);
                }
            }
        return;
    }
    // phase A: row max
    __syncthreads();   // rmax init visible
    #pragma unroll
    for (int i = 0; i < 4; i++)
        #pragma unroll
        for (int r = 0; r < 4; r++) {
            float mx = fmaxf(fmaxf(acc[i][0][r], acc[i][1][r]),
                             fmaxf(acc[i][2][r], acc[i][3][r]));
            mx = fmaxf(mx, __shfl_xor(mx, 1));
            mx = fmaxf(mx, __shfl_xor(mx, 2));
            mx = fmaxf(mx, __shfl_xor(mx, 4));
            mx = fmaxf(mx, __shfl_xor(mx, 8));
            if (m == 0) atomicMax(&rmax[i * 16 + q * 4 + r], __float_as_int(mx));
        }
    __syncthreads();
    // phase B: quantize + pos-space dword stores
    #pragma unroll
    for (int i = 0; i < 4; i++)
        #pragma unroll
        for (int r = 0; r < 4; r++) {
            int row = r0 + i * 16 + q * 4 + r;
            if (row >= NNODES) continue;
            float rm = __int_as_float(rmax[i * 16 + q * 4 + r]);
            float qs = rm > 0.f ? 255.0f / rm : 0.f;
            unsigned int b0 = (unsigned int)fmaf(acc[i][0][r], qs, 0.5f);
            unsigned int b1 = (unsigned int)fmaf(acc[i][1][r], qs, 0.5f);
            unsigned int b2 = (unsigned int)fmaf(acc[i][2][r], qs, 0.5f);
            unsigned int b3 = (unsigned int)fmaf(acc[i][3][r], qs, 0.5f);
            *(unsigned int*)(out_u8 + (size_t)row * NH + w * 64 + m * 4) =
                b0 | (b1 << 8) | (b2 << 16) | (b3 << 24);
        }
    if (t < 64 && r0 + t < NNODES)
        out_scale[r0 + t] = __int_as_float(rmax[t]) * (1.0f / 255.0f);
}

// ---------------------------------------------------------------- logits + log_softmax (bf16 h, natural)

__global__ __launch_bounds__(256) void k_logits(const unsigned short* __restrict__ hb,
                                                const float* __restrict__ W1,
                                                const float* __restrict__ b1,
                                                float* __restrict__ out, int nrows) {
    __shared__ float hs[32][260];
    __shared__ float Ws[40][260];
    __shared__ float ls[32][44];
    __shared__ float lse[32];
    const int t = threadIdx.x;
    const int row0 = blockIdx.x * 32;
    for (int i = t; i < 40 * 64; i += 256) {
        int c = i >> 6, k4 = i & 63;
        *(float4*)&Ws[c][k4 * 4] = *(const float4*)(W1 + (size_t)c * NH + k4 * 4);
    }
    for (int i = t; i < 32 * 32; i += 256) {
        int r = i >> 5, k8 = i & 31;
        int gr = row0 + r;
        uint4 v = make_uint4(0u, 0u, 0u, 0u);
        if (gr < nrows) v = *(const uint4*)(hb + ((size_t)gr << 8) + k8 * 8);
        float* d = &hs[r][k8 * 8];
        d[0] = __uint_as_float(v.x << 16); d[1] = __uint_as_float(v.x & 0xffff0000u);
        d[2] = __uint_as_float(v.y << 16); d[3] = __uint_as_float(v.y & 0xffff0000u);
        d[4] = __uint_as_float(v.z << 16); d[5] = __uint_as_float(v.z & 0xffff0000u);
        d[6] = __uint_as_float(v.w << 16); d[7] = __uint_as_float(v.w & 0xffff0000u);
    }
    __syncthreads();
    const int r = t & 31, cg = t >> 5;   // cg in 0..7, 5 classes each
    float acc[5];
    #pragma unroll
    for (int j = 0; j < 5; j++) acc[j] = b1[cg * 5 + j];
    for (int k = 0; k < NH; k++) {
        float hv = hs[r][k];
        #pragma unroll
        for (int j = 0; j < 5; j++) acc[j] = fmaf(hv, Ws[cg * 5 + j][k], acc[j]);
    }
    #pragma unroll
    for (int j = 0; j < 5; j++) ls[r][cg * 5 + j] = acc[j];
    __syncthreads();
    if (t < 32) {
        float m = -3.4e38f;
        for (int c = 0; c < NC; c++) m = fmaxf(m, ls[t][c]);
        float s = 0.f;
        for (int c = 0; c < NC; c++) s += expf(ls[t][c] - m);
        lse[t] = m + logf(s);
    }
    __syncthreads();
    for (int i = t; i < 32 * NC; i += 256) {
        int r2 = i / NC, c = i % NC;
        int gr = row0 + r2;
        if (gr < nrows) out[(size_t)gr * NC + c] = ls[r2][c] - lse[r2];
    }
}

// ---------------------------------------------------------------- launch

extern "C" void kernel_launch(void* const* d_in, const int* in_sizes, int n_in,
                              void* d_out, int out_size, void* d_ws, size_t ws_size,
                              hipStream_t stream) {
    const float* x      = (const float*)d_in[0];
    const int*   e_src  = (const int*)d_in[1];
    const int*   e_dst  = (const int*)d_in[2];
    const float* e_w    = (const float*)d_in[3];
    const float* W0     = (const float*)d_in[4];
    const float* b0     = (const float*)d_in[5];
    const float* convW  = (const float*)d_in[6];
    const float* W1     = (const float*)d_in[7];
    const float* b1     = (const float*)d_in[8];
    float* out = (float*)d_out;

    char* ws = (char*)d_ws;
    const size_t OFF_H0U8   = 0;                                    // u8 [N,256] 25.6 MB
    const size_t OFF_HU8A   = OFF_H0U8 + (size_t)NNODES * NH;       // u8 [N,256]
    const size_t OFF_HU8B   = OFF_HU8A + (size_t)NNODES * NH;       // u8 [N,256]
    const size_t OFF_H0SC   = OFF_HU8B + (size_t)NNODES * NH;       // f32 [N]
    const size_t OFF_SCA    = OFF_H0SC + (size_t)NNODES * 4;
    const size_t OFF_SCB    = OFF_SCA + (size_t)NNODES * 4;
    const size_t OFF_SUPBF  = OFF_SCB + (size_t)NNODES * 4;         // bf16 [N,256] 51.2 MB
    const size_t OFF_HBF    = OFF_SUPBF + (size_t)NNODES * NH * 2;  // bf16 [N,256] (layer-8)
    const size_t OFF_XBF    = OFF_HBF + (size_t)NNODES * NH * 2;    // bf16 [N,512] 102.4 MB
    const size_t OFF_EPACK  = OFF_XBF + (size_t)NNODES * NF * 2;    // u32 [E] 12.8 MB
    const size_t OFF_RSTART = OFF_EPACK + (size_t)NEDGE * 4;
    const size_t OFF_COUNTS = OFF_RSTART + (size_t)NNODES * 4;
    const size_t OFF_CURSOR = OFF_COUNTS + (size_t)NNODES * 4;
    const size_t OFF_BSUM   = OFF_CURSOR + (size_t)NNODES * 4;
    const size_t OFF_ZC0    = OFF_BSUM + 1024;
    const size_t OFF_ZCC    = OFF_ZC0 + 256 * 512 * 4;
    const size_t OFF_S      = OFF_ZCC + 8 * 65536 * 4;
    const size_t OFF_B      = OFF_S + 9 * 65536 * 4;
    const size_t OFF_T1     = OFF_B + 9 * 65536 * 4;
    const size_t OFF_T2     = OFF_T1 + 9 * 65536 * 4;
    const size_t OFF_T      = OFF_T2 + 9 * 65536 * 4;
    const size_t OFF_W0O    = OFF_T + 8 * 65536 * 4;
    const size_t OFF_SCALES = OFF_W0O + 256 * 512 * 4;
    const size_t OFF_MPACK  = OFF_SCALES + 1024;
    const size_t OFF_WPACK  = OFF_MPACK + 8 * 65536 * 2;

    unsigned char* h0u8 = (unsigned char*)(ws + OFF_H0U8);
    unsigned char* hu8A = (unsigned char*)(ws + OFF_HU8A);
    unsigned char* hu8B = (unsigned char*)(ws + OFF_HU8B);
    float* h0sc = (float*)(ws + OFF_H0SC);
    float* scA  = (float*)(ws + OFF_SCA);
    float* scB  = (float*)(ws + OFF_SCB);
    unsigned short* supbf = (unsigned short*)(ws + OFF_SUPBF);
    unsigned short* hbf   = (unsigned short*)(ws + OFF_HBF);
    unsigned short* xbf   = (unsigned short*)(ws + OFF_XBF);
    unsigned int* epack  = (unsigned int*)(ws + OFF_EPACK);
    int*    rstart = (int*)(ws + OFF_RSTART);
    int*    counts = (int*)(ws + OFF_COUNTS);
    int*    cursor = (int*)(ws + OFF_CURSOR);
    int*    bsum   = (int*)(ws + OFF_BSUM);
    float*  Zc0    = (float*)(ws + OFF_ZC0);
    float*  ZcC    = (float*)(ws + OFF_ZCC);
    float*  Smat   = (float*)(ws + OFF_S);
    float*  Bb     = (float*)(ws + OFF_B);
    float*  T1b    = (float*)(ws + OFF_T1);
    float*  T2b    = (float*)(ws + OFF_T2);
    float*  tbuf   = (float*)(ws + OFF_T);
    float*  W0o    = (float*)(ws + OFF_W0O);
    float*  scales = (float*)(ws + OFF_SCALES);
    unsigned short* Mpack = (unsigned short*)(ws + OFF_MPACK);
    unsigned short* Wpack = (unsigned short*)(ws + OFF_WPACK);

    (void)in_sizes; (void)n_in; (void)out_size; (void)ws_size;

    // ---- CSR build
    hipMemsetAsync(counts, 0, (size_t)NNODES * 4, stream);
    hipMemsetAsync(cursor, 0, (size_t)NNODES * 4, stream);
    k_hist<<<(NEDGE + 255) / 256, 256, 0, stream>>>(e_dst, counts, NEDGE);
    const int NB = (NNODES + 1023) / 1024;   // 98
    k_scan1<<<NB, 1024, 0, stream>>>(counts, rstart, bsum, NNODES);
    k_scan2<<<1, 128, 0, stream>>>(bsum, NB);
    k_scan3<<<NB, 1024, 0, stream>>>(rstart, bsum, NNODES);
    k_scatter<<<(NEDGE + 255) / 256, 256, 0, stream>>>(e_src, e_dst, e_w, rstart, cursor,
                                                       epack, NEDGE);

    // ---- x -> bf16 (coalesced one-shot)
    const long N8 = (long)NNODES * NF / 8;   // 6,400,000
    k_xbf16<<<(int)((N8 + 255) / 256), 256, 0, stream>>>(x, xbf, N8);

    // ---- ortho: batched Newton-Schulz (T=5; first iteration closed-form)
    k_zc0<<<256, 256, 0, stream>>>(W0, Zc0);
    k_zcC<<<8 * 256, 256, 0, stream>>>(convW, ZcC);
    k_gram<<<dim3(4, 4, 9), 256, 0, stream>>>(Zc0, ZcC, Smat);
    k_fro<<<9, 256, 0, stream>>>(Smat, scales);
    k_initB1<<<9 * 256, 256, 0, stream>>>(Smat, scales, Bb);
    for (int it = 1; it < 5; it++) {
        k_ns_pair<<<dim3(4, 4, 18), 256, 0, stream>>>(Bb, Smat, T1b, T2b);
        k_small_nn<<<dim3(4, 4, 9), 256, 0, stream>>>(T1b, T2b, Bb, 65536, 65536, 65536,
                                                      256, 256, 1, scales);
    }
    // W0o = (B0 @ Zc0) * rsqn[0]; t[g] = (B[g+1] @ ZcC[g]) * rsqn[g+1]
    k_small_nn<<<dim3(8, 4, 1), 256, 0, stream>>>(Bb, Zc0, W0o, 0, 0, 0,
                                                  256, 512, 2, scales + 16);
    k_small_nn<<<dim3(4, 4, 8), 256, 0, stream>>>(Bb + 65536, ZcC, tbuf, 65536, 65536, 65536,
                                                  256, 256, 2, scales + 17);

    // ---- pack B-operands for MFMA
    k_prepM<<<256, 256, 0, stream>>>(tbuf, Mpack);
    k_prepW0<<<64, 256, 0, stream>>>(W0o, Wpack);

    // ---- fc0 (MFMA, LDS-free): h0u8/h0sc = quant(relu(xbf @ W0o^T + b0))
    const int GB = (NNODES + 63) / 64;   // 1563
    k_fc0_mfma<<<GB, 256, 0, stream>>>(xbf, Wpack, b0, h0u8, h0sc);

    // ---- 8 GCNII layers: u8 gather spmm -> bf16 sup -> MFMA GEMM -> u8 (or bf16 l=8)
    const unsigned char* hin = h0u8;
    const float* hinsc = h0sc;
    unsigned char* u8bufs[2] = { hu8A, hu8B };
    float* scbufs[2] = { scA, scB };
    for (int l = 1; l <= NLAY; l++) {
        k_spmm<<<NNODES / 4, 256, 0, stream>>>(rstart, counts, epack, hin, hinsc,
                                               h0u8, h0sc, supbf);
        const unsigned short* Mp = Mpack + (size_t)(l - 1) * 65536;
        if (l == NLAY) {
            k_gemm_layer<<<GB, 256, 0, stream>>>(supbf, Mp, nullptr, nullptr, hbf);
        } else {
            unsigned char* ou = u8bufs[(l - 1) & 1];
            float* os = scbufs[(l - 1) & 1];
            k_gemm_layer<<<GB, 256, 0, stream>>>(supbf, Mp, ou, os, nullptr);
            hin = ou; hinsc = os;
        }
    }

    // ---- logits + log_softmax (reads bf16 h, natural order)
    k_logits<<<(NNODES + 31) / 32, 256, 0, stream>>>(hbf, W1, b1, out, NNODES);
}